// Round 1
// baseline (1221.170 us; speedup 1.0000x reference)
//
#include <hip/hip_runtime.h>

#define NSRC 784
#define NTOT 1568
#define NHD 8
#define DVC 256
#define DCC 64
#define D20 20
#define FDIM 512
#define OUT_PER_SRC 25690112

// ---------------------------------------------------------------------------
// identical score dot in phase1/phase2 so softmax stats are consistent
__device__ __forceinline__ float dot20(const float4* q4, const float* kr) {
    const float4* k4 = (const float4*)kr;
    float s = 0.f;
#pragma unroll
    for (int i = 0; i < 5; ++i) {
        float4 a = q4[i], b = k4[i];
        s += a.x * b.x; s += a.y * b.y; s += a.z * b.z; s += a.w * b.w;
    }
    return s;
}

// ---------------------------------------------------------------------------
// K1: window average of values (256d) and coords (64d)
__global__ __launch_bounds__(256) void k1_avg(
    const float* __restrict__ v0, const float* __restrict__ c0,
    const float* __restrict__ v1, const float* __restrict__ c1,
    float* __restrict__ Vavg, float* __restrict__ Cavg) {
    int blk = blockIdx.x;                 // b*NTOT + N
    int b = blk / NTOT, N = blk % NTOT;
    int src = N / NSRC, nloc = N % NSRC;
    int wh = nloc / 28, ww = nloc % 28;
    const float* __restrict__ V = src ? v1 : v0;
    const float* __restrict__ C = src ? c1 : c0;
    int t = threadIdx.x;
    int pbase = (b * 224 + wh * 8) * 224 + ww * 8;
    float s = 0.f;
#pragma unroll 8
    for (int p = 0; p < 64; ++p)
        s += V[(pbase + (p >> 3) * 224 + (p & 7)) * DVC + t];
    Vavg[blk * DVC + t] = s * 0.015625f;
    if (t < DCC) {
        float sc = 0.f;
#pragma unroll 8
        for (int p = 0; p < 64; ++p)
            sc += C[(pbase + (p >> 3) * 224 + (p & 7)) * DCC + t];
        Cavg[blk * DCC + t] = sc * 0.015625f;
    }
}

// ---------------------------------------------------------------------------
// K2: qk = rmsnorm(avg @ Wqk + b, g); split heads into packed 20-dim q/k rows
// q rows pre-scaled by 1/sqrt(128) (v part) and 1/sqrt(32) (c part)
__global__ __launch_bounds__(256) void k2_qk(
    const float* __restrict__ Vavg, const float* __restrict__ Cavg,
    const float* __restrict__ Wqkv, const float* __restrict__ bqkv, const float* __restrict__ gv,
    const float* __restrict__ Wqkc, const float* __restrict__ bqkc, const float* __restrict__ gc,
    float* __restrict__ q20, float* __restrict__ k20) {
    __shared__ float xv[DVC];
    __shared__ float xc[DCC];
    __shared__ float wred[4];
    int blk = blockIdx.x;                 // b*NTOT + N
    int b = blk / NTOT, N = blk % NTOT;
    int t = threadIdx.x;
    xv[t] = Vavg[blk * DVC + t];
    if (t < DCC) xc[t] = Cavg[blk * DCC + t];
    __syncthreads();
    // values qk (256 outputs, one per thread)
    float yv = bqkv[t];
#pragma unroll 4
    for (int d = 0; d < DVC; ++d) yv += xv[d] * Wqkv[d * 256 + t];
    float ss = yv * yv;
#pragma unroll
    for (int off = 32; off; off >>= 1) ss += __shfl_xor(ss, off, 64);
    if ((t & 63) == 0) wred[t >> 6] = ss;
    __syncthreads();
    float tot = wred[0] + wred[1] + wred[2] + wred[3];
    float rv = rsqrtf(tot * (1.f / 256.f) + 1e-6f);
    float yn = yv * rv * gv[t];
    int h = t >> 5, c = t & 31;
    int bh = b * NHD + h;
    if (c < 16) q20[(bh * NTOT + N) * D20 + c] = yn * 0.088388347648318447f;   // 1/sqrt(128)
    else        k20[(bh * NTOT + N) * D20 + (c - 16)] = yn;
    // coords qk (64 outputs, wave 0 only)
    if (t < DCC) {
        float yc = bqkc[t];
#pragma unroll 4
        for (int d = 0; d < DCC; ++d) yc += xc[d] * Wqkc[d * 64 + t];
        float sc = yc * yc;
#pragma unroll
        for (int off = 32; off; off >>= 1) sc += __shfl_xor(sc, off, 64);
        float rc = rsqrtf(sc * (1.f / 64.f) + 1e-6f);
        float ycn = yc * rc * gc[t];
        int h2 = t >> 3, c2 = t & 7;
        int bh2 = b * NHD + h2;
        if (c2 < 4) q20[(bh2 * NTOT + N) * D20 + 16 + c2] = ycn * 0.17677669529663687f; // 1/sqrt(32)
        else        k20[(bh2 * NTOT + N) * D20 + 16 + (c2 - 4)] = ycn;
    }
}

// ---------------------------------------------------------------------------
// K3: per-window GEMM (64 pixels x 256) @ Wv(256 x 64) -> Vv[b][h][N][n*8+e]
__global__ __launch_bounds__(256) void k3_vv(
    const float* __restrict__ v0, const float* __restrict__ v1,
    const float* __restrict__ Wv, float* __restrict__ Vv) {
    __shared__ float Pix[64][65];   // [pixel][dd]  (+1 pad)
    __shared__ float WvB[64][64];   // [dd][e]
    int blk = blockIdx.x;
    int b = blk / NTOT, N = blk % NTOT;
    int src = N / NSRC, nloc = N % NSRC;
    int wh = nloc / 28, ww = nloc % 28;
    const float* __restrict__ V = src ? v1 : v0;
    int t = threadIdx.x;
    int tm = t >> 4, tn = t & 15;
    int pbase = (b * 224 + wh * 8) * 224 + ww * 8;
    float acc[4][4] = {};
    for (int d0 = 0; d0 < DVC; d0 += 64) {
        __syncthreads();
#pragma unroll
        for (int i = 0; i < 16; ++i) {
            int flat = i * 256 + t;
            int r = flat >> 6, c = flat & 63;
            Pix[r][c] = V[(pbase + (r >> 3) * 224 + (r & 7)) * DVC + d0 + c];
            WvB[r][c] = Wv[(d0 + r) * DCC + c];
        }
        __syncthreads();
#pragma unroll 8
        for (int dd = 0; dd < 64; ++dd) {
            float4 b4 = *(const float4*)&WvB[dd][4 * tn];
            float a0 = Pix[4 * tm + 0][dd];
            float a1 = Pix[4 * tm + 1][dd];
            float a2 = Pix[4 * tm + 2][dd];
            float a3 = Pix[4 * tm + 3][dd];
            acc[0][0] += a0 * b4.x; acc[0][1] += a0 * b4.y; acc[0][2] += a0 * b4.z; acc[0][3] += a0 * b4.w;
            acc[1][0] += a1 * b4.x; acc[1][1] += a1 * b4.y; acc[1][2] += a1 * b4.z; acc[1][3] += a1 * b4.w;
            acc[2][0] += a2 * b4.x; acc[2][1] += a2 * b4.y; acc[2][2] += a2 * b4.z; acc[2][3] += a2 * b4.w;
            acc[3][0] += a3 * b4.x; acc[3][1] += a3 * b4.y; acc[3][2] += a3 * b4.z; acc[3][3] += a3 * b4.w;
        }
    }
#pragma unroll
    for (int i = 0; i < 4; ++i)
#pragma unroll
        for (int j = 0; j < 4; ++j) {
            int p = 4 * tm + i, e = 4 * tn + j;
            // Vv[b][h=e&7][N][p*8 + (e>>3)] = acc
            Vv[((b * NHD + (e & 7)) * NTOT + N) * FDIM + p * 8 + (e >> 3)] = acc[i][j];
        }
}

// ---------------------------------------------------------------------------
// K4: flash attention per (bh, 32-query tile). Two-phase softmax, then PV
// with 8q x 8f register tiles against 32x512 LDS V tiles.
__global__ __launch_bounds__(256) void k4_attn(
    const float* __restrict__ q20, const float* __restrict__ k20,
    const float* __restrict__ Vvg, float* __restrict__ rw) {
    __shared__ float qL[32][D20];
    __shared__ float VvL[32][FDIM];
    __shared__ float PL[32][32];
    __shared__ float mbuf[8][32];
    __shared__ float lbuf[8][32];
    __shared__ float mS[32];
    __shared__ float liS[32];
    int qt = blockIdx.x, bh = blockIdx.y;
    int q0 = qt * 32;
    int t = threadIdx.x;
    const float* __restrict__ qb = q20 + (bh * NTOT + q0) * D20;
    const float* __restrict__ kb = k20 + bh * NTOT * D20;
    const float* __restrict__ Vvb = Vvg + bh * NTOT * FDIM;
    for (int i = t; i < 32 * D20; i += 256) qL[i / D20][i % D20] = qb[i];
    __syncthreads();

    int q = t & 31, rep = t >> 5;
    float4 q4[5];
#pragma unroll
    for (int i = 0; i < 5; ++i) q4[i] = *(const float4*)&qL[q][4 * i];

    // phase 1: online max/sumexp, 8 threads per query row
    float m = -1e30f, l = 0.f;
    for (int i = 0; i < NTOT / 8; ++i) {
        int k = rep + 8 * i;
        float s = dot20(q4, kb + k * D20);
        if (s <= m) {
            l += __expf(s - m);
        } else {
            l = l * __expf(m - s) + 1.f;
            m = s;
        }
    }
    mbuf[rep][q] = m; lbuf[rep][q] = l;
    __syncthreads();
    if (t < 32) {
        float M = -1e30f;
#pragma unroll
        for (int r = 0; r < 8; ++r) M = fmaxf(M, mbuf[r][t]);
        float L = 0.f;
#pragma unroll
        for (int r = 0; r < 8; ++r) L += lbuf[r][t] * __expf(mbuf[r][t] - M);
        mS[t] = M;
        liS[t] = 1.f / L;
    }
    __syncthreads();

    // phase 2: PV. wave qg owns queries qg*8..+7; lane fg owns features
    // {4fg..4fg+3} and {256+4fg..+3}
    int qg = t >> 6, fg = t & 63;
    float acc0[8][4] = {};
    float acc1[8][4] = {};
    float myM = mS[q], myLi = liS[q];
    for (int kt = 0; kt < NTOT / 32; ++kt) {
        int k0 = kt * 32;
#pragma unroll
        for (int i = 0; i < 16; ++i) {
            int fi = (i * 256 + t) * 4;
            int row = fi >> 9, col = fi & 511;
            *(float4*)&VvL[row][col] = *(const float4*)&Vvb[(k0 + row) * FDIM + col];
        }
#pragma unroll
        for (int j = 0; j < 4; ++j) {
            int kk = j * 8 + rep;
            float s = dot20(q4, kb + (k0 + kk) * D20);
            PL[kk][q] = __expf(s - myM) * myLi;
        }
        __syncthreads();
#pragma unroll 2
        for (int kk = 0; kk < 32; ++kk) {
            float4 pa = *(const float4*)&PL[kk][qg * 8];
            float4 pb = *(const float4*)&PL[kk][qg * 8 + 4];
            float4 va = *(const float4*)&VvL[kk][4 * fg];
            float4 vb = *(const float4*)&VvL[kk][256 + 4 * fg];
            float pr[8] = {pa.x, pa.y, pa.z, pa.w, pb.x, pb.y, pb.z, pb.w};
            float v0r[4] = {va.x, va.y, va.z, va.w};
            float v1r[4] = {vb.x, vb.y, vb.z, vb.w};
#pragma unroll
            for (int qi = 0; qi < 8; ++qi) {
#pragma unroll
                for (int fj = 0; fj < 4; ++fj) {
                    acc0[qi][fj] += pr[qi] * v0r[fj];
                    acc1[qi][fj] += pr[qi] * v1r[fj];
                }
            }
        }
        __syncthreads();
    }
#pragma unroll
    for (int qi = 0; qi < 8; ++qi) {
        int row = (bh * NTOT + q0 + qg * 8 + qi) * FDIM;
        *(float4*)&rw[row + 4 * fg] =
            make_float4(acc0[qi][0], acc0[qi][1], acc0[qi][2], acc0[qi][3]);
        *(float4*)&rw[row + 256 + 4 * fg] =
            make_float4(acc1[qi][0], acc1[qi][1], acc1[qi][2], acc1[qi][3]);
    }
}

// ---------------------------------------------------------------------------
// K5: gather rw into (n, e*8+h) layout, multiply by Wback, unwindow-scatter
__global__ __launch_bounds__(256) void k5_back(
    const float* __restrict__ rw, const float* __restrict__ Wb,
    float* __restrict__ out) {
    __shared__ float rwL[64][68];   // [n][f2], padded to 68 (16B-aligned rows)
    int blk = blockIdx.x;
    int b = blk / NTOT, N = blk % NTOT;
    int src = N / NSRC, nloc = N % NSRC;
    int wh = nloc / 28, ww = nloc % 28;
    int t = threadIdx.x;
    float w[64];                    // Wback column t in registers
#pragma unroll
    for (int j = 0; j < 64; ++j) w[j] = Wb[j * DVC + t];
#pragma unroll
    for (int i = 0; i < 16; ++i) {
        int flat = i * 256 + t;
        int h = flat >> 9, f = flat & 511;
        rwL[f >> 3][(f & 7) * 8 + h] = rw[((b * NHD + h) * NTOT + N) * FDIM + f];
    }
    __syncthreads();
    float* __restrict__ op = out + src * OUT_PER_SRC
                           + ((b * 224 + wh * 8) * 224 + ww * 8) * DVC;
#pragma unroll 2
    for (int n = 0; n < 64; ++n) {
        const float4* r4 = (const float4*)&rwL[n][0];
        float s = 0.f;
#pragma unroll
        for (int i = 0; i < 16; ++i) {
            float4 r = r4[i];
            s += r.x * w[4 * i] + r.y * w[4 * i + 1] + r.z * w[4 * i + 2] + r.w * w[4 * i + 3];
        }
        op[((n >> 3) * 224 + (n & 7)) * DVC + t] = s;
    }
}

// ---------------------------------------------------------------------------
extern "C" void kernel_launch(void* const* d_in, const int* in_sizes, int n_in,
                              void* d_out, int out_size, void* d_ws, size_t ws_size,
                              hipStream_t stream) {
    const float* v0   = (const float*)d_in[0];
    const float* c0   = (const float*)d_in[1];
    const float* v1   = (const float*)d_in[2];
    const float* c1   = (const float*)d_in[3];
    const float* Wqkv = (const float*)d_in[4];
    const float* bqkv = (const float*)d_in[5];
    const float* gv   = (const float*)d_in[6];
    const float* Wqkc = (const float*)d_in[7];
    const float* bqkc = (const float*)d_in[8];
    const float* gc   = (const float*)d_in[9];
    const float* Wv   = (const float*)d_in[10];
    const float* Wbk  = (const float*)d_in[11];

    float* ws   = (float*)d_ws;
    float* Vavg = ws;                       // 2*1568*256   =   802,816
    float* Cavg = Vavg + 802816;            // 2*1568*64    =   200,704
    float* q20  = Cavg + 200704;            // 16*1568*20   =   501,760
    float* k20  = q20  + 501760;            //                  501,760
    float* Vv   = k20  + 501760;            // 16*1568*512  = 12,845,056
    float* rw   = Vv   + 12845056;          //               12,845,056
    // total: 27,697,152 floats = 110.8 MB of d_ws

    float* outp = (float*)d_out;

    k1_avg <<<2 * NTOT, 256, 0, stream>>>(v0, c0, v1, c1, Vavg, Cavg);
    k2_qk  <<<2 * NTOT, 256, 0, stream>>>(Vavg, Cavg, Wqkv, bqkv, gv, Wqkc, bqkc, gc, q20, k20);
    k3_vv  <<<2 * NTOT, 256, 0, stream>>>(v0, v1, Wv, Vv);
    k4_attn<<<dim3(NTOT / 32, 16), 256, 0, stream>>>(q20, k20, Vv, rw);
    k5_back<<<2 * NTOT, 256, 0, stream>>>(rw, Wbk, outp);
}

// Round 2
// 1103.951 us; speedup vs baseline: 1.1062x; 1.1062x over previous
//
#include <hip/hip_runtime.h>

#define NSRC 784
#define NTOT 1568
#define NHD 8
#define DVC 256
#define DCC 64
#define D20 20
#define FDIM 512
#define OUT_PER_SRC 25690112

typedef short s16x8 __attribute__((ext_vector_type(8)));
typedef unsigned short u16x8 __attribute__((ext_vector_type(8)));
typedef float f32x4 __attribute__((ext_vector_type(4)));

__device__ __forceinline__ unsigned short f2bf(float x) {
    unsigned u = __float_as_uint(x);
    unsigned r = (u + 0x7FFFu + ((u >> 16) & 1u)) >> 16;   // RNE
    return (unsigned short)r;
}

// identical score dot in phase1/phase2 so softmax stats are consistent
__device__ __forceinline__ float dot20(const float4* q4, const float* kr) {
    const float4* k4 = (const float4*)kr;
    float s = 0.f;
#pragma unroll
    for (int i = 0; i < 5; ++i) {
        float4 a = q4[i], b = k4[i];
        s += a.x * b.x; s += a.y * b.y; s += a.z * b.z; s += a.w * b.w;
    }
    return s;
}

// ---------------------------------------------------------------------------
// K1: window average of values (256d) and coords (64d)
__global__ __launch_bounds__(256) void k1_avg(
    const float* __restrict__ v0, const float* __restrict__ c0,
    const float* __restrict__ v1, const float* __restrict__ c1,
    float* __restrict__ Vavg, float* __restrict__ Cavg) {
    int blk = blockIdx.x;
    int b = blk / NTOT, N = blk % NTOT;
    int src = N / NSRC, nloc = N % NSRC;
    int wh = nloc / 28, ww = nloc % 28;
    const float* __restrict__ V = src ? v1 : v0;
    const float* __restrict__ C = src ? c1 : c0;
    int t = threadIdx.x;
    int pbase = (b * 224 + wh * 8) * 224 + ww * 8;
    float s = 0.f;
#pragma unroll 8
    for (int p = 0; p < 64; ++p)
        s += V[(size_t)(pbase + (p >> 3) * 224 + (p & 7)) * DVC + t];
    Vavg[(size_t)blk * DVC + t] = s * 0.015625f;
    if (t < DCC) {
        float sc = 0.f;
#pragma unroll 8
        for (int p = 0; p < 64; ++p)
            sc += C[(size_t)(pbase + (p >> 3) * 224 + (p & 7)) * DCC + t];
        Cavg[(size_t)blk * DCC + t] = sc * 0.015625f;
    }
}

// ---------------------------------------------------------------------------
// K2: qk = rmsnorm(avg @ Wqk + b, g); split heads into packed 20-dim q/k rows
__global__ __launch_bounds__(256) void k2_qk(
    const float* __restrict__ Vavg, const float* __restrict__ Cavg,
    const float* __restrict__ Wqkv, const float* __restrict__ bqkv, const float* __restrict__ gv,
    const float* __restrict__ Wqkc, const float* __restrict__ bqkc, const float* __restrict__ gc,
    float* __restrict__ q20, float* __restrict__ k20) {
    __shared__ float xv[DVC];
    __shared__ float xc[DCC];
    __shared__ float wred[4];
    int blk = blockIdx.x;
    int b = blk / NTOT, N = blk % NTOT;
    int t = threadIdx.x;
    xv[t] = Vavg[(size_t)blk * DVC + t];
    if (t < DCC) xc[t] = Cavg[(size_t)blk * DCC + t];
    __syncthreads();
    float yv = bqkv[t];
#pragma unroll 4
    for (int d = 0; d < DVC; ++d) yv += xv[d] * Wqkv[d * 256 + t];
    float ss = yv * yv;
#pragma unroll
    for (int off = 32; off; off >>= 1) ss += __shfl_xor(ss, off, 64);
    if ((t & 63) == 0) wred[t >> 6] = ss;
    __syncthreads();
    float tot = wred[0] + wred[1] + wred[2] + wred[3];
    float rv = rsqrtf(tot * (1.f / 256.f) + 1e-6f);
    float yn = yv * rv * gv[t];
    int h = t >> 5, c = t & 31;
    int bh = b * NHD + h;
    if (c < 16) q20[((size_t)bh * NTOT + N) * D20 + c] = yn * 0.088388347648318447f;
    else        k20[((size_t)bh * NTOT + N) * D20 + (c - 16)] = yn;
    if (t < DCC) {
        float yc = bqkc[t];
#pragma unroll 4
        for (int d = 0; d < DCC; ++d) yc += xc[d] * Wqkc[d * 64 + t];
        float sc = yc * yc;
#pragma unroll
        for (int off = 32; off; off >>= 1) sc += __shfl_xor(sc, off, 64);
        float rc = rsqrtf(sc * (1.f / 64.f) + 1e-6f);
        float ycn = yc * rc * gc[t];
        int h2 = t >> 3, c2 = t & 7;
        int bh2 = b * NHD + h2;
        if (c2 < 4) q20[((size_t)bh2 * NTOT + N) * D20 + 16 + c2] = ycn * 0.17677669529663687f;
        else        k20[((size_t)bh2 * NTOT + N) * D20 + 16 + (c2 - 4)] = ycn;
    }
}

// ---------------------------------------------------------------------------
// K3: per-window GEMM (64 pixels x 256) @ Wv(256 x 64) -> Vv bf16 [bh][N][f]
__global__ __launch_bounds__(256) void k3_vv(
    const float* __restrict__ v0, const float* __restrict__ v1,
    const float* __restrict__ Wv, unsigned short* __restrict__ Vvb) {
    __shared__ float Pix[64][65];
    __shared__ float WvB[64][64];
    int blk = blockIdx.x;
    int b = blk / NTOT, N = blk % NTOT;
    int src = N / NSRC, nloc = N % NSRC;
    int wh = nloc / 28, ww = nloc % 28;
    const float* __restrict__ V = src ? v1 : v0;
    int t = threadIdx.x;
    int tm = t >> 4, tn = t & 15;
    int pbase = (b * 224 + wh * 8) * 224 + ww * 8;
    float acc[4][4] = {};
    for (int d0 = 0; d0 < DVC; d0 += 64) {
        __syncthreads();
#pragma unroll
        for (int i = 0; i < 16; ++i) {
            int flat = i * 256 + t;
            int r = flat >> 6, c = flat & 63;
            Pix[r][c] = V[(size_t)(pbase + (r >> 3) * 224 + (r & 7)) * DVC + d0 + c];
            WvB[r][c] = Wv[(d0 + r) * DCC + c];
        }
        __syncthreads();
#pragma unroll 8
        for (int dd = 0; dd < 64; ++dd) {
            float4 b4 = *(const float4*)&WvB[dd][4 * tn];
            float a0 = Pix[4 * tm + 0][dd];
            float a1 = Pix[4 * tm + 1][dd];
            float a2 = Pix[4 * tm + 2][dd];
            float a3 = Pix[4 * tm + 3][dd];
            acc[0][0] += a0 * b4.x; acc[0][1] += a0 * b4.y; acc[0][2] += a0 * b4.z; acc[0][3] += a0 * b4.w;
            acc[1][0] += a1 * b4.x; acc[1][1] += a1 * b4.y; acc[1][2] += a1 * b4.z; acc[1][3] += a1 * b4.w;
            acc[2][0] += a2 * b4.x; acc[2][1] += a2 * b4.y; acc[2][2] += a2 * b4.z; acc[2][3] += a2 * b4.w;
            acc[3][0] += a3 * b4.x; acc[3][1] += a3 * b4.y; acc[3][2] += a3 * b4.z; acc[3][3] += a3 * b4.w;
        }
    }
#pragma unroll
    for (int i = 0; i < 4; ++i)
#pragma unroll
        for (int j = 0; j < 4; ++j) {
            int p = 4 * tm + i, e = 4 * tn + j;
            Vvb[((size_t)(b * NHD + (e & 7)) * NTOT + N) * FDIM + p * 8 + (e >> 3)] = f2bf(acc[i][j]);
        }
}

// ---------------------------------------------------------------------------
// K3b: transpose Vv bf16 [bh][N][f] -> VvT bf16 [bh][f][N]
__global__ __launch_bounds__(256) void k3b_tr(
    const unsigned short* __restrict__ Vvb, unsigned short* __restrict__ VvT) {
    __shared__ unsigned short tile[32][136];   // +8 pad
    int n0 = blockIdx.x * 32;      // 49
    int f0 = blockIdx.y * 128;     // 4
    int bh = blockIdx.z;           // 16
    int t = threadIdx.x;
    const unsigned short* src = Vvb + ((size_t)bh * NTOT + n0) * FDIM + f0;
#pragma unroll
    for (int k2 = 0; k2 < 2; ++k2) {
        int i = t + 256 * k2;                  // 0..511
        int r = i >> 4, c8 = (i & 15) * 8;
        *(u16x8*)&tile[r][c8] = *(const u16x8*)&src[(size_t)r * FDIM + c8];
    }
    __syncthreads();
    unsigned short* dst = VvT + ((size_t)bh * FDIM + f0) * NTOT + n0;
#pragma unroll
    for (int k2 = 0; k2 < 2; ++k2) {
        int j = t + 256 * k2;                  // 0..511
        int fr = j >> 2, p8 = (j & 3) * 8;
        u16x8 v;
#pragma unroll
        for (int u = 0; u < 8; ++u) v[u] = tile[p8 + u][fr];
        *(u16x8*)&dst[(size_t)fr * NTOT + p8] = v;
    }
}

// ---------------------------------------------------------------------------
// K4: flash attention, MFMA PV. Block = (bh, 32-query tile), 4 waves.
__global__ __launch_bounds__(256) void k4_attn(
    const float* __restrict__ q20, const float* __restrict__ k20,
    const unsigned short* __restrict__ VvT, float* __restrict__ rw) {
    __shared__ float qL[32][D20];
    __shared__ short VB[512 * 40];             // [f][k] bf16, row stride 40 (80B)
    __shared__ short PAs[1024];                // A-frag layout [mt][kg][ql][jj]
    __shared__ float mbuf[8][32];
    __shared__ float lbuf[8][32];
    __shared__ float mS[32];
    __shared__ float liS[32];
    int qt = blockIdx.x, bh = blockIdx.y;
    int q0 = qt * 32;
    int t = threadIdx.x;
    const float* __restrict__ qb = q20 + ((size_t)bh * NTOT + q0) * D20;
    const float* __restrict__ kb = k20 + (size_t)bh * NTOT * D20;
    const unsigned short* __restrict__ Vt = VvT + (size_t)bh * FDIM * NTOT;
    for (int i = t; i < 32 * D20; i += 256) qL[i / D20][i % D20] = qb[i];
    __syncthreads();

    int q = t & 31, rep = t >> 5;
    float4 q4[5];
#pragma unroll
    for (int i = 0; i < 5; ++i) q4[i] = *(const float4*)&qL[q][4 * i];

    // phase 1: online max/sumexp, 8 threads per query row
    float m = -1e30f, l = 0.f;
    for (int i = 0; i < NTOT / 8; ++i) {
        int k = rep + 8 * i;
        float s = dot20(q4, kb + k * D20);
        if (s <= m) {
            l += __expf(s - m);
        } else {
            l = l * __expf(m - s) + 1.f;
            m = s;
        }
    }
    mbuf[rep][q] = m; lbuf[rep][q] = l;
    __syncthreads();
    if (t < 32) {
        float M = -1e30f;
#pragma unroll
        for (int r = 0; r < 8; ++r) M = fmaxf(M, mbuf[r][t]);
        float L = 0.f;
#pragma unroll
        for (int r = 0; r < 8; ++r) L += lbuf[r][t] * __expf(mbuf[r][t] - M);
        mS[t] = M;
        liS[t] = 1.f / L;
    }
    __syncthreads();
    float myM = mS[q], myLi = liS[q];

    // phase 2: MFMA PV. wave w owns 128 features; both 16-query subtiles.
    int w = t >> 6, lane = t & 63;
    int lm = lane & 15, lk = lane >> 4;
    f32x4 acc0[8], acc1[8];
#pragma unroll
    for (int i = 0; i < 8; ++i) { acc0[i] = (f32x4)0.f; acc1[i] = (f32x4)0.f; }

    for (int kt = 0; kt < NTOT / 32; ++kt) {
        int k0 = kt * 32;
        // stage V tile: VB[f][k] <- VvT[bh][f][k0+k], 8x 16B per thread
#pragma unroll
        for (int i = 0; i < 8; ++i) {
            int c = t + 256 * i;               // 0..2047
            int f = c >> 2, part = (c & 3) * 8;
            *(u16x8*)&VB[f * 40 + part] =
                *(const u16x8*)&Vt[(size_t)f * NTOT + k0 + part];
        }
        // compute P (fp32 scores identical to phase 1), store bf16 A-frags
#pragma unroll
        for (int j = 0; j < 4; ++j) {
            int kk = j * 8 + rep;
            float s = dot20(q4, kb + (size_t)(k0 + kk) * D20);
            float p = __expf(s - myM) * myLi;
            PAs[(((q >> 4) * 4 + (kk >> 3)) * 16 + (q & 15)) * 8 + (kk & 7)] = (short)f2bf(p);
        }
        __syncthreads();
        // MFMA: D[32q][128f per wave] += P(32x32) * V(32x128)
        s16x8 a0 = *(const s16x8*)&PAs[((0 + lk) * 16 + lm) * 8];
        s16x8 a1 = *(const s16x8*)&PAs[((4 + lk) * 16 + lm) * 8];
#pragma unroll
        for (int nt = 0; nt < 8; ++nt) {
            int f = w * 128 + nt * 16 + lm;
            s16x8 bfr = *(const s16x8*)&VB[f * 40 + lk * 8];
            acc0[nt] = __builtin_amdgcn_mfma_f32_16x16x32_bf16(a0, bfr, acc0[nt], 0, 0, 0);
            acc1[nt] = __builtin_amdgcn_mfma_f32_16x16x32_bf16(a1, bfr, acc1[nt], 0, 0, 0);
        }
        __syncthreads();
    }
    // epilogue: rw[bh][q0+m][f]
#pragma unroll
    for (int nt = 0; nt < 8; ++nt) {
        int f = w * 128 + nt * 16 + lm;
#pragma unroll
        for (int r = 0; r < 4; ++r) {
            rw[((size_t)bh * NTOT + q0 + 0  + lk * 4 + r) * FDIM + f] = acc0[nt][r];
            rw[((size_t)bh * NTOT + q0 + 16 + lk * 4 + r) * FDIM + f] = acc1[nt][r];
        }
    }
}

// ---------------------------------------------------------------------------
// K5: gather rw into (n, e*8+h) layout, multiply by Wback, unwindow-scatter
__global__ __launch_bounds__(256) void k5_back(
    const float* __restrict__ rw, const float* __restrict__ Wb,
    float* __restrict__ out) {
    __shared__ float rwL[64][68];
    int blk = blockIdx.x;
    int b = blk / NTOT, N = blk % NTOT;
    int src = N / NSRC, nloc = N % NSRC;
    int wh = nloc / 28, ww = nloc % 28;
    int t = threadIdx.x;
    float w[64];
#pragma unroll
    for (int j = 0; j < 64; ++j) w[j] = Wb[j * DVC + t];
#pragma unroll
    for (int i = 0; i < 16; ++i) {
        int flat = i * 256 + t;
        int h = flat >> 9, f = flat & 511;
        rwL[f >> 3][(f & 7) * 8 + h] = rw[((size_t)(b * NHD + h) * NTOT + N) * FDIM + f];
    }
    __syncthreads();
    float* __restrict__ op = out + (size_t)src * OUT_PER_SRC
                           + (size_t)((b * 224 + wh * 8) * 224 + ww * 8) * DVC;
#pragma unroll 2
    for (int n = 0; n < 64; ++n) {
        const float4* r4 = (const float4*)&rwL[n][0];
        float s = 0.f;
#pragma unroll
        for (int i = 0; i < 16; ++i) {
            float4 r = r4[i];
            s += r.x * w[4 * i] + r.y * w[4 * i + 1] + r.z * w[4 * i + 2] + r.w * w[4 * i + 3];
        }
        op[((n >> 3) * 224 + (n & 7)) * DVC + t] = s;
    }
}

// ---------------------------------------------------------------------------
extern "C" void kernel_launch(void* const* d_in, const int* in_sizes, int n_in,
                              void* d_out, int out_size, void* d_ws, size_t ws_size,
                              hipStream_t stream) {
    const float* v0   = (const float*)d_in[0];
    const float* c0   = (const float*)d_in[1];
    const float* v1   = (const float*)d_in[2];
    const float* c1   = (const float*)d_in[3];
    const float* Wqkv = (const float*)d_in[4];
    const float* bqkv = (const float*)d_in[5];
    const float* gv   = (const float*)d_in[6];
    const float* Wqkc = (const float*)d_in[7];
    const float* bqkc = (const float*)d_in[8];
    const float* gc   = (const float*)d_in[9];
    const float* Wv   = (const float*)d_in[10];
    const float* Wbk  = (const float*)d_in[11];

    float* ws   = (float*)d_ws;
    float* Vavg = ws;                               // 802,816 floats
    float* Cavg = Vavg + 802816;                    // 200,704
    float* q20  = Cavg + 200704;                    // 501,760
    float* k20  = q20  + 501760;                    // 501,760
    unsigned short* Vvb = (unsigned short*)(k20 + 501760);   // 12,845,056 bf16
    unsigned short* VvT = Vvb + 12845056;                    // 12,845,056 bf16
    float* rw   = (float*)(VvT + 12845056);         // 12,845,056 floats
    // total: 27,697,152 floats = 110.8 MB

    float* outp = (float*)d_out;

    k1_avg <<<2 * NTOT, 256, 0, stream>>>(v0, c0, v1, c1, Vavg, Cavg);
    k2_qk  <<<2 * NTOT, 256, 0, stream>>>(Vavg, Cavg, Wqkv, bqkv, gv, Wqkc, bqkc, gc, q20, k20);
    k3_vv  <<<2 * NTOT, 256, 0, stream>>>(v0, v1, Wv, Vvb);
    k3b_tr <<<dim3(49, 4, 16), 256, 0, stream>>>(Vvb, VvT);
    k4_attn<<<dim3(NTOT / 32, 16), 256, 0, stream>>>(q20, k20, VvT, rw);
    k5_back<<<2 * NTOT, 256, 0, stream>>>(rw, Wbk, outp);
}

// Round 3
// 927.939 us; speedup vs baseline: 1.3160x; 1.1897x over previous
//
#include <hip/hip_runtime.h>

#define NSRC 784
#define NTOT 1568
#define NHD 8
#define DVC 256
#define DCC 64
#define D20 20
#define FDIM 512
#define OUT_PER_SRC 25690112

typedef short s16x8 __attribute__((ext_vector_type(8)));
typedef unsigned short u16x8 __attribute__((ext_vector_type(8)));
typedef unsigned short u16x4 __attribute__((ext_vector_type(4)));
typedef float f32x4 __attribute__((ext_vector_type(4)));
typedef float f32x16 __attribute__((ext_vector_type(16)));
typedef unsigned u32x4 __attribute__((ext_vector_type(4)));

__device__ __forceinline__ unsigned short f2bf(float x) {
    unsigned u = __float_as_uint(x);
    unsigned r = (u + 0x7FFFu + ((u >> 16) & 1u)) >> 16;   // RNE
    return (unsigned short)r;
}

__device__ __forceinline__ unsigned cvt_pk_bf16(float lo, float hi) {
    unsigned r;
    asm volatile("v_cvt_pk_bf16_f32 %0, %1, %2" : "=v"(r) : "v"(lo), "v"(hi));
    return r;
}

// split float into bf16 hi + bf16 lo correction
__device__ __forceinline__ void split_bf(float x, unsigned short& hi, unsigned short& lo) {
    unsigned short h = f2bf(x);
    float hf = __uint_as_float(((unsigned)h) << 16);
    hi = h;
    lo = f2bf(x - hf);
}

// ---------------------------------------------------------------------------
// K1c: window average of coords only (V-average fused into K3)
__global__ __launch_bounds__(256) void k1c_avg(
    const float* __restrict__ c0, const float* __restrict__ c1,
    float* __restrict__ Cavg) {
    int wi = blockIdx.x * 4 + (threadIdx.x >> 6);     // 0..3135
    int d = threadIdx.x & 63;
    int b = wi / NTOT, N = wi % NTOT;
    int src = N / NSRC, nloc = N % NSRC;
    int wh = nloc / 28, ww = nloc % 28;
    const float* __restrict__ C = src ? c1 : c0;
    int pbase = (b * 224 + wh * 8) * 224 + ww * 8;
    float s = 0.f;
#pragma unroll 8
    for (int p = 0; p < 64; ++p)
        s += C[(size_t)(pbase + (p >> 3) * 224 + (p & 7)) * DCC + d];
    Cavg[(size_t)wi * DCC + d] = s * 0.015625f;
}

// ---------------------------------------------------------------------------
// K2: qk = rmsnorm(avg @ Wqk + b, g); split heads into packed 20-dim q/k rows
__global__ __launch_bounds__(256) void k2_qk(
    const float* __restrict__ Vavg, const float* __restrict__ Cavg,
    const float* __restrict__ Wqkv, const float* __restrict__ bqkv, const float* __restrict__ gv,
    const float* __restrict__ Wqkc, const float* __restrict__ bqkc, const float* __restrict__ gc,
    float* __restrict__ q20, float* __restrict__ k20) {
    __shared__ float xv[DVC];
    __shared__ float xc[DCC];
    __shared__ float wred[4];
    int blk = blockIdx.x;
    int b = blk / NTOT, N = blk % NTOT;
    int t = threadIdx.x;
    xv[t] = Vavg[(size_t)blk * DVC + t];
    if (t < DCC) xc[t] = Cavg[(size_t)blk * DCC + t];
    __syncthreads();
    float yv = bqkv[t];
#pragma unroll 4
    for (int d = 0; d < DVC; ++d) yv += xv[d] * Wqkv[d * 256 + t];
    float ss = yv * yv;
#pragma unroll
    for (int off = 32; off; off >>= 1) ss += __shfl_xor(ss, off, 64);
    if ((t & 63) == 0) wred[t >> 6] = ss;
    __syncthreads();
    float tot = wred[0] + wred[1] + wred[2] + wred[3];
    float rv = rsqrtf(tot * (1.f / 256.f) + 1e-6f);
    float yn = yv * rv * gv[t];
    int h = t >> 5, c = t & 31;
    int bh = b * NHD + h;
    if (c < 16) q20[((size_t)bh * NTOT + N) * D20 + c] = yn * 0.088388347648318447f;
    else        k20[((size_t)bh * NTOT + N) * D20 + (c - 16)] = yn;
    if (t < DCC) {
        float yc = bqkc[t];
#pragma unroll 4
        for (int d = 0; d < DCC; ++d) yc += xc[d] * Wqkc[d * 64 + t];
        float sc = yc * yc;
#pragma unroll
        for (int off = 32; off; off >>= 1) sc += __shfl_xor(sc, off, 64);
        float rc = rsqrtf(sc * (1.f / 64.f) + 1e-6f);
        float ycn = yc * rc * gc[t];
        int h2 = t >> 3, c2 = t & 7;
        int bh2 = b * NHD + h2;
        if (c2 < 4) q20[((size_t)bh2 * NTOT + N) * D20 + 16 + c2] = ycn * 0.17677669529663687f;
        else        k20[((size_t)bh2 * NTOT + N) * D20 + 16 + (c2 - 4)] = ycn;
    }
}

// ---------------------------------------------------------------------------
// K3: per-window GEMM (64 px x 256) @ Wv(256x64) -> Vv bf16 [bh][N][f]
//     + fused window-average of V (feeds K2)
__global__ __launch_bounds__(256) void k3_vv(
    const float* __restrict__ v0, const float* __restrict__ v1,
    const float* __restrict__ Wv, unsigned short* __restrict__ Vvb,
    float* __restrict__ Vavg) {
    __shared__ float Pix[64][65];
    __shared__ float WvB[64][64];
    int blk = blockIdx.x;
    int b = blk / NTOT, N = blk % NTOT;
    int src = N / NSRC, nloc = N % NSRC;
    int wh = nloc / 28, ww = nloc % 28;
    const float* __restrict__ V = src ? v1 : v0;
    int t = threadIdx.x;
    int tm = t >> 4, tn = t & 15;
    int pbase = (b * 224 + wh * 8) * 224 + ww * 8;
    float acc[4][4] = {};
    for (int d0 = 0; d0 < DVC; d0 += 64) {
        __syncthreads();
#pragma unroll
        for (int i = 0; i < 16; ++i) {
            int flat = i * 256 + t;
            int r = flat >> 6, c = flat & 63;
            Pix[r][c] = V[(size_t)(pbase + (r >> 3) * 224 + (r & 7)) * DVC + d0 + c];
            WvB[r][c] = Wv[(d0 + r) * DCC + c];
        }
        __syncthreads();
        if (t < 64) {           // fused V window-average for column d0+t
            float s = 0.f;
#pragma unroll 8
            for (int p = 0; p < 64; ++p) s += Pix[p][t];
            Vavg[(size_t)blk * DVC + d0 + t] = s * 0.015625f;
        }
#pragma unroll 8
        for (int dd = 0; dd < 64; ++dd) {
            float4 b4 = *(const float4*)&WvB[dd][4 * tn];
            float a0 = Pix[4 * tm + 0][dd];
            float a1 = Pix[4 * tm + 1][dd];
            float a2 = Pix[4 * tm + 2][dd];
            float a3 = Pix[4 * tm + 3][dd];
            acc[0][0] += a0 * b4.x; acc[0][1] += a0 * b4.y; acc[0][2] += a0 * b4.z; acc[0][3] += a0 * b4.w;
            acc[1][0] += a1 * b4.x; acc[1][1] += a1 * b4.y; acc[1][2] += a1 * b4.z; acc[1][3] += a1 * b4.w;
            acc[2][0] += a2 * b4.x; acc[2][1] += a2 * b4.y; acc[2][2] += a2 * b4.z; acc[2][3] += a2 * b4.w;
            acc[3][0] += a3 * b4.x; acc[3][1] += a3 * b4.y; acc[3][2] += a3 * b4.z; acc[3][3] += a3 * b4.w;
        }
    }
#pragma unroll
    for (int i = 0; i < 4; ++i)
#pragma unroll
        for (int j = 0; j < 4; ++j) {
            int p = 4 * tm + i, e = 4 * tn + j;
            Vvb[((size_t)(b * NHD + (e & 7)) * NTOT + N) * FDIM + p * 8 + (e >> 3)] = f2bf(acc[i][j]);
        }
}

// ---------------------------------------------------------------------------
// K3b: transpose Vv bf16 [bh][N][f] -> VvT bf16 [bh][f][N]
__global__ __launch_bounds__(256) void k3b_tr(
    const unsigned short* __restrict__ Vvb, unsigned short* __restrict__ VvT) {
    __shared__ unsigned short tile[32][136];
    int n0 = blockIdx.x * 32;
    int f0 = blockIdx.y * 128;
    int bh = blockIdx.z;
    int t = threadIdx.x;
    const unsigned short* src = Vvb + ((size_t)bh * NTOT + n0) * FDIM + f0;
#pragma unroll
    for (int k2 = 0; k2 < 2; ++k2) {
        int i = t + 256 * k2;
        int r = i >> 4, c8 = (i & 15) * 8;
        *(u16x8*)&tile[r][c8] = *(const u16x8*)&src[(size_t)r * FDIM + c8];
    }
    __syncthreads();
    unsigned short* dst = VvT + ((size_t)bh * FDIM + f0) * NTOT + n0;
#pragma unroll
    for (int k2 = 0; k2 < 2; ++k2) {
        int j = t + 256 * k2;
        int fr = j >> 2, p8 = (j & 3) * 8;
        u16x8 v;
#pragma unroll
        for (int u = 0; u < 8; ++u) v[u] = tile[p8 + u][fr];
        *(u16x8*)&dst[(size_t)fr * NTOT + p8] = v;
    }
}

// ---------------------------------------------------------------------------
// K4: single-pass flash attention, all-MFMA.
// Per block: 32 queries x all 1568 keys, 4 waves, grid 1-D (qt*16+bh) so
// each XCD keeps 2 bh's V slice L2-resident.
// S^T = K @ Q^T via 3-term bf16 hi/lo split (fp32-grade scores).
// Online softmax per-lane (lane = q column), defer-max THR=8.
// PV: O^T = V^T @ P^T, P fed from registers (cvt_pk + shfl half-swap).
__global__ __launch_bounds__(256) void k4_attn(
    const float* __restrict__ q20, const float* __restrict__ k20,
    const unsigned short* __restrict__ VvT, float* __restrict__ rw) {
    __shared__ short VB[512 * 40];        // V^T tile [f][k], stride 40 (80B)
    __shared__ short KThi[32 * 40];       // K tile hi [k][d], d padded to 32
    __shared__ short KTlo[32 * 40];
    __shared__ short QThi[32 * 40];       // Q tile hi [q][d]
    __shared__ short QTlo[32 * 40];

    int wg = blockIdx.x;
    int qt = wg >> 4, bh = wg & 15;       // wg&7 == bh&7 -> XCD affinity per bh
    int q0 = qt * 32;
    int t = threadIdx.x;
    int w = t >> 6, lane = t & 63;
    int l31 = lane & 31, hh = lane >> 5;

    const float* __restrict__ qb = q20 + ((size_t)bh * NTOT + q0) * D20;
    const float* __restrict__ kb = k20 + (size_t)bh * NTOT * D20;
    const unsigned short* __restrict__ Vt = VvT + (size_t)bh * FDIM * NTOT;

    // zero the d=20..39 pad columns of all four k/q tiles
    for (int i = t; i < 32 * 20; i += 256) {
        int r = i / 20, c = 20 + i % 20;
        KThi[r * 40 + c] = 0; KTlo[r * 40 + c] = 0;
        QThi[r * 40 + c] = 0; QTlo[r * 40 + c] = 0;
    }
    // stage Q tile (hi/lo split), rows = local q
    if (t < 160) {
        int row = t / 5, d4 = (t % 5) * 4;
        float4 v = *(const float4*)&qb[row * D20 + d4];
        u16x4 hi, lo;
        unsigned short a, b2;
        split_bf(v.x, a, b2); hi[0] = a; lo[0] = b2;
        split_bf(v.y, a, b2); hi[1] = a; lo[1] = b2;
        split_bf(v.z, a, b2); hi[2] = a; lo[2] = b2;
        split_bf(v.w, a, b2); hi[3] = a; lo[3] = b2;
        *(u16x4*)&QThi[row * 40 + d4] = hi;
        *(u16x4*)&QTlo[row * 40 + d4] = lo;
    }
    __syncthreads();

    float m = -1e30f, lsum = 0.f;
    f32x4 dummy;
    f32x16 acc[4];
#pragma unroll
    for (int s = 0; s < 4; ++s) acc[s] = (f32x16)0.f;

    for (int kt = 0; kt < NTOT / 32; ++kt) {
        int k0 = kt * 32;
        __syncthreads();   // previous tile's LDS reads complete
        // ---- stage V^T tile (32 keys x 512 f, bf16) ----
#pragma unroll
        for (int i = 0; i < 8; ++i) {
            int c = t + 256 * i;
            int f = c >> 2, part = (c & 3) * 8;
            *(u16x8*)&VB[f * 40 + part] =
                *(const u16x8*)&Vt[(size_t)f * NTOT + k0 + part];
        }
        // ---- stage K tile (hi/lo split) ----
        if (t < 160) {
            int row = t / 5, d4 = (t % 5) * 4;
            float4 v = *(const float4*)&kb[(size_t)(k0 + row) * D20 + d4];
            u16x4 hi, lo;
            unsigned short a, b2;
            split_bf(v.x, a, b2); hi[0] = a; lo[0] = b2;
            split_bf(v.y, a, b2); hi[1] = a; lo[1] = b2;
            split_bf(v.z, a, b2); hi[2] = a; lo[2] = b2;
            split_bf(v.w, a, b2); hi[3] = a; lo[3] = b2;
            *(u16x4*)&KThi[row * 40 + d4] = hi;
            *(u16x4*)&KTlo[row * 40 + d4] = lo;
        }
        __syncthreads();   // tiles ready

        // ---- S^T = K @ Q^T (32k x 32q), 3-term hi/lo split, d in 2 chunks ----
        s16x8 ka0 = *(const s16x8*)&KThi[l31 * 40 + hh * 8];
        s16x8 kl0 = *(const s16x8*)&KTlo[l31 * 40 + hh * 8];
        s16x8 qa0 = *(const s16x8*)&QThi[l31 * 40 + hh * 8];
        s16x8 ql0 = *(const s16x8*)&QTlo[l31 * 40 + hh * 8];
        s16x8 ka1 = *(const s16x8*)&KThi[l31 * 40 + 16 + hh * 8];
        s16x8 kl1 = *(const s16x8*)&KTlo[l31 * 40 + 16 + hh * 8];
        s16x8 qa1 = *(const s16x8*)&QThi[l31 * 40 + 16 + hh * 8];
        s16x8 ql1 = *(const s16x8*)&QTlo[l31 * 40 + 16 + hh * 8];
        f32x16 sacc = (f32x16)0.f;
        sacc = __builtin_amdgcn_mfma_f32_32x32x16_bf16(kl0, qa0, sacc, 0, 0, 0);
        sacc = __builtin_amdgcn_mfma_f32_32x32x16_bf16(ka0, ql0, sacc, 0, 0, 0);
        sacc = __builtin_amdgcn_mfma_f32_32x32x16_bf16(ka0, qa0, sacc, 0, 0, 0);
        sacc = __builtin_amdgcn_mfma_f32_32x32x16_bf16(kl1, qa1, sacc, 0, 0, 0);
        sacc = __builtin_amdgcn_mfma_f32_32x32x16_bf16(ka1, ql1, sacc, 0, 0, 0);
        sacc = __builtin_amdgcn_mfma_f32_32x32x16_bf16(ka1, qa1, sacc, 0, 0, 0);
        // lane holds S^T[k(r,hh)][q=l31], k(r,hh) = (r&3)+8*(r>>2)+4*hh

        // ---- online softmax stats (per-lane q column) ----
        float tmax = sacc[0];
#pragma unroll
        for (int r = 1; r < 16; ++r) tmax = fmaxf(tmax, sacc[r]);
        tmax = fmaxf(tmax, __shfl_xor(tmax, 32, 64));
        if (__any(tmax > m + 8.f)) {           // rescale (rare, defer-max)
            float mn = fmaxf(m, tmax);
            float sc = __expf(m - mn);
#pragma unroll
            for (int s = 0; s < 4; ++s) acc[s] = acc[s] * sc;
            lsum *= sc;
            m = mn;
        }
        // ---- P = exp(S - m), pack to bf16 pairs, half-swap ----
        unsigned P2[8];
        float tsum = 0.f;
#pragma unroll
        for (int j = 0; j < 8; ++j) {
            float pa = __expf(sacc[2 * j] - m);
            float pb = __expf(sacc[2 * j + 1] - m);
            tsum += pa + pb;
            P2[j] = cvt_pk_bf16(pa, pb);
        }
        lsum += tsum + __shfl_xor(tsum, 32, 64);
        unsigned X2[8];
#pragma unroll
        for (int j = 0; j < 8; ++j) X2[j] = (unsigned)__shfl_xor((int)P2[j], 32, 64);
        u32x4 b0u, b1u;
        if (hh == 0) {
            b0u[0] = P2[0]; b0u[1] = P2[1]; b0u[2] = X2[0]; b0u[3] = X2[1];
            b1u[0] = P2[4]; b1u[1] = P2[5]; b1u[2] = X2[4]; b1u[3] = X2[5];
        } else {
            b0u[0] = X2[2]; b0u[1] = X2[3]; b0u[2] = P2[2]; b0u[3] = P2[3];
            b1u[0] = X2[6]; b1u[1] = X2[7]; b1u[2] = P2[6]; b1u[3] = P2[7];
        }
        s16x8 pb0 = __builtin_bit_cast(s16x8, b0u);
        s16x8 pb1 = __builtin_bit_cast(s16x8, b1u);

        // ---- PV: O^T[f][q] += V^T[f][kd] P^T[kd][q], wave owns 128 f ----
#pragma unroll
        for (int sub = 0; sub < 4; ++sub) {
            int f = w * 128 + sub * 32 + l31;
            s16x8 va0 = *(const s16x8*)&VB[f * 40 + hh * 8];
            acc[sub] = __builtin_amdgcn_mfma_f32_32x32x16_bf16(va0, pb0, acc[sub], 0, 0, 0);
            s16x8 va1 = *(const s16x8*)&VB[f * 40 + 16 + hh * 8];
            acc[sub] = __builtin_amdgcn_mfma_f32_32x32x16_bf16(va1, pb1, acc[sub], 0, 0, 0);
        }
    }

    // ---- epilogue: normalize, LDS transpose (reuse VB), coalesced store ----
    float inv = 1.f / lsum;
    float* ebuf = (float*)VB;             // 32 x 260 f32 = 33280 B <= 40960
    float* rwg = rw + ((size_t)bh * NTOT + q0) * FDIM;
#pragma unroll
    for (int c = 0; c < 2; ++c) {
        __syncthreads();
        if ((w >> 1) == c) {
#pragma unroll
            for (int sub = 0; sub < 4; ++sub) {
                int fbase = w * 128 + sub * 32 - c * 256;
#pragma unroll
                for (int r = 0; r < 16; ++r) {
                    int fl = fbase + (r & 3) + 8 * (r >> 2) + 4 * hh;
                    ebuf[l31 * 260 + fl] = acc[sub][r] * inv;
                }
            }
        }
        __syncthreads();
        int qr = t >> 3, cc = t & 7;
#pragma unroll
        for (int j = 0; j < 8; ++j) {
            float4 v = *(const float4*)&ebuf[qr * 260 + cc * 32 + j * 4];
            *(float4*)&rwg[(size_t)qr * FDIM + c * 256 + cc * 32 + j * 4] = v;
        }
    }
}

// ---------------------------------------------------------------------------
// K5: gather rw into (n, e*8+h) layout, multiply by Wback, unwindow-scatter
__global__ __launch_bounds__(256) void k5_back(
    const float* __restrict__ rw, const float* __restrict__ Wb,
    float* __restrict__ out) {
    __shared__ float rwL[64][68];
    int blk = blockIdx.x;
    int b = blk / NTOT, N = blk % NTOT;
    int src = N / NSRC, nloc = N % NSRC;
    int wh = nloc / 28, ww = nloc % 28;
    int t = threadIdx.x;
    float w[64];
#pragma unroll
    for (int j = 0; j < 64; ++j) w[j] = Wb[j * DVC + t];
#pragma unroll
    for (int i = 0; i < 16; ++i) {
        int flat = i * 256 + t;
        int h = flat >> 9, f = flat & 511;
        rwL[f >> 3][(f & 7) * 8 + h] = rw[((size_t)(b * NHD + h) * NTOT + N) * FDIM + f];
    }
    __syncthreads();
    float* __restrict__ op = out + (size_t)src * OUT_PER_SRC
                           + (size_t)((b * 224 + wh * 8) * 224 + ww * 8) * DVC;
#pragma unroll 2
    for (int n = 0; n < 64; ++n) {
        const float4* r4 = (const float4*)&rwL[n][0];
        float s = 0.f;
#pragma unroll
        for (int i = 0; i < 16; ++i) {
            float4 r = r4[i];
            s += r.x * w[4 * i] + r.y * w[4 * i + 1] + r.z * w[4 * i + 2] + r.w * w[4 * i + 3];
        }
        op[((n >> 3) * 224 + (n & 7)) * DVC + t] = s;
    }
}

// ---------------------------------------------------------------------------
extern "C" void kernel_launch(void* const* d_in, const int* in_sizes, int n_in,
                              void* d_out, int out_size, void* d_ws, size_t ws_size,
                              hipStream_t stream) {
    const float* v0   = (const float*)d_in[0];
    const float* c0   = (const float*)d_in[1];
    const float* v1   = (const float*)d_in[2];
    const float* c1   = (const float*)d_in[3];
    const float* Wqkv = (const float*)d_in[4];
    const float* bqkv = (const float*)d_in[5];
    const float* gv   = (const float*)d_in[6];
    const float* Wqkc = (const float*)d_in[7];
    const float* bqkc = (const float*)d_in[8];
    const float* gc   = (const float*)d_in[9];
    const float* Wv   = (const float*)d_in[10];
    const float* Wbk  = (const float*)d_in[11];

    float* ws   = (float*)d_ws;
    float* Vavg = ws;                               // 802,816 floats
    float* Cavg = Vavg + 802816;                    // 200,704
    float* q20  = Cavg + 200704;                    // 501,760
    float* k20  = q20  + 501760;                    // 501,760
    unsigned short* Vvb = (unsigned short*)(k20 + 501760);   // 12,845,056 bf16
    unsigned short* VvT = Vvb + 12845056;                    // 12,845,056 bf16
    float* rw   = (float*)(VvT + 12845056);         // 12,845,056 floats

    float* outp = (float*)d_out;

    k3_vv  <<<2 * NTOT, 256, 0, stream>>>(v0, v1, Wv, Vvb, Vavg);
    k1c_avg<<<784, 256, 0, stream>>>(c0, c1, Cavg);
    k2_qk  <<<2 * NTOT, 256, 0, stream>>>(Vavg, Cavg, Wqkv, bqkv, gv, Wqkc, bqkc, gc, q20, k20);
    k3b_tr <<<dim3(49, 4, 16), 256, 0, stream>>>(Vvb, VvT);
    k4_attn<<<784, 256, 0, stream>>>(q20, k20, VvT, rw);
    k5_back<<<2 * NTOT, 256, 0, stream>>>(rw, Wbk, outp);
}

// Round 4
// 582.059 us; speedup vs baseline: 2.0980x; 1.5942x over previous
//
#include <hip/hip_runtime.h>

#define NSRC 784
#define NTOT 1568
#define NHD 8
#define DVC 256
#define DCC 64
#define D20 20
#define FDIM 512
#define OUT_PER_SRC 25690112

typedef short s16x8 __attribute__((ext_vector_type(8)));
typedef unsigned short u16x8 __attribute__((ext_vector_type(8)));
typedef float f32x4 __attribute__((ext_vector_type(4)));
typedef float f32x16 __attribute__((ext_vector_type(16)));
typedef unsigned u32x4 __attribute__((ext_vector_type(4)));

__device__ __forceinline__ unsigned short f2bf(float x) {
    unsigned u = __float_as_uint(x);
    unsigned r = (u + 0x7FFFu + ((u >> 16) & 1u)) >> 16;   // RNE
    return (unsigned short)r;
}

__device__ __forceinline__ unsigned cvt_pk_bf16(float lo, float hi) {
    unsigned r;
    asm volatile("v_cvt_pk_bf16_f32 %0, %1, %2" : "=v"(r) : "v"(lo), "v"(hi));
    return r;
}

// split float into bf16 hi + bf16 lo correction (x ~= hi + lo)
__device__ __forceinline__ void split_bf(float x, unsigned short& hi, unsigned short& lo) {
    unsigned short h = f2bf(x);
    float hf = __uint_as_float(((unsigned)h) << 16);
    hi = h;
    lo = f2bf(x - hf);
}

// ---------------------------------------------------------------------------
// K0: split Wv(256x64 fp32) -> WT hi/lo bf16 [e=64][dd=256] (transposed)
__global__ __launch_bounds__(256) void k0_wsplit(
    const float* __restrict__ Wv,
    unsigned short* __restrict__ WThi, unsigned short* __restrict__ WTlo) {
    int e = blockIdx.x, dd = threadIdx.x;
    float x = Wv[dd * DCC + e];
    unsigned short h, l;
    split_bf(x, h, l);
    WThi[e * 256 + dd] = h;
    WTlo[e * 256 + dd] = l;
}

// ---------------------------------------------------------------------------
// K1c: window average of coords only
__global__ __launch_bounds__(256) void k1c_avg(
    const float* __restrict__ c0, const float* __restrict__ c1,
    float* __restrict__ Cavg) {
    int wi = blockIdx.x * 4 + (threadIdx.x >> 6);
    int d = threadIdx.x & 63;
    int b = wi / NTOT, N = wi % NTOT;
    int src = N / NSRC, nloc = N % NSRC;
    int wh = nloc / 28, ww = nloc % 28;
    const float* __restrict__ C = src ? c1 : c0;
    int pbase = (b * 224 + wh * 8) * 224 + ww * 8;
    float s = 0.f;
#pragma unroll 8
    for (int p = 0; p < 64; ++p)
        s += C[(size_t)(pbase + (p >> 3) * 224 + (p & 7)) * DCC + d];
    Cavg[(size_t)wi * DCC + d] = s * 0.015625f;
}

// ---------------------------------------------------------------------------
// K2: qk = rmsnorm(avg @ Wqk + b, g); packed 20-dim q/k rows (fp32)
__global__ __launch_bounds__(256) void k2_qk(
    const float* __restrict__ Vavg, const float* __restrict__ Cavg,
    const float* __restrict__ Wqkv, const float* __restrict__ bqkv, const float* __restrict__ gv,
    const float* __restrict__ Wqkc, const float* __restrict__ bqkc, const float* __restrict__ gc,
    float* __restrict__ q20, float* __restrict__ k20) {
    __shared__ float xv[DVC];
    __shared__ float xc[DCC];
    __shared__ float wred[4];
    int blk = blockIdx.x;
    int b = blk / NTOT, N = blk % NTOT;
    int t = threadIdx.x;
    xv[t] = Vavg[(size_t)blk * DVC + t];
    if (t < DCC) xc[t] = Cavg[(size_t)blk * DCC + t];
    __syncthreads();
    float yv = bqkv[t];
#pragma unroll 4
    for (int d = 0; d < DVC; ++d) yv += xv[d] * Wqkv[d * 256 + t];
    float ss = yv * yv;
#pragma unroll
    for (int off = 32; off; off >>= 1) ss += __shfl_xor(ss, off, 64);
    if ((t & 63) == 0) wred[t >> 6] = ss;
    __syncthreads();
    float tot = wred[0] + wred[1] + wred[2] + wred[3];
    float rv = rsqrtf(tot * (1.f / 256.f) + 1e-6f);
    float yn = yv * rv * gv[t];
    int h = t >> 5, c = t & 31;
    int bh = b * NHD + h;
    if (c < 16) q20[((size_t)bh * NTOT + N) * D20 + c] = yn * 0.088388347648318447f;
    else        k20[((size_t)bh * NTOT + N) * D20 + (c - 16)] = yn;
    if (t < DCC) {
        float yc = bqkc[t];
#pragma unroll 4
        for (int d = 0; d < DCC; ++d) yc += xc[d] * Wqkc[d * 64 + t];
        float sc = yc * yc;
#pragma unroll
        for (int off = 32; off; off >>= 1) sc += __shfl_xor(sc, off, 64);
        float rc = rsqrtf(sc * (1.f / 64.f) + 1e-6f);
        float ycn = yc * rc * gc[t];
        int h2 = t >> 3, c2 = t & 7;
        int bh2 = b * NHD + h2;
        if (c2 < 4) q20[((size_t)bh2 * NTOT + N) * D20 + 16 + c2] = ycn * 0.17677669529663687f;
        else        k20[((size_t)bh2 * NTOT + N) * D20 + 16 + (c2 - 4)] = ycn;
    }
}

// ---------------------------------------------------------------------------
// K2b: split q20/k20 fp32 -> Qsp/Ksp bf16 hi/lo, row = [hi d0..31 | lo d0..31]
// (d >= 20 zero-padded); fragment-friendly for direct global MFMA reads.
__global__ __launch_bounds__(256) void k2b_split(
    const float* __restrict__ q20, const float* __restrict__ k20,
    unsigned short* __restrict__ Qsp, unsigned short* __restrict__ Ksp) {
    int row = blockIdx.x * 8 + (threadIdx.x >> 5);
    int col = threadIdx.x & 31;
    float xq = (col < 20) ? q20[(size_t)row * D20 + col] : 0.f;
    float xk = (col < 20) ? k20[(size_t)row * D20 + col] : 0.f;
    unsigned short h, l;
    split_bf(xq, h, l);
    Qsp[(size_t)row * 64 + col] = h;
    Qsp[(size_t)row * 64 + 32 + col] = l;
    split_bf(xk, h, l);
    Ksp[(size_t)row * 64 + col] = h;
    Ksp[(size_t)row * 64 + 32 + col] = l;
}

// ---------------------------------------------------------------------------
// K3: MFMA GEMM per window: X(64px x 256) @ Wv(256x64) -> Vv bf16 [bh][N][f]
//     3-term bf16 hi/lo split (fp32-grade). Fused exact fp32 window-average.
__global__ __launch_bounds__(256) void k3_vv(
    const float* __restrict__ v0, const float* __restrict__ v1,
    const unsigned short* __restrict__ WThi, const unsigned short* __restrict__ WTlo,
    unsigned short* __restrict__ Vvb, float* __restrict__ Vavg) {
    __shared__ unsigned short Ahi[64 * 40];   // [px][dd] (+pad to 40)
    __shared__ unsigned short Alo[64 * 40];
    __shared__ float avgpart[256];
    __shared__ float avgrow[256];
    int blk = blockIdx.x;
    int b = blk / NTOT, N = blk % NTOT;
    int src = N / NSRC, nloc = N % NSRC;
    int wh = nloc / 28, ww = nloc % 28;
    const float* __restrict__ V = src ? v1 : v0;
    int t = threadIdx.x;
    int w = t >> 6, lane = t & 63;
    int lm = lane & 15, lk = lane >> 4;
    int ddl = t & 31;            // dd within chunk (col owner)
    int pg = t >> 5;             // px group 0..7
    int pbase = (b * 224 + wh * 8) * 224 + ww * 8;
    const float* xptr[8];
#pragma unroll
    for (int i = 0; i < 8; ++i) {
        int px = i * 8 + pg;
        xptr[i] = V + (size_t)(pbase + (px >> 3) * 224 + (px & 7)) * DVC + ddl;
    }
    f32x4 acc4[4];
#pragma unroll
    for (int nt = 0; nt < 4; ++nt) acc4[nt] = (f32x4)0.f;

    for (int c = 0; c < 8; ++c) {
        int d0 = c * 32;
        float xs[8];
#pragma unroll
        for (int i = 0; i < 8; ++i) xs[i] = xptr[i][d0];
        float part = 0.f;
#pragma unroll
        for (int i = 0; i < 8; ++i) part += xs[i];
        __syncthreads();                       // prev chunk LDS reads done
        avgpart[t] = part;
#pragma unroll
        for (int i = 0; i < 8; ++i) {
            int px = i * 8 + pg;
            unsigned short h, l;
            split_bf(xs[i], h, l);
            Ahi[px * 40 + ddl] = h;
            Alo[px * 40 + ddl] = l;
        }
        __syncthreads();                       // tile staged
        if (t < 32) {
            float s = 0.f;
#pragma unroll
            for (int g = 0; g < 8; ++g) s += avgpart[g * 32 + t];
            avgrow[d0 + t] = s * 0.015625f;
        }
        s16x8 ahi = *(const s16x8*)&Ahi[(w * 16 + lm) * 40 + lk * 8];
        s16x8 alo = *(const s16x8*)&Alo[(w * 16 + lm) * 40 + lk * 8];
#pragma unroll
        for (int nt = 0; nt < 4; ++nt) {
            int e = nt * 16 + lm;
            s16x8 bhi = *(const s16x8*)&WThi[e * 256 + d0 + lk * 8];
            s16x8 blo = *(const s16x8*)&WTlo[e * 256 + d0 + lk * 8];
            acc4[nt] = __builtin_amdgcn_mfma_f32_16x16x32_bf16(ahi, blo, acc4[nt], 0, 0, 0);
            acc4[nt] = __builtin_amdgcn_mfma_f32_16x16x32_bf16(alo, bhi, acc4[nt], 0, 0, 0);
            acc4[nt] = __builtin_amdgcn_mfma_f32_16x16x32_bf16(ahi, bhi, acc4[nt], 0, 0, 0);
        }
    }
    // epilogue: C 16x16 layout col=l&15, row=(l>>4)*4+r
#pragma unroll
    for (int nt = 0; nt < 4; ++nt) {
        int e = nt * 16 + lm;
#pragma unroll
        for (int r = 0; r < 4; ++r) {
            int px = w * 16 + lk * 4 + r;
            Vvb[((size_t)(b * NHD + (e & 7)) * NTOT + N) * FDIM + px * 8 + (e >> 3)] = f2bf(acc4[nt][r]);
        }
    }
    __syncthreads();
    Vavg[(size_t)blk * DVC + t] = avgrow[t];
}

// ---------------------------------------------------------------------------
// K3b: transpose Vv bf16 [bh][N][f] -> VvT bf16 [bh][f][N]
__global__ __launch_bounds__(256) void k3b_tr(
    const unsigned short* __restrict__ Vvb, unsigned short* __restrict__ VvT) {
    __shared__ unsigned short tile[32][136];
    int n0 = blockIdx.x * 32;
    int f0 = blockIdx.y * 128;
    int bh = blockIdx.z;
    int t = threadIdx.x;
    const unsigned short* src = Vvb + ((size_t)bh * NTOT + n0) * FDIM + f0;
#pragma unroll
    for (int k2 = 0; k2 < 2; ++k2) {
        int i = t + 256 * k2;
        int r = i >> 4, c8 = (i & 15) * 8;
        *(u16x8*)&tile[r][c8] = *(const u16x8*)&src[(size_t)r * FDIM + c8];
    }
    __syncthreads();
    unsigned short* dst = VvT + ((size_t)bh * FDIM + f0) * NTOT + n0;
#pragma unroll
    for (int k2 = 0; k2 < 2; ++k2) {
        int j = t + 256 * k2;
        int fr = j >> 2, p8 = (j & 3) * 8;
        u16x8 v;
#pragma unroll
        for (int u = 0; u < 8; ++u) v[u] = tile[p8 + u][fr];
        *(u16x8*)&dst[(size_t)fr * NTOT + p8] = v;
    }
}

// ---------------------------------------------------------------------------
// K4: flash attention; zero-LDS zero-barrier main loop. All fragments (K, Q,
// V) read directly from global (L2-resident). Per block: 32 q x 1568 k.
__global__ __launch_bounds__(256) void k4_attn(
    const unsigned short* __restrict__ Qsp, const unsigned short* __restrict__ Ksp,
    const unsigned short* __restrict__ VvT, float* __restrict__ rw) {
    __shared__ float ebuf[32 * 132];
    int wg = blockIdx.x;
    int qt = wg >> 4, bh = wg & 15;       // wg%8 == bh%8 -> XCD affinity
    int q0 = qt * 32;
    int t = threadIdx.x;
    int w = t >> 6, lane = t & 63;
    int l31 = lane & 31, hh = lane >> 5;

    const unsigned short* __restrict__ Qrow = Qsp + ((size_t)bh * NTOT + q0 + l31) * 64;
    const unsigned short* __restrict__ Kbase = Ksp + (size_t)bh * NTOT * 64;
    const unsigned short* __restrict__ Vt = VvT + (size_t)bh * FDIM * NTOT;

    s16x8 qa0 = *(const s16x8*)&Qrow[hh * 8];
    s16x8 qa1 = *(const s16x8*)&Qrow[16 + hh * 8];
    s16x8 ql0 = *(const s16x8*)&Qrow[32 + hh * 8];
    s16x8 ql1 = *(const s16x8*)&Qrow[48 + hh * 8];

    float m = -1e30f, lsum = 0.f;
    f32x16 acc[4];
#pragma unroll
    for (int s = 0; s < 4; ++s) acc[s] = (f32x16)0.f;

    for (int kt = 0; kt < NTOT / 32; ++kt) {
        int k0 = kt * 32;
        // ---- V fragment loads first (8 x 16B, L2) — consumed last ----
        s16x8 va[8];
#pragma unroll
        for (int sub = 0; sub < 4; ++sub) {
            int f = w * 128 + sub * 32 + l31;
            const unsigned short* vp = &Vt[(size_t)f * NTOT + k0 + hh * 8];
            va[2 * sub]     = *(const s16x8*)(vp);
            va[2 * sub + 1] = *(const s16x8*)(vp + 16);
        }
        // ---- K fragment loads (4 x 16B) ----
        const unsigned short* Krow = Kbase + (size_t)(k0 + l31) * 64;
        s16x8 ka0 = *(const s16x8*)&Krow[hh * 8];
        s16x8 ka1 = *(const s16x8*)&Krow[16 + hh * 8];
        s16x8 kl0 = *(const s16x8*)&Krow[32 + hh * 8];
        s16x8 kl1 = *(const s16x8*)&Krow[48 + hh * 8];
        // ---- S^T = K @ Q^T (32k x 32q), 3-term hi/lo ----
        f32x16 sacc = (f32x16)0.f;
        sacc = __builtin_amdgcn_mfma_f32_32x32x16_bf16(kl0, qa0, sacc, 0, 0, 0);
        sacc = __builtin_amdgcn_mfma_f32_32x32x16_bf16(ka0, ql0, sacc, 0, 0, 0);
        sacc = __builtin_amdgcn_mfma_f32_32x32x16_bf16(ka0, qa0, sacc, 0, 0, 0);
        sacc = __builtin_amdgcn_mfma_f32_32x32x16_bf16(kl1, qa1, sacc, 0, 0, 0);
        sacc = __builtin_amdgcn_mfma_f32_32x32x16_bf16(ka1, ql1, sacc, 0, 0, 0);
        sacc = __builtin_amdgcn_mfma_f32_32x32x16_bf16(ka1, qa1, sacc, 0, 0, 0);

        // ---- online softmax (per-lane q column), defer-max THR=8 ----
        float tmax = sacc[0];
#pragma unroll
        for (int r = 1; r < 16; ++r) tmax = fmaxf(tmax, sacc[r]);
        tmax = fmaxf(tmax, __shfl_xor(tmax, 32, 64));
        if (__any(tmax > m + 8.f)) {
            float mn = fmaxf(m, tmax);
            float sc = __expf(m - mn);
#pragma unroll
            for (int s = 0; s < 4; ++s) acc[s] = acc[s] * sc;
            lsum *= sc;
            m = mn;
        }
        // ---- P = exp(S - m), pack bf16 pairs, half-swap ----
        unsigned P2[8];
        float tsum = 0.f;
#pragma unroll
        for (int j = 0; j < 8; ++j) {
            float pa = __expf(sacc[2 * j] - m);
            float pb = __expf(sacc[2 * j + 1] - m);
            tsum += pa + pb;
            P2[j] = cvt_pk_bf16(pa, pb);
        }
        lsum += tsum + __shfl_xor(tsum, 32, 64);
        unsigned X2[8];
#pragma unroll
        for (int j = 0; j < 8; ++j) X2[j] = (unsigned)__shfl_xor((int)P2[j], 32, 64);
        u32x4 b0u, b1u;
        if (hh == 0) {
            b0u[0] = P2[0]; b0u[1] = P2[1]; b0u[2] = X2[0]; b0u[3] = X2[1];
            b1u[0] = P2[4]; b1u[1] = P2[5]; b1u[2] = X2[4]; b1u[3] = X2[5];
        } else {
            b0u[0] = X2[2]; b0u[1] = X2[3]; b0u[2] = P2[2]; b0u[3] = P2[3];
            b1u[0] = X2[6]; b1u[1] = X2[7]; b1u[2] = P2[6]; b1u[3] = P2[7];
        }
        s16x8 pb0 = __builtin_bit_cast(s16x8, b0u);
        s16x8 pb1 = __builtin_bit_cast(s16x8, b1u);

        // ---- PV: O^T[f][q] += V^T[f][k] P^T[k][q] ----
#pragma unroll
        for (int sub = 0; sub < 4; ++sub) {
            acc[sub] = __builtin_amdgcn_mfma_f32_32x32x16_bf16(va[2 * sub],     pb0, acc[sub], 0, 0, 0);
            acc[sub] = __builtin_amdgcn_mfma_f32_32x32x16_bf16(va[2 * sub + 1], pb1, acc[sub], 0, 0, 0);
        }
    }

    // ---- epilogue: normalize, chunked LDS transpose, coalesced store ----
    float inv = 1.f / lsum;
    float* rwg = rw + ((size_t)bh * NTOT + q0) * FDIM;
#pragma unroll
    for (int c = 0; c < 4; ++c) {
        __syncthreads();
        if (w == c) {
#pragma unroll
            for (int sub = 0; sub < 4; ++sub) {
#pragma unroll
                for (int r = 0; r < 16; ++r) {
                    int fl = sub * 32 + (r & 3) + 8 * (r >> 2) + 4 * hh;
                    ebuf[l31 * 132 + fl] = acc[sub][r] * inv;
                }
            }
        }
        __syncthreads();
        int qr = t >> 3, cb = (t & 7) * 16;
#pragma unroll
        for (int j = 0; j < 4; ++j) {
            *(float4*)&rwg[(size_t)qr * FDIM + c * 128 + cb + j * 4] =
                *(const float4*)&ebuf[qr * 132 + cb + j * 4];
        }
    }
}

// ---------------------------------------------------------------------------
// K5: gather rw into (n, e*8+h) layout, multiply by Wback, unwindow-scatter
__global__ __launch_bounds__(256) void k5_back(
    const float* __restrict__ rw, const float* __restrict__ Wb,
    float* __restrict__ out) {
    __shared__ float rwL[64][68];
    int blk = blockIdx.x;
    int b = blk / NTOT, N = blk % NTOT;
    int src = N / NSRC, nloc = N % NSRC;
    int wh = nloc / 28, ww = nloc % 28;
    int t = threadIdx.x;
    float w[64];
#pragma unroll
    for (int j = 0; j < 64; ++j) w[j] = Wb[j * DVC + t];
#pragma unroll
    for (int i = 0; i < 16; ++i) {
        int flat = i * 256 + t;
        int h = flat >> 9, f = flat & 511;
        rwL[f >> 3][(f & 7) * 8 + h] = rw[((size_t)(b * NHD + h) * NTOT + N) * FDIM + f];
    }
    __syncthreads();
    float* __restrict__ op = out + (size_t)src * OUT_PER_SRC
                           + (size_t)((b * 224 + wh * 8) * 224 + ww * 8) * DVC;
#pragma unroll 2
    for (int n = 0; n < 64; ++n) {
        const float4* r4 = (const float4*)&rwL[n][0];
        float s = 0.f;
#pragma unroll
        for (int i = 0; i < 16; ++i) {
            float4 r = r4[i];
            s += r.x * w[4 * i] + r.y * w[4 * i + 1] + r.z * w[4 * i + 2] + r.w * w[4 * i + 3];
        }
        op[((n >> 3) * 224 + (n & 7)) * DVC + t] = s;
    }
}

// ---------------------------------------------------------------------------
extern "C" void kernel_launch(void* const* d_in, const int* in_sizes, int n_in,
                              void* d_out, int out_size, void* d_ws, size_t ws_size,
                              hipStream_t stream) {
    const float* v0   = (const float*)d_in[0];
    const float* c0   = (const float*)d_in[1];
    const float* v1   = (const float*)d_in[2];
    const float* c1   = (const float*)d_in[3];
    const float* Wqkv = (const float*)d_in[4];
    const float* bqkv = (const float*)d_in[5];
    const float* gv   = (const float*)d_in[6];
    const float* Wqkc = (const float*)d_in[7];
    const float* bqkc = (const float*)d_in[8];
    const float* gc   = (const float*)d_in[9];
    const float* Wv   = (const float*)d_in[10];
    const float* Wbk  = (const float*)d_in[11];

    float* ws = (float*)d_ws;
    // Region A (12,845,056 fl): rw, aliasing Vavg/Cavg/q20/k20 (dead by k4)
    float* rw   = ws;
    float* Vavg = ws;                       //   802,816 fl
    float* Cavg = ws + 802816;              //   200,704 fl
    float* q20  = ws + 1003520;             //   501,760 fl
    float* k20  = ws + 1505280;             //   501,760 fl  (ends 2,007,040)
    unsigned short* Qsp  = (unsigned short*)(ws + 12845056);  // 802,816 fl
    unsigned short* Ksp  = (unsigned short*)(ws + 13647872);  // 802,816 fl
    unsigned short* WThi = (unsigned short*)(ws + 14450688);  //   8,192 fl
    unsigned short* WTlo = (unsigned short*)(ws + 14458880);  //   8,192 fl
    unsigned short* Vvb  = (unsigned short*)(ws + 14467072);  // 6,422,528 fl
    unsigned short* VvT  = (unsigned short*)(ws + 20889600);  // 6,422,528 fl
    // total 27,312,128 fl = 109.2 MB

    float* outp = (float*)d_out;

    k0_wsplit<<<64, 256, 0, stream>>>(Wv, WThi, WTlo);
    k3_vv    <<<2 * NTOT, 256, 0, stream>>>(v0, v1, WThi, WTlo, Vvb, Vavg);
    k1c_avg  <<<784, 256, 0, stream>>>(c0, c1, Cavg);
    k2_qk    <<<2 * NTOT, 256, 0, stream>>>(Vavg, Cavg, Wqkv, bqkv, gv, Wqkc, bqkc, gc, q20, k20);
    k2b_split<<<2 * NTOT / 2 * 2, 256, 0, stream>>>(q20, k20, Qsp, Ksp);
    k3b_tr   <<<dim3(49, 4, 16), 256, 0, stream>>>(Vvb, VvT);
    k4_attn  <<<784, 256, 0, stream>>>(Qsp, Ksp, VvT, rw);
    k5_back  <<<2 * NTOT, 256, 0, stream>>>(rw, Wbk, outp);
}

// Round 5
// 502.564 us; speedup vs baseline: 2.4299x; 1.1582x over previous
//
#include <hip/hip_runtime.h>

#define NSRC 784
#define NTOT 1568
#define NHD 8
#define DVC 256
#define DCC 64
#define D20 20
#define FDIM 512
#define OUT_PER_SRC 25690112

typedef short s16x8 __attribute__((ext_vector_type(8)));
typedef unsigned short u16x8 __attribute__((ext_vector_type(8)));
typedef float f32x4 __attribute__((ext_vector_type(4)));
typedef float f32x16 __attribute__((ext_vector_type(16)));
typedef unsigned u32x4 __attribute__((ext_vector_type(4)));

__device__ __forceinline__ unsigned short f2bf(float x) {
    unsigned u = __float_as_uint(x);
    unsigned r = (u + 0x7FFFu + ((u >> 16) & 1u)) >> 16;   // RNE
    return (unsigned short)r;
}

__device__ __forceinline__ unsigned cvt_pk_bf16(float lo, float hi) {
    unsigned r;
    asm volatile("v_cvt_pk_bf16_f32 %0, %1, %2" : "=v"(r) : "v"(lo), "v"(hi));
    return r;
}

// split float into bf16 hi + bf16 lo correction (x ~= hi + lo)
__device__ __forceinline__ void split_bf(float x, unsigned short& hi, unsigned short& lo) {
    unsigned short h = f2bf(x);
    float hf = __uint_as_float(((unsigned)h) << 16);
    hi = h;
    lo = f2bf(x - hf);
}

// ---------------------------------------------------------------------------
// KZ: zero Qp+Kp (contiguous) — clears the d in [20,32) pad slots
__global__ __launch_bounds__(256) void kz_zero(unsigned short* __restrict__ p) {
    size_t i = (size_t)blockIdx.x * 256 + threadIdx.x;   // grid covers n/8 exactly
    u16x8 z = (u16x8)0;
    *(u16x8*)&p[i * 8] = z;
}

// ---------------------------------------------------------------------------
// K0: split Wv(256x64 fp32) -> WT hi/lo bf16 [e=64][dd=256] (transposed)
__global__ __launch_bounds__(256) void k0_wsplit(
    const float* __restrict__ Wv,
    unsigned short* __restrict__ WThi, unsigned short* __restrict__ WTlo) {
    int e = blockIdx.x, dd = threadIdx.x;
    float x = Wv[dd * DCC + e];
    unsigned short h, l;
    split_bf(x, h, l);
    WThi[e * 256 + dd] = h;
    WTlo[e * 256 + dd] = l;
}

// ---------------------------------------------------------------------------
// K1c: window average of coords only
__global__ __launch_bounds__(256) void k1c_avg(
    const float* __restrict__ c0, const float* __restrict__ c1,
    float* __restrict__ Cavg) {
    int wi = blockIdx.x * 4 + (threadIdx.x >> 6);
    int d = threadIdx.x & 63;
    int b = wi / NTOT, N = wi % NTOT;
    int src = N / NSRC, nloc = N % NSRC;
    int wh = nloc / 28, ww = nloc % 28;
    const float* __restrict__ C = src ? c1 : c0;
    int pbase = (b * 224 + wh * 8) * 224 + ww * 8;
    float s = 0.f;
#pragma unroll 8
    for (int p = 0; p < 64; ++p)
        s += C[(size_t)(pbase + (p >> 3) * 224 + (p & 7)) * DCC + d];
    Cavg[(size_t)wi * DCC + d] = s * 0.015625f;
}

// ---------------------------------------------------------------------------
// K2: qk = rmsnorm(avg @ Wqk + b, g); writes Q/K bf16 hi/lo fragments
// DIRECTLY in k4's packed lane order.
// Layout: [bh][tile49][frag4][lane64][j8], frag = {hi d0-15, hi d16-31,
// lo d0-15, lo d16-31}; lane = hh*32 + (N&31); element (hh,j): d = hh*8+j
// (chunk 0) or 16+hh*8+j (chunk 1). d>=20 slots pre-zeroed by kz_zero.
__global__ __launch_bounds__(256) void k2_qk(
    const float* __restrict__ Vavg, const float* __restrict__ Cavg,
    const float* __restrict__ Wqkv, const float* __restrict__ bqkv, const float* __restrict__ gv,
    const float* __restrict__ Wqkc, const float* __restrict__ bqkc, const float* __restrict__ gc,
    unsigned short* __restrict__ Qp, unsigned short* __restrict__ Kp) {
    __shared__ float xv[DVC];
    __shared__ float xc[DCC];
    __shared__ float wred[4];
    int blk = blockIdx.x;
    int b = blk / NTOT, N = blk % NTOT;
    int t = threadIdx.x;
    int tile = N >> 5, l31 = N & 31;
    xv[t] = Vavg[(size_t)blk * DVC + t];
    if (t < DCC) xc[t] = Cavg[(size_t)blk * DCC + t];
    __syncthreads();
    float yv = bqkv[t];
#pragma unroll 4
    for (int d = 0; d < DVC; ++d) yv += xv[d] * Wqkv[d * 256 + t];
    float ss = yv * yv;
#pragma unroll
    for (int off = 32; off; off >>= 1) ss += __shfl_xor(ss, off, 64);
    if ((t & 63) == 0) wred[t >> 6] = ss;
    __syncthreads();
    float tot = wred[0] + wred[1] + wred[2] + wred[3];
    float rv = rsqrtf(tot * (1.f / 256.f) + 1e-6f);
    float yn = yv * rv * gv[t];
    int h = t >> 5, c = t & 31;
    int bh = b * NHD + h;
    {
        int isq = (c < 16);
        int d = isq ? c : c - 16;
        float val = isq ? yn * 0.088388347648318447f : yn;   // q pre-scaled 1/sqrt(128)
        unsigned short h16, l16;
        split_bf(val, h16, l16);
        int hh = d >> 3, j = d & 7;
        size_t base = ((size_t)(bh * 49 + tile) * 4) * 512 + (size_t)(hh * 32 + l31) * 8 + j;
        unsigned short* dst = isq ? Qp : Kp;
        dst[base] = h16;            // frag 0 (hi, d0-15)
        dst[base + 1024] = l16;     // frag 2 (lo, d0-15)
    }
    if (t < DCC) {
        float yc = bqkc[t];
#pragma unroll 4
        for (int d = 0; d < DCC; ++d) yc += xc[d] * Wqkc[d * 64 + t];
        float sc = yc * yc;
#pragma unroll
        for (int off = 32; off; off >>= 1) sc += __shfl_xor(sc, off, 64);
        float rc = rsqrtf(sc * (1.f / 64.f) + 1e-6f);
        float ycn = yc * rc * gc[t];
        int h2 = t >> 3, c2 = t & 7;
        int bh2 = b * NHD + h2;
        int isq = (c2 < 4);
        int dd = isq ? c2 : c2 - 4;          // d = 16 + dd, chunk 1, hh = 0, j = dd
        float val = isq ? ycn * 0.17677669529663687f : ycn;  // q pre-scaled 1/sqrt(32)
        unsigned short h16, l16;
        split_bf(val, h16, l16);
        size_t base = ((size_t)(bh2 * 49 + tile) * 4 + 1) * 512 + (size_t)l31 * 8 + dd;
        unsigned short* dst = isq ? Qp : Kp;
        dst[base] = h16;            // frag 1 (hi, d16-31)
        dst[base + 1024] = l16;     // frag 3 (lo, d16-31)
    }
}

// ---------------------------------------------------------------------------
// K3: MFMA GEMM per window: X(64px x 256) @ Wv(256x64) -> Vv bf16 [bh][N][f]
//     3-term bf16 hi/lo split (fp32-grade). Fused exact fp32 window-average.
__global__ __launch_bounds__(256) void k3_vv(
    const float* __restrict__ v0, const float* __restrict__ v1,
    const unsigned short* __restrict__ WThi, const unsigned short* __restrict__ WTlo,
    unsigned short* __restrict__ Vvb, float* __restrict__ Vavg) {
    __shared__ unsigned short Ahi[64 * 40];   // [px][dd] (+pad to 40)
    __shared__ unsigned short Alo[64 * 40];
    __shared__ float avgpart[256];
    __shared__ float avgrow[256];
    int blk = blockIdx.x;
    int b = blk / NTOT, N = blk % NTOT;
    int src = N / NSRC, nloc = N % NSRC;
    int wh = nloc / 28, ww = nloc % 28;
    const float* __restrict__ V = src ? v1 : v0;
    int t = threadIdx.x;
    int w = t >> 6, lane = t & 63;
    int lm = lane & 15, lk = lane >> 4;
    int ddl = t & 31;            // dd within chunk (col owner)
    int pg = t >> 5;             // px group 0..7
    int pbase = (b * 224 + wh * 8) * 224 + ww * 8;
    const float* xptr[8];
#pragma unroll
    for (int i = 0; i < 8; ++i) {
        int px = i * 8 + pg;
        xptr[i] = V + (size_t)(pbase + (px >> 3) * 224 + (px & 7)) * DVC + ddl;
    }
    f32x4 acc4[4];
#pragma unroll
    for (int nt = 0; nt < 4; ++nt) acc4[nt] = (f32x4)0.f;

    for (int c = 0; c < 8; ++c) {
        int d0 = c * 32;
        float xs[8];
#pragma unroll
        for (int i = 0; i < 8; ++i) xs[i] = xptr[i][d0];
        float part = 0.f;
#pragma unroll
        for (int i = 0; i < 8; ++i) part += xs[i];
        __syncthreads();                       // prev chunk LDS reads done
        avgpart[t] = part;
#pragma unroll
        for (int i = 0; i < 8; ++i) {
            int px = i * 8 + pg;
            unsigned short h, l;
            split_bf(xs[i], h, l);
            Ahi[px * 40 + ddl] = h;
            Alo[px * 40 + ddl] = l;
        }
        __syncthreads();                       // tile staged
        if (t < 32) {
            float s = 0.f;
#pragma unroll
            for (int g = 0; g < 8; ++g) s += avgpart[g * 32 + t];
            avgrow[d0 + t] = s * 0.015625f;
        }
        s16x8 ahi = *(const s16x8*)&Ahi[(w * 16 + lm) * 40 + lk * 8];
        s16x8 alo = *(const s16x8*)&Alo[(w * 16 + lm) * 40 + lk * 8];
#pragma unroll
        for (int nt = 0; nt < 4; ++nt) {
            int e = nt * 16 + lm;
            s16x8 bhi = *(const s16x8*)&WThi[e * 256 + d0 + lk * 8];
            s16x8 blo = *(const s16x8*)&WTlo[e * 256 + d0 + lk * 8];
            acc4[nt] = __builtin_amdgcn_mfma_f32_16x16x32_bf16(ahi, blo, acc4[nt], 0, 0, 0);
            acc4[nt] = __builtin_amdgcn_mfma_f32_16x16x32_bf16(alo, bhi, acc4[nt], 0, 0, 0);
            acc4[nt] = __builtin_amdgcn_mfma_f32_16x16x32_bf16(ahi, bhi, acc4[nt], 0, 0, 0);
        }
    }
#pragma unroll
    for (int nt = 0; nt < 4; ++nt) {
        int e = nt * 16 + lm;
#pragma unroll
        for (int r = 0; r < 4; ++r) {
            int px = w * 16 + lk * 4 + r;
            Vvb[((size_t)(b * NHD + (e & 7)) * NTOT + N) * FDIM + px * 8 + (e >> 3)] = f2bf(acc4[nt][r]);
        }
    }
    __syncthreads();
    Vavg[(size_t)blk * DVC + t] = avgrow[t];
}

// ---------------------------------------------------------------------------
// K3b: pack Vvb [bh][N][f] -> Vp fragment order [bh][kt][w][sub][kh][lane][8]
// element j = V[f = w*128+sub*32+(lane&31)][k = kt*32 + kh*16 + (lane>>5)*8 + j]
__global__ __launch_bounds__(256) void k3b_pack(
    const unsigned short* __restrict__ Vvb, unsigned short* __restrict__ Vp) {
    __shared__ unsigned short tile[32 * 520];   // [k][f], +8 pad
    int kt = blockIdx.x, bh = blockIdx.y;
    int t = threadIdx.x;
    const unsigned short* src = Vvb + ((size_t)bh * NTOT + kt * 32) * FDIM;
#pragma unroll
    for (int it = 0; it < 8; ++it) {
        int flat = it * 256 + t;                // 0..2047
        int r = flat >> 6, c8 = (flat & 63) * 8;
        *(u16x8*)&tile[r * 520 + c8] = *(const u16x8*)&src[(size_t)r * FDIM + c8];
    }
    __syncthreads();
    unsigned short* dst = Vp + ((size_t)bh * 49 + kt) * 16384;
#pragma unroll
    for (int it = 0; it < 8; ++it) {
        int flato = it * 256 + t;               // 0..2047
        int lane = flato & 63;
        int kh = (flato >> 6) & 1;
        int sub = (flato >> 7) & 3;
        int w = flato >> 9;
        int l31 = lane & 31, hh = lane >> 5;
        int f = w * 128 + sub * 32 + l31;
        int kbase = kh * 16 + hh * 8;
        u16x8 v;
#pragma unroll
        for (int j = 0; j < 8; ++j) v[j] = tile[(kbase + j) * 520 + f];
        *(u16x8*)&dst[(size_t)flato * 8] = v;
    }
}

// ---------------------------------------------------------------------------
// K4: flash attention; zero-LDS zero-barrier main loop, all fragment loads
// perfectly coalesced (lane-ordered packed buffers), 1-deep K prefetch.
__global__ __launch_bounds__(256) void k4_attn(
    const unsigned short* __restrict__ Qp, const unsigned short* __restrict__ Kp,
    const unsigned short* __restrict__ Vp, float* __restrict__ rw) {
    __shared__ float ebuf[32 * 132];
    int wg = blockIdx.x;
    int qt = wg >> 4, bh = wg & 15;       // wg%8 == bh%8 -> XCD affinity
    int q0 = qt * 32;
    int t = threadIdx.x;
    int w = t >> 6, lane = t & 63;
    int l31 = lane & 31, hh = lane >> 5;

    const unsigned short* __restrict__ Qpb = Qp + ((size_t)(bh * 49 + qt) * 4) * 512 + lane * 8;
    const unsigned short* __restrict__ Kpb = Kp + (size_t)bh * 49 * 2048 + lane * 8;
    const unsigned short* __restrict__ Vpb = Vp + (size_t)bh * 49 * 16384 + lane * 8;

    s16x8 qa0 = *(const s16x8*)&Qpb[0];
    s16x8 qa1 = *(const s16x8*)&Qpb[512];
    s16x8 ql0 = *(const s16x8*)&Qpb[1024];
    s16x8 ql1 = *(const s16x8*)&Qpb[1536];

    // K fragments for tile 0
    s16x8 ka0 = *(const s16x8*)&Kpb[0];
    s16x8 ka1 = *(const s16x8*)&Kpb[512];
    s16x8 kl0 = *(const s16x8*)&Kpb[1024];
    s16x8 kl1 = *(const s16x8*)&Kpb[1536];

    float m = -1e30f, lsum = 0.f;
    f32x16 acc[4];
#pragma unroll
    for (int s = 0; s < 4; ++s) acc[s] = (f32x16)0.f;

    for (int kt = 0; kt < NTOT / 32; ++kt) {
        // ---- V fragment loads (8 x coalesced 1KB) ----
        const unsigned short* Vtile = Vpb + (size_t)kt * 16384 + (w * 8) * 512;
        s16x8 va[8];
#pragma unroll
        for (int fr = 0; fr < 8; ++fr)
            va[fr] = *(const s16x8*)&Vtile[fr * 512];
        // ---- prefetch next K tile ----
        int ktn = (kt < 48) ? kt + 1 : 48;
        const unsigned short* Ktn = Kpb + (size_t)ktn * 2048;
        s16x8 kn0 = *(const s16x8*)&Ktn[0];
        s16x8 kn1 = *(const s16x8*)&Ktn[512];
        s16x8 kn2 = *(const s16x8*)&Ktn[1024];
        s16x8 kn3 = *(const s16x8*)&Ktn[1536];

        // ---- S^T = K @ Q^T (32k x 32q), 3-term hi/lo ----
        f32x16 sacc = (f32x16)0.f;
        sacc = __builtin_amdgcn_mfma_f32_32x32x16_bf16(kl0, qa0, sacc, 0, 0, 0);
        sacc = __builtin_amdgcn_mfma_f32_32x32x16_bf16(ka0, ql0, sacc, 0, 0, 0);
        sacc = __builtin_amdgcn_mfma_f32_32x32x16_bf16(ka0, qa0, sacc, 0, 0, 0);
        sacc = __builtin_amdgcn_mfma_f32_32x32x16_bf16(kl1, qa1, sacc, 0, 0, 0);
        sacc = __builtin_amdgcn_mfma_f32_32x32x16_bf16(ka1, ql1, sacc, 0, 0, 0);
        sacc = __builtin_amdgcn_mfma_f32_32x32x16_bf16(ka1, qa1, sacc, 0, 0, 0);

        // ---- online softmax (per-lane q column), defer-max THR=8 ----
        float tmax = sacc[0];
#pragma unroll
        for (int r = 1; r < 16; ++r) tmax = fmaxf(tmax, sacc[r]);
        tmax = fmaxf(tmax, __shfl_xor(tmax, 32, 64));
        if (__any(tmax > m + 8.f)) {
            float mn = fmaxf(m, tmax);
            float sc = __expf(m - mn);
#pragma unroll
            for (int s = 0; s < 4; ++s) acc[s] = acc[s] * sc;
            lsum *= sc;
            m = mn;
        }
        // ---- P = exp(S - m), pack bf16 pairs, half-swap ----
        unsigned P2[8];
        float tsum = 0.f;
#pragma unroll
        for (int j = 0; j < 8; ++j) {
            float pa = __expf(sacc[2 * j] - m);
            float pb = __expf(sacc[2 * j + 1] - m);
            tsum += pa + pb;
            P2[j] = cvt_pk_bf16(pa, pb);
        }
        lsum += tsum + __shfl_xor(tsum, 32, 64);
        unsigned X2[8];
#pragma unroll
        for (int j = 0; j < 8; ++j) X2[j] = (unsigned)__shfl_xor((int)P2[j], 32, 64);
        u32x4 b0u, b1u;
        if (hh == 0) {
            b0u[0] = P2[0]; b0u[1] = P2[1]; b0u[2] = X2[0]; b0u[3] = X2[1];
            b1u[0] = P2[4]; b1u[1] = P2[5]; b1u[2] = X2[4]; b1u[3] = X2[5];
        } else {
            b0u[0] = X2[2]; b0u[1] = X2[3]; b0u[2] = P2[2]; b0u[3] = P2[3];
            b1u[0] = X2[6]; b1u[1] = X2[7]; b1u[2] = P2[6]; b1u[3] = P2[7];
        }
        s16x8 pb0 = __builtin_bit_cast(s16x8, b0u);
        s16x8 pb1 = __builtin_bit_cast(s16x8, b1u);

        // ---- PV: O^T[f][q] += V^T[f][k] P^T[k][q] ----
#pragma unroll
        for (int sub = 0; sub < 4; ++sub) {
            acc[sub] = __builtin_amdgcn_mfma_f32_32x32x16_bf16(va[2 * sub],     pb0, acc[sub], 0, 0, 0);
            acc[sub] = __builtin_amdgcn_mfma_f32_32x32x16_bf16(va[2 * sub + 1], pb1, acc[sub], 0, 0, 0);
        }
        ka0 = kn0; ka1 = kn1; kl0 = kn2; kl1 = kn3;
    }

    // ---- epilogue: normalize, chunked LDS transpose, coalesced store ----
    float inv = 1.f / lsum;
    float* rwg = rw + ((size_t)bh * NTOT + q0) * FDIM;
#pragma unroll
    for (int c = 0; c < 4; ++c) {
        __syncthreads();
        if (w == c) {
#pragma unroll
            for (int sub = 0; sub < 4; ++sub) {
#pragma unroll
                for (int r = 0; r < 16; ++r) {
                    int fl = sub * 32 + (r & 3) + 8 * (r >> 2) + 4 * hh;
                    ebuf[l31 * 132 + fl] = acc[sub][r] * inv;
                }
            }
        }
        __syncthreads();
        int qr = t >> 3, cb = (t & 7) * 16;
#pragma unroll
        for (int j = 0; j < 4; ++j) {
            *(float4*)&rwg[(size_t)qr * FDIM + c * 128 + cb + j * 4] =
                *(const float4*)&ebuf[qr * 132 + cb + j * 4];
        }
    }
}

// ---------------------------------------------------------------------------
// K5: gather rw into (n, e*8+h) layout, multiply by Wback, unwindow-scatter
__global__ __launch_bounds__(256) void k5_back(
    const float* __restrict__ rw, const float* __restrict__ Wb,
    float* __restrict__ out) {
    __shared__ float rwL[64][68];
    int blk = blockIdx.x;
    int b = blk / NTOT, N = blk % NTOT;
    int src = N / NSRC, nloc = N % NSRC;
    int wh = nloc / 28, ww = nloc % 28;
    int t = threadIdx.x;
    float w[64];
#pragma unroll
    for (int j = 0; j < 64; ++j) w[j] = Wb[j * DVC + t];
#pragma unroll
    for (int i = 0; i < 16; ++i) {
        int flat = i * 256 + t;
        int h = flat >> 9, f = flat & 511;
        rwL[f >> 3][(f & 7) * 8 + h] = rw[((size_t)(b * NHD + h) * NTOT + N) * FDIM + f];
    }
    __syncthreads();
    float* __restrict__ op = out + (size_t)src * OUT_PER_SRC
                           + (size_t)((b * 224 + wh * 8) * 224 + ww * 8) * DVC;
#pragma unroll 2
    for (int n = 0; n < 64; ++n) {
        const float4* r4 = (const float4*)&rwL[n][0];
        float s = 0.f;
#pragma unroll
        for (int i = 0; i < 16; ++i) {
            float4 r = r4[i];
            s += r.x * w[4 * i] + r.y * w[4 * i + 1] + r.z * w[4 * i + 2] + r.w * w[4 * i + 3];
        }
        op[((n >> 3) * 224 + (n & 7)) * DVC + t] = s;
    }
}

// ---------------------------------------------------------------------------
extern "C" void kernel_launch(void* const* d_in, const int* in_sizes, int n_in,
                              void* d_out, int out_size, void* d_ws, size_t ws_size,
                              hipStream_t stream) {
    const float* v0   = (const float*)d_in[0];
    const float* c0   = (const float*)d_in[1];
    const float* v1   = (const float*)d_in[2];
    const float* c1   = (const float*)d_in[3];
    const float* Wqkv = (const float*)d_in[4];
    const float* bqkv = (const float*)d_in[5];
    const float* gv   = (const float*)d_in[6];
    const float* Wqkc = (const float*)d_in[7];
    const float* bqkc = (const float*)d_in[8];
    const float* gc   = (const float*)d_in[9];
    const float* Wv   = (const float*)d_in[10];
    const float* Wbk  = (const float*)d_in[11];

    float* ws = (float*)d_ws;
    // Region A: rw (12,845,056 fl), aliasing Vavg/Cavg (dead before k4)
    float* rw   = ws;
    float* Vavg = ws;                       //   802,816 fl
    float* Cavg = ws + 802816;              //   200,704 fl
    unsigned short* Qp   = (unsigned short*)(ws + 12845056);  // 1,605,632 u16
    unsigned short* Kp   = (unsigned short*)(ws + 13647872);  // 1,605,632 u16
    unsigned short* WThi = (unsigned short*)(ws + 14450688);  //    16,384 u16
    unsigned short* WTlo = (unsigned short*)(ws + 14458880);  //    16,384 u16
    unsigned short* Vvb  = (unsigned short*)(ws + 14467072);  // 12,845,056 u16
    unsigned short* Vp   = (unsigned short*)(ws + 20889600);  // 12,845,056 u16
    // total 27,312,128 fl = 109.2 MB

    float* outp = (float*)d_out;

    kz_zero  <<<1568, 256, 0, stream>>>(Qp);   // zeros Qp+Kp (contiguous, 3,211,264 u16)
    k0_wsplit<<<64, 256, 0, stream>>>(Wv, WThi, WTlo);
    k3_vv    <<<2 * NTOT, 256, 0, stream>>>(v0, v1, WThi, WTlo, Vvb, Vavg);
    k1c_avg  <<<784, 256, 0, stream>>>(c0, c1, Cavg);
    k2_qk    <<<2 * NTOT, 256, 0, stream>>>(Vavg, Cavg, Wqkv, bqkv, gv, Wqkc, bqkc, gc, Qp, Kp);
    k3b_pack <<<dim3(49, 16), 256, 0, stream>>>(Vvb, Vp);
    k4_attn  <<<784, 256, 0, stream>>>(Qp, Kp, Vp, rw);
    k5_back  <<<2 * NTOT, 256, 0, stream>>>(rw, Wbk, outp);
}

// Round 7
// 391.427 us; speedup vs baseline: 3.1198x; 1.2839x over previous
//
#include <hip/hip_runtime.h>

#define NSRC 784
#define NTOT 1568
#define NHD 8
#define DVC 256
#define DCC 64
#define D20 20
#define FDIM 512
#define OUT_PER_SRC 25690112

typedef short s16x8 __attribute__((ext_vector_type(8)));
typedef unsigned short u16x8 __attribute__((ext_vector_type(8)));
typedef float f32x4 __attribute__((ext_vector_type(4)));
typedef float f32x16 __attribute__((ext_vector_type(16)));
typedef unsigned u32x4 __attribute__((ext_vector_type(4)));

__device__ __forceinline__ unsigned short f2bf(float x) {
    unsigned u = __float_as_uint(x);
    unsigned r = (u + 0x7FFFu + ((u >> 16) & 1u)) >> 16;   // RNE
    return (unsigned short)r;
}

__device__ __forceinline__ unsigned cvt_pk_bf16(float lo, float hi) {
    unsigned r;
    asm volatile("v_cvt_pk_bf16_f32 %0, %1, %2" : "=v"(r) : "v"(lo), "v"(hi));
    return r;
}

// split float into bf16 hi + bf16 lo correction (x ~= hi + lo)
__device__ __forceinline__ void split_bf(float x, unsigned short& hi, unsigned short& lo) {
    unsigned short h = f2bf(x);
    float hf = __uint_as_float(((unsigned)h) << 16);
    hi = h;
    lo = f2bf(x - hf);
}

// ---------------------------------------------------------------------------
// KZ: zero Qp+Kp (contiguous) — clears the d in [20,32) pad slots
__global__ __launch_bounds__(256) void kz_zero(unsigned short* __restrict__ p) {
    size_t i = (size_t)blockIdx.x * 256 + threadIdx.x;
    u16x8 z = (u16x8)0;
    *(u16x8*)&p[i * 8] = z;
}

// ---------------------------------------------------------------------------
// K0: split Wv(256x64 fp32) -> WT hi/lo bf16 [e=64][dd=256] (transposed)
__global__ __launch_bounds__(256) void k0_wsplit(
    const float* __restrict__ Wv,
    unsigned short* __restrict__ WThi, unsigned short* __restrict__ WTlo) {
    int e = blockIdx.x, dd = threadIdx.x;
    float x = Wv[dd * DCC + e];
    unsigned short h, l;
    split_bf(x, h, l);
    WThi[e * 256 + dd] = h;
    WTlo[e * 256 + dd] = l;
}

// ---------------------------------------------------------------------------
// K0b: pack Wback(64j x 256c) -> A-fragment order hi/lo:
// Wp[mt16][kc2][hl2][lane64][jj8]; element = Wb[j = kc*32+(lane>>4)*8+jj][c = mt*16+(lane&15)]
__global__ __launch_bounds__(256) void k0b_wback(
    const float* __restrict__ Wb, unsigned short* __restrict__ Wp) {
    int idx = blockIdx.x * 256 + threadIdx.x;        // 0..65535
    int jj = idx & 7, lane = (idx >> 3) & 63, hl = (idx >> 9) & 1;
    int kc = (idx >> 10) & 1, mt = idx >> 11;
    int c = mt * 16 + (lane & 15);
    int j = kc * 32 + (lane >> 4) * 8 + jj;
    unsigned short h, l;
    split_bf(Wb[j * 256 + c], h, l);
    Wp[idx] = hl ? l : h;
}

// ---------------------------------------------------------------------------
// K1c: window average of coords only
__global__ __launch_bounds__(256) void k1c_avg(
    const float* __restrict__ c0, const float* __restrict__ c1,
    float* __restrict__ Cavg) {
    int wi = blockIdx.x * 4 + (threadIdx.x >> 6);
    int d = threadIdx.x & 63;
    int b = wi / NTOT, N = wi % NTOT;
    int src = N / NSRC, nloc = N % NSRC;
    int wh = nloc / 28, ww = nloc % 28;
    const float* __restrict__ C = src ? c1 : c0;
    int pbase = (b * 224 + wh * 8) * 224 + ww * 8;
    float s = 0.f;
#pragma unroll 8
    for (int p = 0; p < 64; ++p)
        s += C[(size_t)(pbase + (p >> 3) * 224 + (p & 7)) * DCC + d];
    Cavg[(size_t)wi * DCC + d] = s * 0.015625f;
}

// ---------------------------------------------------------------------------
// K2: qk = rmsnorm(avg @ Wqk + b, g); writes Q/K bf16 hi/lo fragments
// DIRECTLY in k4's packed lane order (see R5 comments).
__global__ __launch_bounds__(256) void k2_qk(
    const float* __restrict__ Vavg, const float* __restrict__ Cavg,
    const float* __restrict__ Wqkv, const float* __restrict__ bqkv, const float* __restrict__ gv,
    const float* __restrict__ Wqkc, const float* __restrict__ bqkc, const float* __restrict__ gc,
    unsigned short* __restrict__ Qp, unsigned short* __restrict__ Kp) {
    __shared__ float xv[DVC];
    __shared__ float xc[DCC];
    __shared__ float wred[4];
    int blk = blockIdx.x;
    int b = blk / NTOT, N = blk % NTOT;
    int t = threadIdx.x;
    int tile = N >> 5, l31 = N & 31;
    xv[t] = Vavg[(size_t)blk * DVC + t];
    if (t < DCC) xc[t] = Cavg[(size_t)blk * DCC + t];
    __syncthreads();
    float yv = bqkv[t];
#pragma unroll 4
    for (int d = 0; d < DVC; ++d) yv += xv[d] * Wqkv[d * 256 + t];
    float ss = yv * yv;
#pragma unroll
    for (int off = 32; off; off >>= 1) ss += __shfl_xor(ss, off, 64);
    if ((t & 63) == 0) wred[t >> 6] = ss;
    __syncthreads();
    float tot = wred[0] + wred[1] + wred[2] + wred[3];
    float rv = rsqrtf(tot * (1.f / 256.f) + 1e-6f);
    float yn = yv * rv * gv[t];
    int h = t >> 5, c = t & 31;
    int bh = b * NHD + h;
    {
        int isq = (c < 16);
        int d = isq ? c : c - 16;
        float val = isq ? yn * 0.088388347648318447f : yn;
        unsigned short h16, l16;
        split_bf(val, h16, l16);
        int hh = d >> 3, j = d & 7;
        size_t base = ((size_t)(bh * 49 + tile) * 4) * 512 + (size_t)(hh * 32 + l31) * 8 + j;
        unsigned short* dst = isq ? Qp : Kp;
        dst[base] = h16;
        dst[base + 1024] = l16;
    }
    if (t < DCC) {
        float yc = bqkc[t];
#pragma unroll 4
        for (int d = 0; d < DCC; ++d) yc += xc[d] * Wqkc[d * 64 + t];
        float sc = yc * yc;
#pragma unroll
        for (int off = 32; off; off >>= 1) sc += __shfl_xor(sc, off, 64);
        float rc = rsqrtf(sc * (1.f / 64.f) + 1e-6f);
        float ycn = yc * rc * gc[t];
        int h2 = t >> 3, c2 = t & 7;
        int bh2 = b * NHD + h2;
        int isq = (c2 < 4);
        int dd = isq ? c2 : c2 - 4;
        float val = isq ? ycn * 0.17677669529663687f : ycn;
        unsigned short h16, l16;
        split_bf(val, h16, l16);
        size_t base = ((size_t)(bh2 * 49 + tile) * 4 + 1) * 512 + (size_t)l31 * 8 + dd;
        unsigned short* dst = isq ? Qp : Kp;
        dst[base] = h16;
        dst[base + 1024] = l16;
    }
}

// ---------------------------------------------------------------------------
// K3: MFMA GEMM per window: X(64px x 256) @ Wv(256x64) -> Vv bf16 [bh][N][f]
__global__ __launch_bounds__(256) void k3_vv(
    const float* __restrict__ v0, const float* __restrict__ v1,
    const unsigned short* __restrict__ WThi, const unsigned short* __restrict__ WTlo,
    unsigned short* __restrict__ Vvb, float* __restrict__ Vavg) {
    __shared__ unsigned short Ahi[64 * 40];
    __shared__ unsigned short Alo[64 * 40];
    __shared__ float avgpart[256];
    __shared__ float avgrow[256];
    int blk = blockIdx.x;
    int b = blk / NTOT, N = blk % NTOT;
    int src = N / NSRC, nloc = N % NSRC;
    int wh = nloc / 28, ww = nloc % 28;
    const float* __restrict__ V = src ? v1 : v0;
    int t = threadIdx.x;
    int w = t >> 6, lane = t & 63;
    int lm = lane & 15, lk = lane >> 4;
    int ddl = t & 31;
    int pg = t >> 5;
    int pbase = (b * 224 + wh * 8) * 224 + ww * 8;
    const float* xptr[8];
#pragma unroll
    for (int i = 0; i < 8; ++i) {
        int px = i * 8 + pg;
        xptr[i] = V + (size_t)(pbase + (px >> 3) * 224 + (px & 7)) * DVC + ddl;
    }
    f32x4 acc4[4];
#pragma unroll
    for (int nt = 0; nt < 4; ++nt) acc4[nt] = (f32x4)0.f;

    for (int c = 0; c < 8; ++c) {
        int d0 = c * 32;
        float xs[8];
#pragma unroll
        for (int i = 0; i < 8; ++i) xs[i] = xptr[i][d0];
        float part = 0.f;
#pragma unroll
        for (int i = 0; i < 8; ++i) part += xs[i];
        __syncthreads();
        avgpart[t] = part;
#pragma unroll
        for (int i = 0; i < 8; ++i) {
            int px = i * 8 + pg;
            unsigned short h, l;
            split_bf(xs[i], h, l);
            Ahi[px * 40 + ddl] = h;
            Alo[px * 40 + ddl] = l;
        }
        __syncthreads();
        if (t < 32) {
            float s = 0.f;
#pragma unroll
            for (int g = 0; g < 8; ++g) s += avgpart[g * 32 + t];
            avgrow[d0 + t] = s * 0.015625f;
        }
        s16x8 ahi = *(const s16x8*)&Ahi[(w * 16 + lm) * 40 + lk * 8];
        s16x8 alo = *(const s16x8*)&Alo[(w * 16 + lm) * 40 + lk * 8];
#pragma unroll
        for (int nt = 0; nt < 4; ++nt) {
            int e = nt * 16 + lm;
            s16x8 bhi = *(const s16x8*)&WThi[e * 256 + d0 + lk * 8];
            s16x8 blo = *(const s16x8*)&WTlo[e * 256 + d0 + lk * 8];
            acc4[nt] = __builtin_amdgcn_mfma_f32_16x16x32_bf16(ahi, blo, acc4[nt], 0, 0, 0);
            acc4[nt] = __builtin_amdgcn_mfma_f32_16x16x32_bf16(alo, bhi, acc4[nt], 0, 0, 0);
            acc4[nt] = __builtin_amdgcn_mfma_f32_16x16x32_bf16(ahi, bhi, acc4[nt], 0, 0, 0);
        }
    }
#pragma unroll
    for (int nt = 0; nt < 4; ++nt) {
        int e = nt * 16 + lm;
#pragma unroll
        for (int r = 0; r < 4; ++r) {
            int px = w * 16 + lk * 4 + r;
            Vvb[((size_t)(b * NHD + (e & 7)) * NTOT + N) * FDIM + px * 8 + (e >> 3)] = f2bf(acc4[nt][r]);
        }
    }
    __syncthreads();
    Vavg[(size_t)blk * DVC + t] = avgrow[t];
}

// ---------------------------------------------------------------------------
// K3b: pack Vvb [bh][N][f] -> Vp fragment order [bh][kt][w][sub][kh][lane][8]
__global__ __launch_bounds__(256) void k3b_pack(
    const unsigned short* __restrict__ Vvb, unsigned short* __restrict__ Vp) {
    __shared__ unsigned short tile[32 * 520];
    int kt = blockIdx.x, bh = blockIdx.y;
    int t = threadIdx.x;
    const unsigned short* src = Vvb + ((size_t)bh * NTOT + kt * 32) * FDIM;
#pragma unroll
    for (int it = 0; it < 8; ++it) {
        int flat = it * 256 + t;
        int r = flat >> 6, c8 = (flat & 63) * 8;
        *(u16x8*)&tile[r * 520 + c8] = *(const u16x8*)&src[(size_t)r * FDIM + c8];
    }
    __syncthreads();
    unsigned short* dst = Vp + ((size_t)bh * 49 + kt) * 16384;
#pragma unroll
    for (int it = 0; it < 8; ++it) {
        int flato = it * 256 + t;
        int lane = flato & 63;
        int kh = (flato >> 6) & 1;
        int sub = (flato >> 7) & 3;
        int w = flato >> 9;
        int l31 = lane & 31, hh = lane >> 5;
        int f = w * 128 + sub * 32 + l31;
        int kbase = kh * 16 + hh * 8;
        u16x8 v;
#pragma unroll
        for (int j = 0; j < 8; ++j) v[j] = tile[(kbase + j) * 520 + f];
        *(u16x8*)&dst[(size_t)flato * 8] = v;
    }
}

// ---------------------------------------------------------------------------
// K4: flash attention; zero-LDS zero-barrier main loop, coalesced packed
// fragment loads, 1-deep K prefetch. (unchanged from R5)
__global__ __launch_bounds__(256) void k4_attn(
    const unsigned short* __restrict__ Qp, const unsigned short* __restrict__ Kp,
    const unsigned short* __restrict__ Vp, float* __restrict__ rw) {
    __shared__ float ebuf[32 * 132];
    int wg = blockIdx.x;
    int qt = wg >> 4, bh = wg & 15;
    int q0 = qt * 32;
    int t = threadIdx.x;
    int w = t >> 6, lane = t & 63;
    int l31 = lane & 31, hh = lane >> 5;

    const unsigned short* __restrict__ Qpb = Qp + ((size_t)(bh * 49 + qt) * 4) * 512 + lane * 8;
    const unsigned short* __restrict__ Kpb = Kp + (size_t)bh * 49 * 2048 + lane * 8;
    const unsigned short* __restrict__ Vpb = Vp + (size_t)bh * 49 * 16384 + lane * 8;

    s16x8 qa0 = *(const s16x8*)&Qpb[0];
    s16x8 qa1 = *(const s16x8*)&Qpb[512];
    s16x8 ql0 = *(const s16x8*)&Qpb[1024];
    s16x8 ql1 = *(const s16x8*)&Qpb[1536];

    s16x8 ka0 = *(const s16x8*)&Kpb[0];
    s16x8 ka1 = *(const s16x8*)&Kpb[512];
    s16x8 kl0 = *(const s16x8*)&Kpb[1024];
    s16x8 kl1 = *(const s16x8*)&Kpb[1536];

    float m = -1e30f, lsum = 0.f;
    f32x16 acc[4];
#pragma unroll
    for (int s = 0; s < 4; ++s) acc[s] = (f32x16)0.f;

    for (int kt = 0; kt < NTOT / 32; ++kt) {
        const unsigned short* Vtile = Vpb + (size_t)kt * 16384 + (w * 8) * 512;
        s16x8 va[8];
#pragma unroll
        for (int fr = 0; fr < 8; ++fr)
            va[fr] = *(const s16x8*)&Vtile[fr * 512];
        int ktn = (kt < 48) ? kt + 1 : 48;
        const unsigned short* Ktn = Kpb + (size_t)ktn * 2048;
        s16x8 kn0 = *(const s16x8*)&Ktn[0];
        s16x8 kn1 = *(const s16x8*)&Ktn[512];
        s16x8 kn2 = *(const s16x8*)&Ktn[1024];
        s16x8 kn3 = *(const s16x8*)&Ktn[1536];

        f32x16 sacc = (f32x16)0.f;
        sacc = __builtin_amdgcn_mfma_f32_32x32x16_bf16(kl0, qa0, sacc, 0, 0, 0);
        sacc = __builtin_amdgcn_mfma_f32_32x32x16_bf16(ka0, ql0, sacc, 0, 0, 0);
        sacc = __builtin_amdgcn_mfma_f32_32x32x16_bf16(ka0, qa0, sacc, 0, 0, 0);
        sacc = __builtin_amdgcn_mfma_f32_32x32x16_bf16(kl1, qa1, sacc, 0, 0, 0);
        sacc = __builtin_amdgcn_mfma_f32_32x32x16_bf16(ka1, ql1, sacc, 0, 0, 0);
        sacc = __builtin_amdgcn_mfma_f32_32x32x16_bf16(ka1, qa1, sacc, 0, 0, 0);

        float tmax = sacc[0];
#pragma unroll
        for (int r = 1; r < 16; ++r) tmax = fmaxf(tmax, sacc[r]);
        tmax = fmaxf(tmax, __shfl_xor(tmax, 32, 64));
        if (__any(tmax > m + 8.f)) {
            float mn = fmaxf(m, tmax);
            float sc = __expf(m - mn);
#pragma unroll
            for (int s = 0; s < 4; ++s) acc[s] = acc[s] * sc;
            lsum *= sc;
            m = mn;
        }
        unsigned P2[8];
        float tsum = 0.f;
#pragma unroll
        for (int j = 0; j < 8; ++j) {
            float pa = __expf(sacc[2 * j] - m);
            float pb = __expf(sacc[2 * j + 1] - m);
            tsum += pa + pb;
            P2[j] = cvt_pk_bf16(pa, pb);
        }
        lsum += tsum + __shfl_xor(tsum, 32, 64);
        unsigned X2[8];
#pragma unroll
        for (int j = 0; j < 8; ++j) X2[j] = (unsigned)__shfl_xor((int)P2[j], 32, 64);
        u32x4 b0u, b1u;
        if (hh == 0) {
            b0u[0] = P2[0]; b0u[1] = P2[1]; b0u[2] = X2[0]; b0u[3] = X2[1];
            b1u[0] = P2[4]; b1u[1] = P2[5]; b1u[2] = X2[4]; b1u[3] = X2[5];
        } else {
            b0u[0] = X2[2]; b0u[1] = X2[3]; b0u[2] = P2[2]; b0u[3] = P2[3];
            b1u[0] = X2[6]; b1u[1] = X2[7]; b1u[2] = P2[6]; b1u[3] = P2[7];
        }
        s16x8 pb0 = __builtin_bit_cast(s16x8, b0u);
        s16x8 pb1 = __builtin_bit_cast(s16x8, b1u);

#pragma unroll
        for (int sub = 0; sub < 4; ++sub) {
            acc[sub] = __builtin_amdgcn_mfma_f32_32x32x16_bf16(va[2 * sub],     pb0, acc[sub], 0, 0, 0);
            acc[sub] = __builtin_amdgcn_mfma_f32_32x32x16_bf16(va[2 * sub + 1], pb1, acc[sub], 0, 0, 0);
        }
        ka0 = kn0; ka1 = kn1; kl0 = kn2; kl1 = kn3;
    }

    float inv = 1.f / lsum;
    float* rwg = rw + ((size_t)bh * NTOT + q0) * FDIM;
#pragma unroll
    for (int c = 0; c < 4; ++c) {
        __syncthreads();
        if (w == c) {
#pragma unroll
            for (int sub = 0; sub < 4; ++sub) {
#pragma unroll
                for (int r = 0; r < 16; ++r) {
                    int fl = sub * 32 + (r & 3) + 8 * (r >> 2) + 4 * hh;
                    ebuf[l31 * 132 + fl] = acc[sub][r] * inv;
                }
            }
        }
        __syncthreads();
        int qr = t >> 3, cb = (t & 7) * 16;
#pragma unroll
        for (int j = 0; j < 4; ++j) {
            *(float4*)&rwg[(size_t)qr * FDIM + c * 128 + cb + j * 4] =
                *(const float4*)&ebuf[qr * 132 + cb + j * 4];
        }
    }
}

// ---------------------------------------------------------------------------
// K5: MFMA GEMM per window: out(64n x 256c) = rwL(64n x 64j) @ Wback(64j x 256c)
// computed as D[c][n] = sum_j WbT[c][j] * rwL[n][j], 3-term bf16 hi/lo split.
// A-frags from packed Wp (global, L2-hot); B staged in swizzled LDS.
__global__ __launch_bounds__(256) void k5_back(
    const float* __restrict__ rw, const unsigned short* __restrict__ Wp,
    float* __restrict__ out) {
    __shared__ unsigned short SB[2 * 64 * 72];   // hi plane, lo plane (18.4 KB)
    unsigned short* BhL = SB;
    unsigned short* BlL = SB + 64 * 72;
    int blk = blockIdx.x;
    int b = blk / NTOT, N = blk % NTOT;
    int src = N / NSRC, nloc = N % NSRC;
    int wh = nloc / 28, ww = nloc % 28;
    int t = threadIdx.x;
    int w = t >> 6, lane = t & 63;
    int lm = lane & 15, lk = lane >> 4;
    int pbase = (b * 224 + wh * 8) * 224 + ww * 8;

    // ---- stage rw -> split -> swizzled LDS B[n][j] ----
#pragma unroll
    for (int i = 0; i < 4; ++i) {
        int flat4 = i * 256 + t;                 // 0..1023
        int h = flat4 >> 7;
        int f0 = (flat4 & 127) * 4;
        float4 v = *(const float4*)&rw[((size_t)(b * NHD + h) * NTOT + N) * FDIM + f0];
        int n = f0 >> 3;
        int ebase = f0 & 7;                      // 0 or 4
        float vv[4] = {v.x, v.y, v.z, v.w};
#pragma unroll
        for (int u = 0; u < 4; ++u) {
            int j8 = ebase + u;                  // j = (e)*8 + h, e = ebase+u
            unsigned short h16, l16;
            split_bf(vv[u], h16, l16);
            int col = ((j8 ^ (n & 7)) << 3) | h;
            BhL[n * 72 + col] = h16;
            BlL[n * 72 + col] = l16;
        }
    }
    __syncthreads();

    // ---- MFMA: D[c][n], wave w owns c in [w*64, w*64+64) ----
    f32x4 acc[4][4];
#pragma unroll
    for (int mi = 0; mi < 4; ++mi)
#pragma unroll
        for (int nt = 0; nt < 4; ++nt) acc[mi][nt] = (f32x4)0.f;

    const unsigned short* Wpw = Wp + (size_t)(w * 4) * 2048 + lane * 8;
#pragma unroll
    for (int kc = 0; kc < 2; ++kc) {
        s16x8 Ah[4], Al[4], Bh4[4], Bl4[4];
#pragma unroll
        for (int mi = 0; mi < 4; ++mi) {
            int base = mi * 2048 + kc * 1024;
            Ah[mi] = *(const s16x8*)&Wpw[base];
            Al[mi] = *(const s16x8*)&Wpw[base + 512];
        }
#pragma unroll
        for (int nt = 0; nt < 4; ++nt) {
            int n = nt * 16 + lm;
            int addr = n * 72 + (((kc * 4 + lk) ^ (n & 7)) << 3);
            Bh4[nt] = *(const s16x8*)&BhL[addr];
            Bl4[nt] = *(const s16x8*)&BlL[addr];
        }
#pragma unroll
        for (int mi = 0; mi < 4; ++mi)
#pragma unroll
            for (int nt = 0; nt < 4; ++nt) {
                acc[mi][nt] = __builtin_amdgcn_mfma_f32_16x16x32_bf16(Ah[mi], Bl4[nt], acc[mi][nt], 0, 0, 0);
                acc[mi][nt] = __builtin_amdgcn_mfma_f32_16x16x32_bf16(Al[mi], Bh4[nt], acc[mi][nt], 0, 0, 0);
                acc[mi][nt] = __builtin_amdgcn_mfma_f32_16x16x32_bf16(Ah[mi], Bh4[nt], acc[mi][nt], 0, 0, 0);
            }
    }

    // ---- epilogue: 4 chunks of 64 c via LDS transpose, coalesced stores ----
    float* eb = (float*)SB;                       // 64 x 68 fp32 = 17.4 KB
    float* outp = out + (size_t)src * OUT_PER_SRC;
#pragma unroll
    for (int ch = 0; ch < 4; ++ch) {
        __syncthreads();
        if (w == ch) {
#pragma unroll
            for (int mi = 0; mi < 4; ++mi)
#pragma unroll
                for (int nt = 0; nt < 4; ++nt)
#pragma unroll
                    for (int r = 0; r < 4; ++r) {
                        int n = nt * 16 + lm;
                        int cl = mi * 16 + lk * 4 + r;    // c - ch*64
                        eb[n * 68 + cl] = acc[mi][nt][r];
                    }
        }
        __syncthreads();
#pragma unroll
        for (int i = 0; i < 4; ++i) {
            int fl4 = i * 256 + t;               // 0..1023
            int n = fl4 >> 4, c4 = (fl4 & 15) * 4;
            int opix = pbase + (n >> 3) * 224 + (n & 7);
            *(float4*)&outp[(size_t)opix * DVC + ch * 64 + c4] =
                *(const float4*)&eb[n * 68 + c4];
        }
    }
}

// ---------------------------------------------------------------------------
extern "C" void kernel_launch(void* const* d_in, const int* in_sizes, int n_in,
                              void* d_out, int out_size, void* d_ws, size_t ws_size,
                              hipStream_t stream) {
    const float* v0   = (const float*)d_in[0];
    const float* c0   = (const float*)d_in[1];
    const float* v1   = (const float*)d_in[2];
    const float* c1   = (const float*)d_in[3];
    const float* Wqkv = (const float*)d_in[4];
    const float* bqkv = (const float*)d_in[5];
    const float* gv   = (const float*)d_in[6];
    const float* Wqkc = (const float*)d_in[7];
    const float* bqkc = (const float*)d_in[8];
    const float* gc   = (const float*)d_in[9];
    const float* Wv   = (const float*)d_in[10];
    const float* Wbk  = (const float*)d_in[11];

    float* ws = (float*)d_ws;
    float* rw   = ws;                        // 12,845,056 fl (aliases Vavg/Cavg)
    float* Vavg = ws;                        //    802,816 fl
    float* Cavg = ws + 802816;               //    200,704 fl
    unsigned short* Qp   = (unsigned short*)(ws + 12845056);  // 1,605,632 u16
    unsigned short* Kp   = (unsigned short*)(ws + 13647872);  // 1,605,632 u16
    unsigned short* WThi = (unsigned short*)(ws + 14450688);  //    16,384 u16
    unsigned short* WTlo = (unsigned short*)(ws + 14458880);  //    16,384 u16
    unsigned short* Vvb  = (unsigned short*)(ws + 14467072);  // 12,845,056 u16
    unsigned short* Vp   = (unsigned short*)(ws + 20889600);  // 12,845,056 u16
    unsigned short* Wp   = (unsigned short*)(ws + 27312128);  //    65,536 u16
    // total ends at 27,344,896 fl = 109.4 MB (<= 110.8 MB proven in R1-R3)

    float* outp = (float*)d_out;

    kz_zero  <<<1568, 256, 0, stream>>>(Qp);   // zeros Qp+Kp (contiguous)
    k0_wsplit<<<64, 256, 0, stream>>>(Wv, WThi, WTlo);
    k0b_wback<<<256, 256, 0, stream>>>(Wbk, Wp);
    k3_vv    <<<2 * NTOT, 256, 0, stream>>>(v0, v1, WThi, WTlo, Vvb, Vavg);
    k1c_avg  <<<784, 256, 0, stream>>>(c0, c1, Cavg);
    k2_qk    <<<2 * NTOT, 256, 0, stream>>>(Vavg, Cavg, Wqkv, bqkv, gv, Wqkc, bqkc, gc, Qp, Kp);
    k3b_pack <<<dim3(49, 16), 256, 0, stream>>>(Vvb, Vp);
    k4_attn  <<<784, 256, 0, stream>>>(Qp, Kp, Vp, rw);
    k5_back  <<<2 * NTOT, 256, 0, stream>>>(rw, Wp, outp);
}

// Round 8
// 389.866 us; speedup vs baseline: 3.1323x; 1.0040x over previous
//
#include <hip/hip_runtime.h>

#define NSRC 784
#define NTOT 1568
#define NHD 8
#define DVC 256
#define DCC 64
#define D20 20
#define FDIM 512
#define OUT_PER_SRC 25690112

typedef short s16x8 __attribute__((ext_vector_type(8)));
typedef unsigned short u16x8 __attribute__((ext_vector_type(8)));
typedef unsigned short u16x4 __attribute__((ext_vector_type(4)));
typedef float f32x4 __attribute__((ext_vector_type(4)));
typedef float f32x16 __attribute__((ext_vector_type(16)));
typedef unsigned u32x4 __attribute__((ext_vector_type(4)));

__device__ __forceinline__ unsigned short f2bf(float x) {
    unsigned u = __float_as_uint(x);
    unsigned r = (u + 0x7FFFu + ((u >> 16) & 1u)) >> 16;   // RNE
    return (unsigned short)r;
}

__device__ __forceinline__ unsigned cvt_pk_bf16(float lo, float hi) {
    unsigned r;
    asm volatile("v_cvt_pk_bf16_f32 %0, %1, %2" : "=v"(r) : "v"(lo), "v"(hi));
    return r;
}

// split float into bf16 hi + bf16 lo correction (x ~= hi + lo)
__device__ __forceinline__ void split_bf(float x, unsigned short& hi, unsigned short& lo) {
    unsigned short h = f2bf(x);
    float hf = __uint_as_float(((unsigned)h) << 16);
    hi = h;
    lo = f2bf(x - hf);
}

// ---------------------------------------------------------------------------
// KZ: zero Qp+Kp (contiguous) — clears the d in [20,32) pad slots
__global__ __launch_bounds__(256) void kz_zero(unsigned short* __restrict__ p) {
    size_t i = (size_t)blockIdx.x * 256 + threadIdx.x;
    u16x8 z = (u16x8)0;
    *(u16x8*)&p[i * 8] = z;
}

// ---------------------------------------------------------------------------
// K0: split Wv(256x64 fp32) -> WT hi/lo bf16 [e=64][dd=256] (transposed)
__global__ __launch_bounds__(256) void k0_wsplit(
    const float* __restrict__ Wv,
    unsigned short* __restrict__ WThi, unsigned short* __restrict__ WTlo) {
    int e = blockIdx.x, dd = threadIdx.x;
    float x = Wv[dd * DCC + e];
    unsigned short h, l;
    split_bf(x, h, l);
    WThi[e * 256 + dd] = h;
    WTlo[e * 256 + dd] = l;
}

// ---------------------------------------------------------------------------
// K0b: pack Wback(64j x 256c) -> A-fragment order hi/lo:
// Wp[mt16][kc2][hl2][lane64][jj8]; element = Wb[j = kc*32+(lane>>4)*8+jj][c = mt*16+(lane&15)]
__global__ __launch_bounds__(256) void k0b_wback(
    const float* __restrict__ Wb, unsigned short* __restrict__ Wp) {
    int idx = blockIdx.x * 256 + threadIdx.x;        // 0..65535
    int jj = idx & 7, lane = (idx >> 3) & 63, hl = (idx >> 9) & 1;
    int kc = (idx >> 10) & 1, mt = idx >> 11;
    int c = mt * 16 + (lane & 15);
    int j = kc * 32 + (lane >> 4) * 8 + jj;
    unsigned short h, l;
    split_bf(Wb[j * 256 + c], h, l);
    Wp[idx] = hl ? l : h;
}

// ---------------------------------------------------------------------------
// K1c: window average of coords only
__global__ __launch_bounds__(256) void k1c_avg(
    const float* __restrict__ c0, const float* __restrict__ c1,
    float* __restrict__ Cavg) {
    int wi = blockIdx.x * 4 + (threadIdx.x >> 6);
    int d = threadIdx.x & 63;
    int b = wi / NTOT, N = wi % NTOT;
    int src = N / NSRC, nloc = N % NSRC;
    int wh = nloc / 28, ww = nloc % 28;
    const float* __restrict__ C = src ? c1 : c0;
    int pbase = (b * 224 + wh * 8) * 224 + ww * 8;
    float s = 0.f;
#pragma unroll 8
    for (int p = 0; p < 64; ++p)
        s += C[(size_t)(pbase + (p >> 3) * 224 + (p & 7)) * DCC + d];
    Cavg[(size_t)wi * DCC + d] = s * 0.015625f;
}

// ---------------------------------------------------------------------------
// K2: qk = rmsnorm(avg @ Wqk + b, g); writes Q/K bf16 hi/lo fragments
// DIRECTLY in k4's packed lane order (see R5 comments).
__global__ __launch_bounds__(256) void k2_qk(
    const float* __restrict__ Vavg, const float* __restrict__ Cavg,
    const float* __restrict__ Wqkv, const float* __restrict__ bqkv, const float* __restrict__ gv,
    const float* __restrict__ Wqkc, const float* __restrict__ bqkc, const float* __restrict__ gc,
    unsigned short* __restrict__ Qp, unsigned short* __restrict__ Kp) {
    __shared__ float xv[DVC];
    __shared__ float xc[DCC];
    __shared__ float wred[4];
    int blk = blockIdx.x;
    int b = blk / NTOT, N = blk % NTOT;
    int t = threadIdx.x;
    int tile = N >> 5, l31 = N & 31;
    xv[t] = Vavg[(size_t)blk * DVC + t];
    if (t < DCC) xc[t] = Cavg[(size_t)blk * DCC + t];
    __syncthreads();
    float yv = bqkv[t];
#pragma unroll 4
    for (int d = 0; d < DVC; ++d) yv += xv[d] * Wqkv[d * 256 + t];
    float ss = yv * yv;
#pragma unroll
    for (int off = 32; off; off >>= 1) ss += __shfl_xor(ss, off, 64);
    if ((t & 63) == 0) wred[t >> 6] = ss;
    __syncthreads();
    float tot = wred[0] + wred[1] + wred[2] + wred[3];
    float rv = rsqrtf(tot * (1.f / 256.f) + 1e-6f);
    float yn = yv * rv * gv[t];
    int h = t >> 5, c = t & 31;
    int bh = b * NHD + h;
    {
        int isq = (c < 16);
        int d = isq ? c : c - 16;
        float val = isq ? yn * 0.088388347648318447f : yn;
        unsigned short h16, l16;
        split_bf(val, h16, l16);
        int hh = d >> 3, j = d & 7;
        size_t base = ((size_t)(bh * 49 + tile) * 4) * 512 + (size_t)(hh * 32 + l31) * 8 + j;
        unsigned short* dst = isq ? Qp : Kp;
        dst[base] = h16;
        dst[base + 1024] = l16;
    }
    if (t < DCC) {
        float yc = bqkc[t];
#pragma unroll 4
        for (int d = 0; d < DCC; ++d) yc += xc[d] * Wqkc[d * 64 + t];
        float sc = yc * yc;
#pragma unroll
        for (int off = 32; off; off >>= 1) sc += __shfl_xor(sc, off, 64);
        float rc = rsqrtf(sc * (1.f / 64.f) + 1e-6f);
        float ycn = yc * rc * gc[t];
        int h2 = t >> 3, c2 = t & 7;
        int bh2 = b * NHD + h2;
        int isq = (c2 < 4);
        int dd = isq ? c2 : c2 - 4;
        float val = isq ? ycn * 0.17677669529663687f : ycn;
        unsigned short h16, l16;
        split_bf(val, h16, l16);
        size_t base = ((size_t)(bh2 * 49 + tile) * 4 + 1) * 512 + (size_t)l31 * 8 + dd;
        unsigned short* dst = isq ? Qp : Kp;
        dst[base] = h16;
        dst[base + 1024] = l16;
    }
}

// ---------------------------------------------------------------------------
// K3: MFMA GEMM per window: X(64px x 256) @ Wv(256x64) -> Vv bf16 [bh][N][f]
// R8 restructure: 2 phases of K=128; per-wave 64-lane float4 staging
// (2x512B segments/instr), u16x4 LDS writes (stride 138 -> bank-parity
// split), 3 barriers total; window-average from staged registers.
__global__ __launch_bounds__(256) void k3_vv(
    const float* __restrict__ v0, const float* __restrict__ v1,
    const unsigned short* __restrict__ WThi, const unsigned short* __restrict__ WTlo,
    unsigned short* __restrict__ Vvb, float* __restrict__ Vavg) {
    __shared__ unsigned short Ahi[64 * 138];    // [px][d-in-phase]
    __shared__ unsigned short Alo[64 * 138];
    int blk = blockIdx.x;
    int b = blk / NTOT, N = blk % NTOT;
    int src = N / NSRC, nloc = N % NSRC;
    int wh = nloc / 28, ww = nloc % 28;
    const float* __restrict__ V = src ? v1 : v0;
    int t = threadIdx.x;
    int w = t >> 6, lane = t & 63;
    int lm = lane & 15, lk = lane >> 4;
    int pxw = w * 16;
    int lhalf = lane >> 5;           // 0/1: which px of the pair
    int d4 = (lane & 31) * 4;        // d offset within the 128-phase
    int pbase = (b * 224 + wh * 8) * 224 + ww * 8;

    float ap[8] = {0.f, 0.f, 0.f, 0.f, 0.f, 0.f, 0.f, 0.f};  // [ph*4+c] avg partials
    f32x4 acc4[4];
#pragma unroll
    for (int nt = 0; nt < 4; ++nt) acc4[nt] = (f32x4)0.f;

#pragma unroll
    for (int ph = 0; ph < 2; ++ph) {
        int d0 = ph * 128;
        // ---- stage: 8 independent 64-lane float4 loads (2x512B segments) ----
        float4 xs[8];
#pragma unroll
        for (int i = 0; i < 8; ++i) {
            int px = pxw + i * 2 + lhalf;
            xs[i] = *(const float4*)&V[(size_t)(pbase + (px >> 3) * 224 + (px & 7)) * DVC + d0 + d4];
        }
#pragma unroll
        for (int i = 0; i < 8; ++i) {
            ap[ph * 4 + 0] += xs[i].x; ap[ph * 4 + 1] += xs[i].y;
            ap[ph * 4 + 2] += xs[i].z; ap[ph * 4 + 3] += xs[i].w;
        }
        if (ph) __syncthreads();     // phase-0 MFMA reads done before overwrite
#pragma unroll
        for (int i = 0; i < 8; ++i) {
            int px = pxw + i * 2 + lhalf;
            u16x4 h4, l4;
            unsigned short hq, lq;
            split_bf(xs[i].x, hq, lq); h4[0] = hq; l4[0] = lq;
            split_bf(xs[i].y, hq, lq); h4[1] = hq; l4[1] = lq;
            split_bf(xs[i].z, hq, lq); h4[2] = hq; l4[2] = lq;
            split_bf(xs[i].w, hq, lq); h4[3] = hq; l4[3] = lq;
            *(u16x4*)&Ahi[px * 138 + d4] = h4;
            *(u16x4*)&Alo[px * 138 + d4] = l4;
        }
        __syncthreads();             // tile staged
        // ---- MFMA: 4 chunks of K=32 ----
#pragma unroll
        for (int c2 = 0; c2 < 4; ++c2) {
            int dd0 = c2 * 32;
            s16x8 ahi = *(const s16x8*)&Ahi[(pxw + lm) * 138 + dd0 + lk * 8];
            s16x8 alo = *(const s16x8*)&Alo[(pxw + lm) * 138 + dd0 + lk * 8];
#pragma unroll
            for (int nt = 0; nt < 4; ++nt) {
                int e = nt * 16 + lm;
                s16x8 bhi = *(const s16x8*)&WThi[e * 256 + d0 + dd0 + lk * 8];
                s16x8 blo = *(const s16x8*)&WTlo[e * 256 + d0 + dd0 + lk * 8];
                acc4[nt] = __builtin_amdgcn_mfma_f32_16x16x32_bf16(ahi, blo, acc4[nt], 0, 0, 0);
                acc4[nt] = __builtin_amdgcn_mfma_f32_16x16x32_bf16(alo, bhi, acc4[nt], 0, 0, 0);
                acc4[nt] = __builtin_amdgcn_mfma_f32_16x16x32_bf16(ahi, bhi, acc4[nt], 0, 0, 0);
            }
        }
    }
    // ---- epilogue: Vvb stores (C 16x16 layout: col=lm, row=lk*4+r) ----
#pragma unroll
    for (int nt = 0; nt < 4; ++nt) {
        int e = nt * 16 + lm;
#pragma unroll
        for (int r = 0; r < 4; ++r) {
            int px = w * 16 + lk * 4 + r;
            Vvb[((size_t)(b * NHD + (e & 7)) * NTOT + N) * FDIM + px * 8 + (e >> 3)] = f2bf(acc4[nt][r]);
        }
    }
    // ---- window average: combine lane pairs, reduce across waves in LDS ----
#pragma unroll
    for (int j = 0; j < 8; ++j) ap[j] += __shfl_xor(ap[j], 32, 64);
    __syncthreads();                 // all MFMA LDS reads done; reuse Ahi
    float* avgb = (float*)Ahi;       // [w][256] = 4 KB
    if (lhalf == 0) {
#pragma unroll
        for (int ph = 0; ph < 2; ++ph) {
            float4 v4 = make_float4(ap[ph * 4], ap[ph * 4 + 1], ap[ph * 4 + 2], ap[ph * 4 + 3]);
            *(float4*)&avgb[w * 256 + ph * 128 + d4] = v4;
        }
    }
    __syncthreads();
    Vavg[(size_t)blk * DVC + t] =
        (avgb[t] + avgb[256 + t] + avgb[512 + t] + avgb[768 + t]) * 0.015625f;
}

// ---------------------------------------------------------------------------
// K3b: pack Vvb [bh][N][f] -> Vp fragment order [bh][kt][w][sub][kh][lane][8]
__global__ __launch_bounds__(256) void k3b_pack(
    const unsigned short* __restrict__ Vvb, unsigned short* __restrict__ Vp) {
    __shared__ unsigned short tile[32 * 520];
    int kt = blockIdx.x, bh = blockIdx.y;
    int t = threadIdx.x;
    const unsigned short* src = Vvb + ((size_t)bh * NTOT + kt * 32) * FDIM;
#pragma unroll
    for (int it = 0; it < 8; ++it) {
        int flat = it * 256 + t;
        int r = flat >> 6, c8 = (flat & 63) * 8;
        *(u16x8*)&tile[r * 520 + c8] = *(const u16x8*)&src[(size_t)r * FDIM + c8];
    }
    __syncthreads();
    unsigned short* dst = Vp + ((size_t)bh * 49 + kt) * 16384;
#pragma unroll
    for (int it = 0; it < 8; ++it) {
        int flato = it * 256 + t;
        int lane = flato & 63;
        int kh = (flato >> 6) & 1;
        int sub = (flato >> 7) & 3;
        int w = flato >> 9;
        int l31 = lane & 31, hh = lane >> 5;
        int f = w * 128 + sub * 32 + l31;
        int kbase = kh * 16 + hh * 8;
        u16x8 v;
#pragma unroll
        for (int j = 0; j < 8; ++j) v[j] = tile[(kbase + j) * 520 + f];
        *(u16x8*)&dst[(size_t)flato * 8] = v;
    }
}

// ---------------------------------------------------------------------------
// K4: flash attention; zero-LDS zero-barrier main loop, coalesced packed
// fragment loads, 1-deep K prefetch. (unchanged from R5)
__global__ __launch_bounds__(256) void k4_attn(
    const unsigned short* __restrict__ Qp, const unsigned short* __restrict__ Kp,
    const unsigned short* __restrict__ Vp, float* __restrict__ rw) {
    __shared__ float ebuf[32 * 132];
    int wg = blockIdx.x;
    int qt = wg >> 4, bh = wg & 15;
    int q0 = qt * 32;
    int t = threadIdx.x;
    int w = t >> 6, lane = t & 63;
    int l31 = lane & 31, hh = lane >> 5;

    const unsigned short* __restrict__ Qpb = Qp + ((size_t)(bh * 49 + qt) * 4) * 512 + lane * 8;
    const unsigned short* __restrict__ Kpb = Kp + (size_t)bh * 49 * 2048 + lane * 8;
    const unsigned short* __restrict__ Vpb = Vp + (size_t)bh * 49 * 16384 + lane * 8;

    s16x8 qa0 = *(const s16x8*)&Qpb[0];
    s16x8 qa1 = *(const s16x8*)&Qpb[512];
    s16x8 ql0 = *(const s16x8*)&Qpb[1024];
    s16x8 ql1 = *(const s16x8*)&Qpb[1536];

    s16x8 ka0 = *(const s16x8*)&Kpb[0];
    s16x8 ka1 = *(const s16x8*)&Kpb[512];
    s16x8 kl0 = *(const s16x8*)&Kpb[1024];
    s16x8 kl1 = *(const s16x8*)&Kpb[1536];

    float m = -1e30f, lsum = 0.f;
    f32x16 acc[4];
#pragma unroll
    for (int s = 0; s < 4; ++s) acc[s] = (f32x16)0.f;

    for (int kt = 0; kt < NTOT / 32; ++kt) {
        const unsigned short* Vtile = Vpb + (size_t)kt * 16384 + (w * 8) * 512;
        s16x8 va[8];
#pragma unroll
        for (int fr = 0; fr < 8; ++fr)
            va[fr] = *(const s16x8*)&Vtile[fr * 512];
        int ktn = (kt < 48) ? kt + 1 : 48;
        const unsigned short* Ktn = Kpb + (size_t)ktn * 2048;
        s16x8 kn0 = *(const s16x8*)&Ktn[0];
        s16x8 kn1 = *(const s16x8*)&Ktn[512];
        s16x8 kn2 = *(const s16x8*)&Ktn[1024];
        s16x8 kn3 = *(const s16x8*)&Ktn[1536];

        f32x16 sacc = (f32x16)0.f;
        sacc = __builtin_amdgcn_mfma_f32_32x32x16_bf16(kl0, qa0, sacc, 0, 0, 0);
        sacc = __builtin_amdgcn_mfma_f32_32x32x16_bf16(ka0, ql0, sacc, 0, 0, 0);
        sacc = __builtin_amdgcn_mfma_f32_32x32x16_bf16(ka0, qa0, sacc, 0, 0, 0);
        sacc = __builtin_amdgcn_mfma_f32_32x32x16_bf16(kl1, qa1, sacc, 0, 0, 0);
        sacc = __builtin_amdgcn_mfma_f32_32x32x16_bf16(ka1, ql1, sacc, 0, 0, 0);
        sacc = __builtin_amdgcn_mfma_f32_32x32x16_bf16(ka1, qa1, sacc, 0, 0, 0);

        float tmax = sacc[0];
#pragma unroll
        for (int r = 1; r < 16; ++r) tmax = fmaxf(tmax, sacc[r]);
        tmax = fmaxf(tmax, __shfl_xor(tmax, 32, 64));
        if (__any(tmax > m + 8.f)) {
            float mn = fmaxf(m, tmax);
            float sc = __expf(m - mn);
#pragma unroll
            for (int s = 0; s < 4; ++s) acc[s] = acc[s] * sc;
            lsum *= sc;
            m = mn;
        }
        unsigned P2[8];
        float tsum = 0.f;
#pragma unroll
        for (int j = 0; j < 8; ++j) {
            float pa = __expf(sacc[2 * j] - m);
            float pb = __expf(sacc[2 * j + 1] - m);
            tsum += pa + pb;
            P2[j] = cvt_pk_bf16(pa, pb);
        }
        lsum += tsum + __shfl_xor(tsum, 32, 64);
        unsigned X2[8];
#pragma unroll
        for (int j = 0; j < 8; ++j) X2[j] = (unsigned)__shfl_xor((int)P2[j], 32, 64);
        u32x4 b0u, b1u;
        if (hh == 0) {
            b0u[0] = P2[0]; b0u[1] = P2[1]; b0u[2] = X2[0]; b0u[3] = X2[1];
            b1u[0] = P2[4]; b1u[1] = P2[5]; b1u[2] = X2[4]; b1u[3] = X2[5];
        } else {
            b0u[0] = X2[2]; b0u[1] = X2[3]; b0u[2] = P2[2]; b0u[3] = P2[3];
            b1u[0] = X2[6]; b1u[1] = X2[7]; b1u[2] = P2[6]; b1u[3] = P2[7];
        }
        s16x8 pb0 = __builtin_bit_cast(s16x8, b0u);
        s16x8 pb1 = __builtin_bit_cast(s16x8, b1u);

#pragma unroll
        for (int sub = 0; sub < 4; ++sub) {
            acc[sub] = __builtin_amdgcn_mfma_f32_32x32x16_bf16(va[2 * sub],     pb0, acc[sub], 0, 0, 0);
            acc[sub] = __builtin_amdgcn_mfma_f32_32x32x16_bf16(va[2 * sub + 1], pb1, acc[sub], 0, 0, 0);
        }
        ka0 = kn0; ka1 = kn1; kl0 = kn2; kl1 = kn3;
    }

    float inv = 1.f / lsum;
    float* rwg = rw + ((size_t)bh * NTOT + q0) * FDIM;
#pragma unroll
    for (int c = 0; c < 4; ++c) {
        __syncthreads();
        if (w == c) {
#pragma unroll
            for (int sub = 0; sub < 4; ++sub) {
#pragma unroll
                for (int r = 0; r < 16; ++r) {
                    int fl = sub * 32 + (r & 3) + 8 * (r >> 2) + 4 * hh;
                    ebuf[l31 * 132 + fl] = acc[sub][r] * inv;
                }
            }
        }
        __syncthreads();
        int qr = t >> 3, cb = (t & 7) * 16;
#pragma unroll
        for (int j = 0; j < 4; ++j) {
            *(float4*)&rwg[(size_t)qr * FDIM + c * 128 + cb + j * 4] =
                *(const float4*)&ebuf[qr * 132 + cb + j * 4];
        }
    }
}

// ---------------------------------------------------------------------------
// K5: MFMA GEMM per window: out(64n x 256c) = rwL(64n x 64j) @ Wback(64j x 256c)
// computed as D[c][n] = sum_j WbT[c][j] * rwL[n][j], 3-term bf16 hi/lo split.
__global__ __launch_bounds__(256) void k5_back(
    const float* __restrict__ rw, const unsigned short* __restrict__ Wp,
    float* __restrict__ out) {
    __shared__ unsigned short SB[2 * 64 * 72];   // hi plane, lo plane (18.4 KB)
    unsigned short* BhL = SB;
    unsigned short* BlL = SB + 64 * 72;
    int blk = blockIdx.x;
    int b = blk / NTOT, N = blk % NTOT;
    int src = N / NSRC, nloc = N % NSRC;
    int wh = nloc / 28, ww = nloc % 28;
    int t = threadIdx.x;
    int w = t >> 6, lane = t & 63;
    int lm = lane & 15, lk = lane >> 4;
    int pbase = (b * 224 + wh * 8) * 224 + ww * 8;

    // ---- stage rw -> split -> swizzled LDS B[n][j] ----
#pragma unroll
    for (int i = 0; i < 4; ++i) {
        int flat4 = i * 256 + t;                 // 0..1023
        int h = flat4 >> 7;
        int f0 = (flat4 & 127) * 4;
        float4 v = *(const float4*)&rw[((size_t)(b * NHD + h) * NTOT + N) * FDIM + f0];
        int n = f0 >> 3;
        int ebase = f0 & 7;                      // 0 or 4
        float vv[4] = {v.x, v.y, v.z, v.w};
#pragma unroll
        for (int u = 0; u < 4; ++u) {
            int j8 = ebase + u;
            unsigned short h16, l16;
            split_bf(vv[u], h16, l16);
            int col = ((j8 ^ (n & 7)) << 3) | h;
            BhL[n * 72 + col] = h16;
            BlL[n * 72 + col] = l16;
        }
    }
    __syncthreads();

    // ---- MFMA: D[c][n], wave w owns c in [w*64, w*64+64) ----
    f32x4 acc[4][4];
#pragma unroll
    for (int mi = 0; mi < 4; ++mi)
#pragma unroll
        for (int nt = 0; nt < 4; ++nt) acc[mi][nt] = (f32x4)0.f;

    const unsigned short* Wpw = Wp + (size_t)(w * 4) * 2048 + lane * 8;
#pragma unroll
    for (int kc = 0; kc < 2; ++kc) {
        s16x8 Ah[4], Al[4], Bh4[4], Bl4[4];
#pragma unroll
        for (int mi = 0; mi < 4; ++mi) {
            int base = mi * 2048 + kc * 1024;
            Ah[mi] = *(const s16x8*)&Wpw[base];
            Al[mi] = *(const s16x8*)&Wpw[base + 512];
        }
#pragma unroll
        for (int nt = 0; nt < 4; ++nt) {
            int n = nt * 16 + lm;
            int addr = n * 72 + (((kc * 4 + lk) ^ (n & 7)) << 3);
            Bh4[nt] = *(const s16x8*)&BhL[addr];
            Bl4[nt] = *(const s16x8*)&BlL[addr];
        }
#pragma unroll
        for (int mi = 0; mi < 4; ++mi)
#pragma unroll
            for (int nt = 0; nt < 4; ++nt) {
                acc[mi][nt] = __builtin_amdgcn_mfma_f32_16x16x32_bf16(Ah[mi], Bl4[nt], acc[mi][nt], 0, 0, 0);
                acc[mi][nt] = __builtin_amdgcn_mfma_f32_16x16x32_bf16(Al[mi], Bh4[nt], acc[mi][nt], 0, 0, 0);
                acc[mi][nt] = __builtin_amdgcn_mfma_f32_16x16x32_bf16(Ah[mi], Bh4[nt], acc[mi][nt], 0, 0, 0);
            }
    }

    // ---- epilogue: 4 chunks of 64 c via LDS transpose, coalesced stores ----
    float* eb = (float*)SB;                       // 64 x 68 fp32 = 17.4 KB
    float* outp = out + (size_t)src * OUT_PER_SRC;
#pragma unroll
    for (int ch = 0; ch < 4; ++ch) {
        __syncthreads();
        if (w == ch) {
#pragma unroll
            for (int mi = 0; mi < 4; ++mi)
#pragma unroll
                for (int nt = 0; nt < 4; ++nt)
#pragma unroll
                    for (int r = 0; r < 4; ++r) {
                        int n = nt * 16 + lm;
                        int cl = mi * 16 + lk * 4 + r;    // c - ch*64
                        eb[n * 68 + cl] = acc[mi][nt][r];
                    }
        }
        __syncthreads();
#pragma unroll
        for (int i = 0; i < 4; ++i) {
            int fl4 = i * 256 + t;               // 0..1023
            int n = fl4 >> 4, c4 = (fl4 & 15) * 4;
            int opix = pbase + (n >> 3) * 224 + (n & 7);
            *(float4*)&outp[(size_t)opix * DVC + ch * 64 + c4] =
                *(const float4*)&eb[n * 68 + c4];
        }
    }
}

// ---------------------------------------------------------------------------
extern "C" void kernel_launch(void* const* d_in, const int* in_sizes, int n_in,
                              void* d_out, int out_size, void* d_ws, size_t ws_size,
                              hipStream_t stream) {
    const float* v0   = (const float*)d_in[0];
    const float* c0   = (const float*)d_in[1];
    const float* v1   = (const float*)d_in[2];
    const float* c1   = (const float*)d_in[3];
    const float* Wqkv = (const float*)d_in[4];
    const float* bqkv = (const float*)d_in[5];
    const float* gv   = (const float*)d_in[6];
    const float* Wqkc = (const float*)d_in[7];
    const float* bqkc = (const float*)d_in[8];
    const float* gc   = (const float*)d_in[9];
    const float* Wv   = (const float*)d_in[10];
    const float* Wbk  = (const float*)d_in[11];

    float* ws = (float*)d_ws;
    float* rw   = ws;                        // 12,845,056 fl (aliases Vavg/Cavg)
    float* Vavg = ws;                        //    802,816 fl
    float* Cavg = ws + 802816;               //    200,704 fl
    unsigned short* Qp   = (unsigned short*)(ws + 12845056);  // 1,605,632 u16
    unsigned short* Kp   = (unsigned short*)(ws + 13647872);  // 1,605,632 u16
    unsigned short* WThi = (unsigned short*)(ws + 14450688);  //    16,384 u16
    unsigned short* WTlo = (unsigned short*)(ws + 14458880);  //    16,384 u16
    unsigned short* Vvb  = (unsigned short*)(ws + 14467072);  // 12,845,056 u16
    unsigned short* Vp   = (unsigned short*)(ws + 20889600);  // 12,845,056 u16
    unsigned short* Wp   = (unsigned short*)(ws + 27312128);  //    65,536 u16
    // total ends at 27,344,896 fl = 109.4 MB

    float* outp = (float*)d_out;

    kz_zero  <<<1568, 256, 0, stream>>>(Qp);   // zeros Qp+Kp (contiguous)
    k0_wsplit<<<64, 256, 0, stream>>>(Wv, WThi, WTlo);
    k0b_wback<<<256, 256, 0, stream>>>(Wbk, Wp);
    k3_vv    <<<2 * NTOT, 256, 0, stream>>>(v0, v1, WThi, WTlo, Vvb, Vavg);
    k1c_avg  <<<784, 256, 0, stream>>>(c0, c1, Cavg);
    k2_qk    <<<2 * NTOT, 256, 0, stream>>>(Vavg, Cavg, Wqkv, bqkv, gv, Wqkc, bqkc, gc, Qp, Kp);
    k3b_pack <<<dim3(49, 16), 256, 0, stream>>>(Vvb, Vp);
    k4_attn  <<<784, 256, 0, stream>>>(Qp, Kp, Vp, rw);
    k5_back  <<<2 * NTOT, 256, 0, stream>>>(rw, Wp, outp);
}

// Round 9
// 359.041 us; speedup vs baseline: 3.4012x; 1.0859x over previous
//
#include <hip/hip_runtime.h>

#define NSRC 784
#define NTOT 1568
#define NHD 8
#define DVC 256
#define DCC 64
#define D20 20
#define FDIM 512
#define OUT_PER_SRC 25690112

typedef short s16x8 __attribute__((ext_vector_type(8)));
typedef unsigned short u16x8 __attribute__((ext_vector_type(8)));
typedef unsigned short u16x4 __attribute__((ext_vector_type(4)));
typedef float f32x4 __attribute__((ext_vector_type(4)));
typedef float f32x16 __attribute__((ext_vector_type(16)));
typedef unsigned u32x4 __attribute__((ext_vector_type(4)));

__device__ __forceinline__ unsigned short f2bf(float x) {
    unsigned u = __float_as_uint(x);
    unsigned r = (u + 0x7FFFu + ((u >> 16) & 1u)) >> 16;   // RNE
    return (unsigned short)r;
}

__device__ __forceinline__ unsigned cvt_pk_bf16(float lo, float hi) {
    unsigned r;
    asm volatile("v_cvt_pk_bf16_f32 %0, %1, %2" : "=v"(r) : "v"(lo), "v"(hi));
    return r;
}

// split float into bf16 hi + bf16 lo correction (x ~= hi + lo)
__device__ __forceinline__ void split_bf(float x, unsigned short& hi, unsigned short& lo) {
    unsigned short h = f2bf(x);
    float hf = __uint_as_float(((unsigned)h) << 16);
    hi = h;
    lo = f2bf(x - hf);
}

// ---------------------------------------------------------------------------
// KZ: zero Qp+Kp (contiguous) — clears the d in [20,32) pad slots
__global__ __launch_bounds__(256) void kz_zero(unsigned short* __restrict__ p) {
    size_t i = (size_t)blockIdx.x * 256 + threadIdx.x;
    u16x8 z = (u16x8)0;
    *(u16x8*)&p[i * 8] = z;
}

// ---------------------------------------------------------------------------
// K0: split Wv(256x64 fp32) -> WT hi/lo bf16 [e=64][dd=256] (transposed)
__global__ __launch_bounds__(256) void k0_wsplit(
    const float* __restrict__ Wv,
    unsigned short* __restrict__ WThi, unsigned short* __restrict__ WTlo) {
    int e = blockIdx.x, dd = threadIdx.x;
    float x = Wv[dd * DCC + e];
    unsigned short h, l;
    split_bf(x, h, l);
    WThi[e * 256 + dd] = h;
    WTlo[e * 256 + dd] = l;
}

// ---------------------------------------------------------------------------
// K0b: pack Wback(64j x 256c) -> A-fragment order hi/lo
__global__ __launch_bounds__(256) void k0b_wback(
    const float* __restrict__ Wb, unsigned short* __restrict__ Wp) {
    int idx = blockIdx.x * 256 + threadIdx.x;        // 0..65535
    int jj = idx & 7, lane = (idx >> 3) & 63, hl = (idx >> 9) & 1;
    int kc = (idx >> 10) & 1, mt = idx >> 11;
    int c = mt * 16 + (lane & 15);
    int j = kc * 32 + (lane >> 4) * 8 + jj;
    unsigned short h, l;
    split_bf(Wb[j * 256 + c], h, l);
    Wp[idx] = hl ? l : h;
}

// ---------------------------------------------------------------------------
// K1c: window average of coords only
__global__ __launch_bounds__(256) void k1c_avg(
    const float* __restrict__ c0, const float* __restrict__ c1,
    float* __restrict__ Cavg) {
    int wi = blockIdx.x * 4 + (threadIdx.x >> 6);
    int d = threadIdx.x & 63;
    int b = wi / NTOT, N = wi % NTOT;
    int src = N / NSRC, nloc = N % NSRC;
    int wh = nloc / 28, ww = nloc % 28;
    const float* __restrict__ C = src ? c1 : c0;
    int pbase = (b * 224 + wh * 8) * 224 + ww * 8;
    float s = 0.f;
#pragma unroll 8
    for (int p = 0; p < 64; ++p)
        s += C[(size_t)(pbase + (p >> 3) * 224 + (p & 7)) * DCC + d];
    Cavg[(size_t)wi * DCC + d] = s * 0.015625f;
}

// ---------------------------------------------------------------------------
// K2: qk = rmsnorm(avg @ Wqk + b, g); writes Q/K bf16 hi/lo fragments
// DIRECTLY in k4's packed lane order.
__global__ __launch_bounds__(256) void k2_qk(
    const float* __restrict__ Vavg, const float* __restrict__ Cavg,
    const float* __restrict__ Wqkv, const float* __restrict__ bqkv, const float* __restrict__ gv,
    const float* __restrict__ Wqkc, const float* __restrict__ bqkc, const float* __restrict__ gc,
    unsigned short* __restrict__ Qp, unsigned short* __restrict__ Kp) {
    __shared__ float xv[DVC];
    __shared__ float xc[DCC];
    __shared__ float wred[4];
    int blk = blockIdx.x;
    int b = blk / NTOT, N = blk % NTOT;
    int t = threadIdx.x;
    int tile = N >> 5, l31 = N & 31;
    xv[t] = Vavg[(size_t)blk * DVC + t];
    if (t < DCC) xc[t] = Cavg[(size_t)blk * DCC + t];
    __syncthreads();
    float yv = bqkv[t];
#pragma unroll 4
    for (int d = 0; d < DVC; ++d) yv += xv[d] * Wqkv[d * 256 + t];
    float ss = yv * yv;
#pragma unroll
    for (int off = 32; off; off >>= 1) ss += __shfl_xor(ss, off, 64);
    if ((t & 63) == 0) wred[t >> 6] = ss;
    __syncthreads();
    float tot = wred[0] + wred[1] + wred[2] + wred[3];
    float rv = rsqrtf(tot * (1.f / 256.f) + 1e-6f);
    float yn = yv * rv * gv[t];
    int h = t >> 5, c = t & 31;
    int bh = b * NHD + h;
    {
        int isq = (c < 16);
        int d = isq ? c : c - 16;
        float val = isq ? yn * 0.088388347648318447f : yn;
        unsigned short h16, l16;
        split_bf(val, h16, l16);
        int hh = d >> 3, j = d & 7;
        size_t base = ((size_t)(bh * 49 + tile) * 4) * 512 + (size_t)(hh * 32 + l31) * 8 + j;
        unsigned short* dst = isq ? Qp : Kp;
        dst[base] = h16;
        dst[base + 1024] = l16;
    }
    if (t < DCC) {
        float yc = bqkc[t];
#pragma unroll 4
        for (int d = 0; d < DCC; ++d) yc += xc[d] * Wqkc[d * 64 + t];
        float sc = yc * yc;
#pragma unroll
        for (int off = 32; off; off >>= 1) sc += __shfl_xor(sc, off, 64);
        float rc = rsqrtf(sc * (1.f / 64.f) + 1e-6f);
        float ycn = yc * rc * gc[t];
        int h2 = t >> 3, c2 = t & 7;
        int bh2 = b * NHD + h2;
        int isq = (c2 < 4);
        int dd = isq ? c2 : c2 - 4;
        float val = isq ? ycn * 0.17677669529663687f : ycn;
        unsigned short h16, l16;
        split_bf(val, h16, l16);
        size_t base = ((size_t)(bh2 * 49 + tile) * 4 + 1) * 512 + (size_t)l31 * 8 + dd;
        unsigned short* dst = isq ? Qp : Kp;
        dst[base] = h16;
        dst[base + 1024] = l16;
    }
}

// ---------------------------------------------------------------------------
// K3: MFMA GEMM per window: X(64px x 256) @ Wv(256x64) -> Vv bf16.
// R9: XOR-swizzled A-tile (aligned b128, ~2-way banks), batched WT register
// preloads, LDS-transpose epilogue -> coalesced u16x8 stores in layout
// Vvb[b][N][f3=e>>3][h=e&7][px]. Fused exact fp32 window-average.
__global__ __launch_bounds__(256) void k3_vv(
    const float* __restrict__ v0, const float* __restrict__ v1,
    const unsigned short* __restrict__ WThi, const unsigned short* __restrict__ WTlo,
    unsigned short* __restrict__ Vvb, float* __restrict__ Vavg) {
    __shared__ unsigned short Ahi[64 * 128];   // [px][d] XOR-swizzled, 16 KB
    __shared__ unsigned short Alo[64 * 128];
    int blk = blockIdx.x;
    int b = blk / NTOT, N = blk % NTOT;
    int src = N / NSRC, nloc = N % NSRC;
    int wh = nloc / 28, ww = nloc % 28;
    const float* __restrict__ V = src ? v1 : v0;
    int t = threadIdx.x;
    int w = t >> 6, lane = t & 63;
    int lm = lane & 15, lk = lane >> 4;
    int pxw = w * 16;
    int lhalf = lane >> 5;           // which px of the pair
    int d4 = (lane & 31) * 4;        // u16 offset within the 128-d phase
    int pbase = (b * 224 + wh * 8) * 224 + ww * 8;

    float ap[8] = {0.f, 0.f, 0.f, 0.f, 0.f, 0.f, 0.f, 0.f};
    f32x4 acc4[4];
#pragma unroll
    for (int nt = 0; nt < 4; ++nt) acc4[nt] = (f32x4)0.f;

#pragma unroll
    for (int ph = 0; ph < 2; ++ph) {
        int d0 = ph * 128;
        // ---- stage: 8 independent 64-lane float4 loads ----
        float4 xs[8];
#pragma unroll
        for (int i = 0; i < 8; ++i) {
            int px = pxw + i * 2 + lhalf;
            xs[i] = *(const float4*)&V[(size_t)(pbase + (px >> 3) * 224 + (px & 7)) * DVC + d0 + d4];
        }
#pragma unroll
        for (int i = 0; i < 8; ++i) {
            ap[ph * 4 + 0] += xs[i].x; ap[ph * 4 + 1] += xs[i].y;
            ap[ph * 4 + 2] += xs[i].z; ap[ph * 4 + 3] += xs[i].w;
        }
        if (ph) __syncthreads();     // phase-0 MFMA reads done before overwrite
#pragma unroll
        for (int i = 0; i < 8; ++i) {
            int px = pxw + i * 2 + lhalf;
            u16x4 h4, l4;
            unsigned short hq, lq;
            split_bf(xs[i].x, hq, lq); h4[0] = hq; l4[0] = lq;
            split_bf(xs[i].y, hq, lq); h4[1] = hq; l4[1] = lq;
            split_bf(xs[i].z, hq, lq); h4[2] = hq; l4[2] = lq;
            split_bf(xs[i].w, hq, lq); h4[3] = hq; l4[3] = lq;
            int addr = px * 128 + (((d4 >> 3) ^ (px & 7)) << 3) + (d4 & 7);
            *(u16x4*)&Ahi[addr] = h4;
            *(u16x4*)&Alo[addr] = l4;
        }
        __syncthreads();             // tile staged
        // ---- MFMA: 4 chunks of K=32, WT frags batched into registers ----
#pragma unroll
        for (int c2 = 0; c2 < 4; ++c2) {
            int dd0 = c2 * 32;
            s16x8 Bh4[4], Bl4[4];
#pragma unroll
            for (int nt = 0; nt < 4; ++nt) {
                int e = nt * 16 + lm;
                Bh4[nt] = *(const s16x8*)&WThi[e * 256 + d0 + dd0 + lk * 8];
                Bl4[nt] = *(const s16x8*)&WTlo[e * 256 + d0 + dd0 + lk * 8];
            }
            int row = pxw + lm;
            int raddr = row * 128 + ((((dd0 >> 3) + lk) ^ (row & 7)) << 3);
            s16x8 ahi = *(const s16x8*)&Ahi[raddr];
            s16x8 alo = *(const s16x8*)&Alo[raddr];
#pragma unroll
            for (int nt = 0; nt < 4; ++nt) {
                acc4[nt] = __builtin_amdgcn_mfma_f32_16x16x32_bf16(ahi, Bl4[nt], acc4[nt], 0, 0, 0);
                acc4[nt] = __builtin_amdgcn_mfma_f32_16x16x32_bf16(alo, Bh4[nt], acc4[nt], 0, 0, 0);
                acc4[nt] = __builtin_amdgcn_mfma_f32_16x16x32_bf16(ahi, Bh4[nt], acc4[nt], 0, 0, 0);
            }
        }
    }
    // ---- epilogue: C tile -> LDS (bf16) + avg partials -> LDS ----
    __syncthreads();                 // all MFMA LDS reads done
    unsigned short* eb = Ahi;        // [px][e] 64 x 66 u16 = 8.4 KB
#pragma unroll
    for (int nt = 0; nt < 4; ++nt) {
        int e = nt * 16 + lm;
#pragma unroll
        for (int r = 0; r < 4; ++r) {
            int px = pxw + lk * 4 + r;
            eb[px * 66 + e] = f2bf(acc4[nt][r]);
        }
    }
#pragma unroll
    for (int j = 0; j < 8; ++j) ap[j] += __shfl_xor(ap[j], 32, 64);
    float* avgb = (float*)Alo;       // [w][256] f32 = 4 KB
    if (lhalf == 0) {
#pragma unroll
        for (int ph = 0; ph < 2; ++ph) {
            float4 v4 = make_float4(ap[ph * 4], ap[ph * 4 + 1], ap[ph * 4 + 2], ap[ph * 4 + 3]);
            *(float4*)&avgb[w * 256 + ph * 128 + d4] = v4;
        }
    }
    __syncthreads();
    // ---- coalesced stores: Vvb[blk][f3][h][px] as u16x8 ----
    unsigned short* dst = Vvb + (size_t)blk * 4096;
#pragma unroll
    for (int i = 0; i < 2; ++i) {
        int flat16 = i * 256 + t;            // 0..511
        int f3 = flat16 >> 6;
        int h = (flat16 >> 3) & 7;
        int px8 = (flat16 & 7) * 8;
        u16x8 vv;
#pragma unroll
        for (int u = 0; u < 8; ++u) vv[u] = eb[(px8 + u) * 66 + f3 * 8 + h];
        *(u16x8*)&dst[flat16 * 8] = vv;
    }
    Vavg[(size_t)blk * DVC + t] =
        (avgb[t] + avgb[256 + t] + avgb[512 + t] + avgb[768 + t]) * 0.015625f;
}

// ---------------------------------------------------------------------------
// K3b: pack Vvb [b][N][f3][h][px] -> Vp fragment order
// [bh][kt][w][sub][kh][lane][8]; element j = V[f][k = kt*32+kh*16+hh*8+j]
__global__ __launch_bounds__(256) void k3b_pack(
    const unsigned short* __restrict__ Vvb, unsigned short* __restrict__ Vp) {
    __shared__ unsigned short tile[32 * 576];   // [N][f3][72]
    int kt = blockIdx.x, bh = blockIdx.y;
    int b = bh >> 3, h = bh & 7;
    int t = threadIdx.x;
#pragma unroll
    for (int it = 0; it < 8; ++it) {
        int flat = it * 256 + t;                // 0..2047
        int r5 = flat >> 6;                     // N-local 0..31
        int c = flat & 63;
        int f3 = c >> 3, px8 = (c & 7) * 8;
        const unsigned short* s =
            Vvb + ((size_t)(b * NTOT + kt * 32 + r5) * 8 + f3) * 512 + h * 64 + px8;
        *(u16x8*)&tile[r5 * 576 + f3 * 72 + px8] = *(const u16x8*)s;
    }
    __syncthreads();
    unsigned short* dst = Vp + ((size_t)bh * 49 + kt) * 16384;
#pragma unroll
    for (int it = 0; it < 8; ++it) {
        int flato = it * 256 + t;               // 0..2047
        int lane = flato & 63;
        int kh = (flato >> 6) & 1;
        int sub = (flato >> 7) & 3;
        int w = flato >> 9;
        int l31 = lane & 31, hh = lane >> 5;
        int f = w * 128 + sub * 32 + l31;
        int kbase = kh * 16 + hh * 8;
        u16x8 v;
#pragma unroll
        for (int j = 0; j < 8; ++j)
            v[j] = tile[(kbase + j) * 576 + (f & 7) * 72 + (f >> 3)];
        *(u16x8*)&dst[(size_t)flato * 8] = v;
    }
}

// ---------------------------------------------------------------------------
// K4: flash attention; zero-LDS zero-barrier main loop, coalesced packed
// fragment loads, 1-deep K prefetch. (unchanged)
__global__ __launch_bounds__(256) void k4_attn(
    const unsigned short* __restrict__ Qp, const unsigned short* __restrict__ Kp,
    const unsigned short* __restrict__ Vp, float* __restrict__ rw) {
    __shared__ float ebuf[32 * 132];
    int wg = blockIdx.x;
    int qt = wg >> 4, bh = wg & 15;
    int q0 = qt * 32;
    int t = threadIdx.x;
    int w = t >> 6, lane = t & 63;
    int l31 = lane & 31, hh = lane >> 5;

    const unsigned short* __restrict__ Qpb = Qp + ((size_t)(bh * 49 + qt) * 4) * 512 + lane * 8;
    const unsigned short* __restrict__ Kpb = Kp + (size_t)bh * 49 * 2048 + lane * 8;
    const unsigned short* __restrict__ Vpb = Vp + (size_t)bh * 49 * 16384 + lane * 8;

    s16x8 qa0 = *(const s16x8*)&Qpb[0];
    s16x8 qa1 = *(const s16x8*)&Qpb[512];
    s16x8 ql0 = *(const s16x8*)&Qpb[1024];
    s16x8 ql1 = *(const s16x8*)&Qpb[1536];

    s16x8 ka0 = *(const s16x8*)&Kpb[0];
    s16x8 ka1 = *(const s16x8*)&Kpb[512];
    s16x8 kl0 = *(const s16x8*)&Kpb[1024];
    s16x8 kl1 = *(const s16x8*)&Kpb[1536];

    float m = -1e30f, lsum = 0.f;
    f32x16 acc[4];
#pragma unroll
    for (int s = 0; s < 4; ++s) acc[s] = (f32x16)0.f;

    for (int kt = 0; kt < NTOT / 32; ++kt) {
        const unsigned short* Vtile = Vpb + (size_t)kt * 16384 + (w * 8) * 512;
        s16x8 va[8];
#pragma unroll
        for (int fr = 0; fr < 8; ++fr)
            va[fr] = *(const s16x8*)&Vtile[fr * 512];
        int ktn = (kt < 48) ? kt + 1 : 48;
        const unsigned short* Ktn = Kpb + (size_t)ktn * 2048;
        s16x8 kn0 = *(const s16x8*)&Ktn[0];
        s16x8 kn1 = *(const s16x8*)&Ktn[512];
        s16x8 kn2 = *(const s16x8*)&Ktn[1024];
        s16x8 kn3 = *(const s16x8*)&Ktn[1536];

        f32x16 sacc = (f32x16)0.f;
        sacc = __builtin_amdgcn_mfma_f32_32x32x16_bf16(kl0, qa0, sacc, 0, 0, 0);
        sacc = __builtin_amdgcn_mfma_f32_32x32x16_bf16(ka0, ql0, sacc, 0, 0, 0);
        sacc = __builtin_amdgcn_mfma_f32_32x32x16_bf16(ka0, qa0, sacc, 0, 0, 0);
        sacc = __builtin_amdgcn_mfma_f32_32x32x16_bf16(kl1, qa1, sacc, 0, 0, 0);
        sacc = __builtin_amdgcn_mfma_f32_32x32x16_bf16(ka1, ql1, sacc, 0, 0, 0);
        sacc = __builtin_amdgcn_mfma_f32_32x32x16_bf16(ka1, qa1, sacc, 0, 0, 0);

        float tmax = sacc[0];
#pragma unroll
        for (int r = 1; r < 16; ++r) tmax = fmaxf(tmax, sacc[r]);
        tmax = fmaxf(tmax, __shfl_xor(tmax, 32, 64));
        if (__any(tmax > m + 8.f)) {
            float mn = fmaxf(m, tmax);
            float sc = __expf(m - mn);
#pragma unroll
            for (int s = 0; s < 4; ++s) acc[s] = acc[s] * sc;
            lsum *= sc;
            m = mn;
        }
        unsigned P2[8];
        float tsum = 0.f;
#pragma unroll
        for (int j = 0; j < 8; ++j) {
            float pa = __expf(sacc[2 * j] - m);
            float pb = __expf(sacc[2 * j + 1] - m);
            tsum += pa + pb;
            P2[j] = cvt_pk_bf16(pa, pb);
        }
        lsum += tsum + __shfl_xor(tsum, 32, 64);
        unsigned X2[8];
#pragma unroll
        for (int j = 0; j < 8; ++j) X2[j] = (unsigned)__shfl_xor((int)P2[j], 32, 64);
        u32x4 b0u, b1u;
        if (hh == 0) {
            b0u[0] = P2[0]; b0u[1] = P2[1]; b0u[2] = X2[0]; b0u[3] = X2[1];
            b1u[0] = P2[4]; b1u[1] = P2[5]; b1u[2] = X2[4]; b1u[3] = X2[5];
        } else {
            b0u[0] = X2[2]; b0u[1] = X2[3]; b0u[2] = P2[2]; b0u[3] = P2[3];
            b1u[0] = X2[6]; b1u[1] = X2[7]; b1u[2] = P2[6]; b1u[3] = P2[7];
        }
        s16x8 pb0 = __builtin_bit_cast(s16x8, b0u);
        s16x8 pb1 = __builtin_bit_cast(s16x8, b1u);

#pragma unroll
        for (int sub = 0; sub < 4; ++sub) {
            acc[sub] = __builtin_amdgcn_mfma_f32_32x32x16_bf16(va[2 * sub],     pb0, acc[sub], 0, 0, 0);
            acc[sub] = __builtin_amdgcn_mfma_f32_32x32x16_bf16(va[2 * sub + 1], pb1, acc[sub], 0, 0, 0);
        }
        ka0 = kn0; ka1 = kn1; kl0 = kn2; kl1 = kn3;
    }

    float inv = 1.f / lsum;
    float* rwg = rw + ((size_t)bh * NTOT + q0) * FDIM;
#pragma unroll
    for (int c = 0; c < 4; ++c) {
        __syncthreads();
        if (w == c) {
#pragma unroll
            for (int sub = 0; sub < 4; ++sub) {
#pragma unroll
                for (int r = 0; r < 16; ++r) {
                    int fl = sub * 32 + (r & 3) + 8 * (r >> 2) + 4 * hh;
                    ebuf[l31 * 132 + fl] = acc[sub][r] * inv;
                }
            }
        }
        __syncthreads();
        int qr = t >> 3, cb = (t & 7) * 16;
#pragma unroll
        for (int j = 0; j < 4; ++j) {
            *(float4*)&rwg[(size_t)qr * FDIM + c * 128 + cb + j * 4] =
                *(const float4*)&ebuf[qr * 132 + cb + j * 4];
        }
    }
}

// ---------------------------------------------------------------------------
// K5: MFMA GEMM per window: out(64n x 256c) = rwL(64n x 64j) @ Wback(64j x 256c)
__global__ __launch_bounds__(256) void k5_back(
    const float* __restrict__ rw, const unsigned short* __restrict__ Wp,
    float* __restrict__ out) {
    __shared__ unsigned short SB[2 * 64 * 72];   // hi plane, lo plane (18.4 KB)
    unsigned short* BhL = SB;
    unsigned short* BlL = SB + 64 * 72;
    int blk = blockIdx.x;
    int b = blk / NTOT, N = blk % NTOT;
    int src = N / NSRC, nloc = N % NSRC;
    int wh = nloc / 28, ww = nloc % 28;
    int t = threadIdx.x;
    int w = t >> 6, lane = t & 63;
    int lm = lane & 15, lk = lane >> 4;
    int pbase = (b * 224 + wh * 8) * 224 + ww * 8;

#pragma unroll
    for (int i = 0; i < 4; ++i) {
        int flat4 = i * 256 + t;
        int h = flat4 >> 7;
        int f0 = (flat4 & 127) * 4;
        float4 v = *(const float4*)&rw[((size_t)(b * NHD + h) * NTOT + N) * FDIM + f0];
        int n = f0 >> 3;
        int ebase = f0 & 7;
        float vv[4] = {v.x, v.y, v.z, v.w};
#pragma unroll
        for (int u = 0; u < 4; ++u) {
            int j8 = ebase + u;
            unsigned short h16, l16;
            split_bf(vv[u], h16, l16);
            int col = ((j8 ^ (n & 7)) << 3) | h;
            BhL[n * 72 + col] = h16;
            BlL[n * 72 + col] = l16;
        }
    }
    __syncthreads();

    f32x4 acc[4][4];
#pragma unroll
    for (int mi = 0; mi < 4; ++mi)
#pragma unroll
        for (int nt = 0; nt < 4; ++nt) acc[mi][nt] = (f32x4)0.f;

    const unsigned short* Wpw = Wp + (size_t)(w * 4) * 2048 + lane * 8;
#pragma unroll
    for (int kc = 0; kc < 2; ++kc) {
        s16x8 Ah[4], Al[4], Bh4[4], Bl4[4];
#pragma unroll
        for (int mi = 0; mi < 4; ++mi) {
            int base = mi * 2048 + kc * 1024;
            Ah[mi] = *(const s16x8*)&Wpw[base];
            Al[mi] = *(const s16x8*)&Wpw[base + 512];
        }
#pragma unroll
        for (int nt = 0; nt < 4; ++nt) {
            int n = nt * 16 + lm;
            int addr = n * 72 + (((kc * 4 + lk) ^ (n & 7)) << 3);
            Bh4[nt] = *(const s16x8*)&BhL[addr];
            Bl4[nt] = *(const s16x8*)&BlL[addr];
        }
#pragma unroll
        for (int mi = 0; mi < 4; ++mi)
#pragma unroll
            for (int nt = 0; nt < 4; ++nt) {
                acc[mi][nt] = __builtin_amdgcn_mfma_f32_16x16x32_bf16(Ah[mi], Bl4[nt], acc[mi][nt], 0, 0, 0);
                acc[mi][nt] = __builtin_amdgcn_mfma_f32_16x16x32_bf16(Al[mi], Bh4[nt], acc[mi][nt], 0, 0, 0);
                acc[mi][nt] = __builtin_amdgcn_mfma_f32_16x16x32_bf16(Ah[mi], Bh4[nt], acc[mi][nt], 0, 0, 0);
            }
    }

    float* eb = (float*)SB;
    float* outp = out + (size_t)src * OUT_PER_SRC;
#pragma unroll
    for (int ch = 0; ch < 4; ++ch) {
        __syncthreads();
        if (w == ch) {
#pragma unroll
            for (int mi = 0; mi < 4; ++mi)
#pragma unroll
                for (int nt = 0; nt < 4; ++nt)
#pragma unroll
                    for (int r = 0; r < 4; ++r) {
                        int n = nt * 16 + lm;
                        int cl = mi * 16 + lk * 4 + r;
                        eb[n * 68 + cl] = acc[mi][nt][r];
                    }
        }
        __syncthreads();
#pragma unroll
        for (int i = 0; i < 4; ++i) {
            int fl4 = i * 256 + t;
            int n = fl4 >> 4, c4 = (fl4 & 15) * 4;
            int opix = pbase + (n >> 3) * 224 + (n & 7);
            *(float4*)&outp[(size_t)opix * DVC + ch * 64 + c4] =
                *(const float4*)&eb[n * 68 + c4];
        }
    }
}

// ---------------------------------------------------------------------------
extern "C" void kernel_launch(void* const* d_in, const int* in_sizes, int n_in,
                              void* d_out, int out_size, void* d_ws, size_t ws_size,
                              hipStream_t stream) {
    const float* v0   = (const float*)d_in[0];
    const float* c0   = (const float*)d_in[1];
    const float* v1   = (const float*)d_in[2];
    const float* c1   = (const float*)d_in[3];
    const float* Wqkv = (const float*)d_in[4];
    const float* bqkv = (const float*)d_in[5];
    const float* gv   = (const float*)d_in[6];
    const float* Wqkc = (const float*)d_in[7];
    const float* bqkc = (const float*)d_in[8];
    const float* gc   = (const float*)d_in[9];
    const float* Wv   = (const float*)d_in[10];
    const float* Wbk  = (const float*)d_in[11];

    float* ws = (float*)d_ws;
    float* rw   = ws;                        // 12,845,056 fl (aliases Vavg/Cavg)
    float* Vavg = ws;                        //    802,816 fl
    float* Cavg = ws + 802816;               //    200,704 fl
    unsigned short* Qp   = (unsigned short*)(ws + 12845056);  // 1,605,632 u16
    unsigned short* Kp   = (unsigned short*)(ws + 13647872);  // 1,605,632 u16
    unsigned short* WThi = (unsigned short*)(ws + 14450688);  //    16,384 u16
    unsigned short* WTlo = (unsigned short*)(ws + 14458880);  //    16,384 u16
    unsigned short* Vvb  = (unsigned short*)(ws + 14467072);  // 12,845,056 u16
    unsigned short* Vp   = (unsigned short*)(ws + 20889600);  // 12,845,056 u16
    unsigned short* Wp   = (unsigned short*)(ws + 27312128);  //    65,536 u16
    // total ends at 27,344,896 fl = 109.4 MB

    float* outp = (float*)d_out;

    kz_zero  <<<1568, 256, 0, stream>>>(Qp);   // zeros Qp+Kp (contiguous)
    k0_wsplit<<<64, 256, 0, stream>>>(Wv, WThi, WTlo);
    k0b_wback<<<256, 256, 0, stream>>>(Wbk, Wp);
    k3_vv    <<<2 * NTOT, 256, 0, stream>>>(v0, v1, WThi, WTlo, Vvb, Vavg);
    k1c_avg  <<<784, 256, 0, stream>>>(c0, c1, Cavg);
    k2_qk    <<<2 * NTOT, 256, 0, stream>>>(Vavg, Cavg, Wqkv, bqkv, gv, Wqkc, bqkc, gc, Qp, Kp);
    k3b_pack <<<dim3(49, 16), 256, 0, stream>>>(Vvb, Vp);
    k4_attn  <<<784, 256, 0, stream>>>(Qp, Kp, Vp, rw);
    k5_back  <<<2 * NTOT, 256, 0, stream>>>(rw, Wp, outp);
}

// Round 10
// 335.595 us; speedup vs baseline: 3.6388x; 1.0699x over previous
//
#include <hip/hip_runtime.h>

#define NSRC 784
#define NTOT 1568
#define NHD 8
#define DVC 256
#define DCC 64
#define D20 20
#define FDIM 512
#define OUT_PER_SRC 25690112

typedef short s16x8 __attribute__((ext_vector_type(8)));
typedef unsigned short u16x8 __attribute__((ext_vector_type(8)));
typedef unsigned short u16x4 __attribute__((ext_vector_type(4)));
typedef float f32x4 __attribute__((ext_vector_type(4)));
typedef float f32x16 __attribute__((ext_vector_type(16)));
typedef unsigned u32x4 __attribute__((ext_vector_type(4)));

__device__ __forceinline__ unsigned short f2bf(float x) {
    unsigned u = __float_as_uint(x);
    unsigned r = (u + 0x7FFFu + ((u >> 16) & 1u)) >> 16;   // RNE
    return (unsigned short)r;
}

__device__ __forceinline__ unsigned cvt_pk_bf16(float lo, float hi) {
    unsigned r;
    asm volatile("v_cvt_pk_bf16_f32 %0, %1, %2" : "=v"(r) : "v"(lo), "v"(hi));
    return r;
}

// split float into bf16 hi + bf16 lo correction (x ~= hi + lo)
__device__ __forceinline__ void split_bf(float x, unsigned short& hi, unsigned short& lo) {
    unsigned short h = f2bf(x);
    float hf = __uint_as_float(((unsigned)h) << 16);
    hi = h;
    lo = f2bf(x - hf);
}

// ---------------------------------------------------------------------------
// KZ: zero Qp+Kp (contiguous) — clears the d in [20,32) pad slots
__global__ __launch_bounds__(256) void kz_zero(unsigned short* __restrict__ p) {
    size_t i = (size_t)blockIdx.x * 256 + threadIdx.x;
    u16x8 z = (u16x8)0;
    *(u16x8*)&p[i * 8] = z;
}

// ---------------------------------------------------------------------------
// K0c: pack Wv(256dd x 64e) -> A-fragment order hi/lo for k3:
// Wvp[((mi*8 + c)*2 + hl)*512 + lane*8 + j];
// element = Wv[dd = c*32 + (lane>>4)*8 + j][e = mi*16 + (lane&15)]
__global__ __launch_bounds__(256) void k0c_wvpack(
    const float* __restrict__ Wv, unsigned short* __restrict__ Wvp) {
    int idx = blockIdx.x * 256 + threadIdx.x;        // 0..65535
    int j = idx & 7, lane = (idx >> 3) & 63, hl = (idx >> 9) & 1;
    int c = (idx >> 10) & 7, mi = idx >> 13;
    int e = mi * 16 + (lane & 15);
    int dd = c * 32 + (lane >> 4) * 8 + j;
    unsigned short h, l;
    split_bf(Wv[dd * DCC + e], h, l);
    Wvp[idx] = hl ? l : h;
}

// ---------------------------------------------------------------------------
// K0b: pack Wback(64j x 256c) -> A-fragment order hi/lo
__global__ __launch_bounds__(256) void k0b_wback(
    const float* __restrict__ Wb, unsigned short* __restrict__ Wp) {
    int idx = blockIdx.x * 256 + threadIdx.x;        // 0..65535
    int jj = idx & 7, lane = (idx >> 3) & 63, hl = (idx >> 9) & 1;
    int kc = (idx >> 10) & 1, mt = idx >> 11;
    int c = mt * 16 + (lane & 15);
    int j = kc * 32 + (lane >> 4) * 8 + jj;
    unsigned short h, l;
    split_bf(Wb[j * 256 + c], h, l);
    Wp[idx] = hl ? l : h;
}

// ---------------------------------------------------------------------------
// K1c: window average of coords only
__global__ __launch_bounds__(256) void k1c_avg(
    const float* __restrict__ c0, const float* __restrict__ c1,
    float* __restrict__ Cavg) {
    int wi = blockIdx.x * 4 + (threadIdx.x >> 6);
    int d = threadIdx.x & 63;
    int b = wi / NTOT, N = wi % NTOT;
    int src = N / NSRC, nloc = N % NSRC;
    int wh = nloc / 28, ww = nloc % 28;
    const float* __restrict__ C = src ? c1 : c0;
    int pbase = (b * 224 + wh * 8) * 224 + ww * 8;
    float s = 0.f;
#pragma unroll 8
    for (int p = 0; p < 64; ++p)
        s += C[(size_t)(pbase + (p >> 3) * 224 + (p & 7)) * DCC + d];
    Cavg[(size_t)wi * DCC + d] = s * 0.015625f;
}

// ---------------------------------------------------------------------------
// K2: qk = rmsnorm(avg @ Wqk + b, g); writes Q/K bf16 hi/lo fragments
// DIRECTLY in k4's packed lane order.
__global__ __launch_bounds__(256) void k2_qk(
    const float* __restrict__ Vavg, const float* __restrict__ Cavg,
    const float* __restrict__ Wqkv, const float* __restrict__ bqkv, const float* __restrict__ gv,
    const float* __restrict__ Wqkc, const float* __restrict__ bqkc, const float* __restrict__ gc,
    unsigned short* __restrict__ Qp, unsigned short* __restrict__ Kp) {
    __shared__ float xv[DVC];
    __shared__ float xc[DCC];
    __shared__ float wred[4];
    int blk = blockIdx.x;
    int b = blk / NTOT, N = blk % NTOT;
    int t = threadIdx.x;
    int tile = N >> 5, l31 = N & 31;
    xv[t] = Vavg[(size_t)blk * DVC + t];
    if (t < DCC) xc[t] = Cavg[(size_t)blk * DCC + t];
    __syncthreads();
    float yv = bqkv[t];
#pragma unroll 4
    for (int d = 0; d < DVC; ++d) yv += xv[d] * Wqkv[d * 256 + t];
    float ss = yv * yv;
#pragma unroll
    for (int off = 32; off; off >>= 1) ss += __shfl_xor(ss, off, 64);
    if ((t & 63) == 0) wred[t >> 6] = ss;
    __syncthreads();
    float tot = wred[0] + wred[1] + wred[2] + wred[3];
    float rv = rsqrtf(tot * (1.f / 256.f) + 1e-6f);
    float yn = yv * rv * gv[t];
    int h = t >> 5, c = t & 31;
    int bh = b * NHD + h;
    {
        int isq = (c < 16);
        int d = isq ? c : c - 16;
        float val = isq ? yn * 0.088388347648318447f : yn;
        unsigned short h16, l16;
        split_bf(val, h16, l16);
        int hh = d >> 3, j = d & 7;
        size_t base = ((size_t)(bh * 49 + tile) * 4) * 512 + (size_t)(hh * 32 + l31) * 8 + j;
        unsigned short* dst = isq ? Qp : Kp;
        dst[base] = h16;
        dst[base + 1024] = l16;
    }
    if (t < DCC) {
        float yc = bqkc[t];
#pragma unroll 4
        for (int d = 0; d < DCC; ++d) yc += xc[d] * Wqkc[d * 64 + t];
        float sc = yc * yc;
#pragma unroll
        for (int off = 32; off; off >>= 1) sc += __shfl_xor(sc, off, 64);
        float rc = rsqrtf(sc * (1.f / 64.f) + 1e-6f);
        float ycn = yc * rc * gc[t];
        int h2 = t >> 3, c2 = t & 7;
        int bh2 = b * NHD + h2;
        int isq = (c2 < 4);
        int dd = isq ? c2 : c2 - 4;
        float val = isq ? ycn * 0.17677669529663687f : ycn;
        unsigned short h16, l16;
        split_bf(val, h16, l16);
        size_t base = ((size_t)(bh2 * 49 + tile) * 4 + 1) * 512 + (size_t)l31 * 8 + dd;
        unsigned short* dst = isq ? Qp : Kp;
        dst[base] = h16;
        dst[base + 1024] = l16;
    }
}

// ---------------------------------------------------------------------------
// K3: per-window GEMM as D[e][px] = W^T @ X^T — zero-LDS, zero-barrier main
// loop. B-frags (X) read directly from global (coalesced float4 pairs, split
// in-register); A-frags (W) from pre-packed Wvp (L2-hot). Window-average via
// shfl butterfly over the 16 px-lanes + 4KB LDS plane. Epilogue as R9.
__global__ __launch_bounds__(256) void k3_vv(
    const float* __restrict__ v0, const float* __restrict__ v1,
    const unsigned short* __restrict__ Wvp,
    unsigned short* __restrict__ Vvb, float* __restrict__ Vavg) {
    __shared__ unsigned short eb[64 * 66];   // 8.4 KB
    __shared__ float avgw[1024];             // 4 KB
    int blk = blockIdx.x;
    int b = blk / NTOT, N = blk % NTOT;
    int src = N / NSRC, nloc = N % NSRC;
    int wh = nloc / 28, ww = nloc % 28;
    const float* __restrict__ V = src ? v1 : v0;
    int t = threadIdx.x;
    int w = t >> 6, lane = t & 63;
    int lm = lane & 15, lk = lane >> 4;
    int px = w * 16 + lm;
    int pbase = (b * 224 + wh * 8) * 224 + ww * 8;
    const float* __restrict__ xrow =
        V + (size_t)(pbase + (px >> 3) * 224 + (px & 7)) * DVC + lk * 8;

    f32x4 acc[4];
#pragma unroll
    for (int mi = 0; mi < 4; ++mi) acc[mi] = (f32x4)0.f;

#pragma unroll
    for (int c = 0; c < 8; ++c) {
        float4 x0 = *(const float4*)&xrow[c * 32];
        float4 x1 = *(const float4*)&xrow[c * 32 + 4];
        float xv8[8] = {x0.x, x0.y, x0.z, x0.w, x1.x, x1.y, x1.z, x1.w};
        // ---- split to bf16 hi/lo B-frags ----
        u16x8 bhu, blu;
#pragma unroll
        for (int j = 0; j < 8; ++j) {
            unsigned short hq, lq;
            split_bf(xv8[j], hq, lq);
            bhu[j] = hq; blu[j] = lq;
        }
        s16x8 xhi = __builtin_bit_cast(s16x8, bhu);
        s16x8 xlo = __builtin_bit_cast(s16x8, blu);
        // ---- window-average butterfly over lm lanes (bits 0..3) ----
        float sv[8] = {xv8[0], xv8[1], xv8[2], xv8[3], xv8[4], xv8[5], xv8[6], xv8[7]};
#pragma unroll
        for (int off = 1; off <= 8; off <<= 1)
#pragma unroll
            for (int j = 0; j < 8; ++j) sv[j] += __shfl_xor(sv[j], off, 64);
        if (lm == 0) {
#pragma unroll
            for (int j = 0; j < 8; ++j)
                avgw[w * 256 + c * 32 + lk * 8 + j] = sv[j];
        }
        // ---- MFMAs: A-frags from Wvp (L2-hot), 3-term hi/lo ----
#pragma unroll
        for (int mi = 0; mi < 4; ++mi) {
            const unsigned short* Wf = Wvp + (size_t)((mi * 8 + c) * 2) * 512 + lane * 8;
            s16x8 Ah = *(const s16x8*)&Wf[0];
            s16x8 Al = *(const s16x8*)&Wf[512];
            acc[mi] = __builtin_amdgcn_mfma_f32_16x16x32_bf16(Ah, xlo, acc[mi], 0, 0, 0);
            acc[mi] = __builtin_amdgcn_mfma_f32_16x16x32_bf16(Al, xhi, acc[mi], 0, 0, 0);
            acc[mi] = __builtin_amdgcn_mfma_f32_16x16x32_bf16(Ah, xhi, acc[mi], 0, 0, 0);
        }
    }
    // ---- epilogue: C tile -> LDS bf16 (C layout: m=e=mi*16+lk*4+r, n=px=lm) ----
#pragma unroll
    for (int mi = 0; mi < 4; ++mi) {
#pragma unroll
        for (int r = 0; r < 4; ++r) {
            int e = mi * 16 + lk * 4 + r;
            eb[px * 66 + e] = f2bf(acc[mi][r]);
        }
    }
    __syncthreads();
    // ---- coalesced stores: Vvb[blk][f3][h][px] as u16x8 (R9 layout) ----
    unsigned short* dst = Vvb + (size_t)blk * 4096;
#pragma unroll
    for (int i = 0; i < 2; ++i) {
        int flat16 = i * 256 + t;            // 0..511
        int f3 = flat16 >> 6;
        int h = (flat16 >> 3) & 7;
        int px8 = (flat16 & 7) * 8;
        u16x8 vv;
#pragma unroll
        for (int u = 0; u < 8; ++u) vv[u] = eb[(px8 + u) * 66 + f3 * 8 + h];
        *(u16x8*)&dst[flat16 * 8] = vv;
    }
    Vavg[(size_t)blk * DVC + t] =
        (avgw[t] + avgw[256 + t] + avgw[512 + t] + avgw[768 + t]) * 0.015625f;
}

// ---------------------------------------------------------------------------
// K3b: pack Vvb [b][N][f3][h][px] -> Vp fragment order
// [bh][kt][w][sub][kh][lane][8]; element j = V[f][k = kt*32+kh*16+hh*8+j]
__global__ __launch_bounds__(256) void k3b_pack(
    const unsigned short* __restrict__ Vvb, unsigned short* __restrict__ Vp) {
    __shared__ unsigned short tile[32 * 576];   // [N][f3][72]
    int kt = blockIdx.x, bh = blockIdx.y;
    int b = bh >> 3, h = bh & 7;
    int t = threadIdx.x;
#pragma unroll
    for (int it = 0; it < 8; ++it) {
        int flat = it * 256 + t;                // 0..2047
        int r5 = flat >> 6;                     // N-local 0..31
        int c = flat & 63;
        int f3 = c >> 3, px8 = (c & 7) * 8;
        const unsigned short* s =
            Vvb + ((size_t)(b * NTOT + kt * 32 + r5) * 8 + f3) * 512 + h * 64 + px8;
        *(u16x8*)&tile[r5 * 576 + f3 * 72 + px8] = *(const u16x8*)s;
    }
    __syncthreads();
    unsigned short* dst = Vp + ((size_t)bh * 49 + kt) * 16384;
#pragma unroll
    for (int it = 0; it < 8; ++it) {
        int flato = it * 256 + t;               // 0..2047
        int lane = flato & 63;
        int kh = (flato >> 6) & 1;
        int sub = (flato >> 7) & 3;
        int w = flato >> 9;
        int l31 = lane & 31, hh = lane >> 5;
        int f = w * 128 + sub * 32 + l31;
        int kbase = kh * 16 + hh * 8;
        u16x8 v;
#pragma unroll
        for (int j = 0; j < 8; ++j)
            v[j] = tile[(kbase + j) * 576 + (f & 7) * 72 + (f >> 3)];
        *(u16x8*)&dst[(size_t)flato * 8] = v;
    }
}

// ---------------------------------------------------------------------------
// K4: flash attention; zero-LDS zero-barrier main loop, coalesced packed
// fragment loads, 1-deep K prefetch. (unchanged)
__global__ __launch_bounds__(256) void k4_attn(
    const unsigned short* __restrict__ Qp, const unsigned short* __restrict__ Kp,
    const unsigned short* __restrict__ Vp, float* __restrict__ rw) {
    __shared__ float ebuf[32 * 132];
    int wg = blockIdx.x;
    int qt = wg >> 4, bh = wg & 15;
    int q0 = qt * 32;
    int t = threadIdx.x;
    int w = t >> 6, lane = t & 63;
    int l31 = lane & 31, hh = lane >> 5;

    const unsigned short* __restrict__ Qpb = Qp + ((size_t)(bh * 49 + qt) * 4) * 512 + lane * 8;
    const unsigned short* __restrict__ Kpb = Kp + (size_t)bh * 49 * 2048 + lane * 8;
    const unsigned short* __restrict__ Vpb = Vp + (size_t)bh * 49 * 16384 + lane * 8;

    s16x8 qa0 = *(const s16x8*)&Qpb[0];
    s16x8 qa1 = *(const s16x8*)&Qpb[512];
    s16x8 ql0 = *(const s16x8*)&Qpb[1024];
    s16x8 ql1 = *(const s16x8*)&Qpb[1536];

    s16x8 ka0 = *(const s16x8*)&Kpb[0];
    s16x8 ka1 = *(const s16x8*)&Kpb[512];
    s16x8 kl0 = *(const s16x8*)&Kpb[1024];
    s16x8 kl1 = *(const s16x8*)&Kpb[1536];

    float m = -1e30f, lsum = 0.f;
    f32x16 acc[4];
#pragma unroll
    for (int s = 0; s < 4; ++s) acc[s] = (f32x16)0.f;

    for (int kt = 0; kt < NTOT / 32; ++kt) {
        const unsigned short* Vtile = Vpb + (size_t)kt * 16384 + (w * 8) * 512;
        s16x8 va[8];
#pragma unroll
        for (int fr = 0; fr < 8; ++fr)
            va[fr] = *(const s16x8*)&Vtile[fr * 512];
        int ktn = (kt < 48) ? kt + 1 : 48;
        const unsigned short* Ktn = Kpb + (size_t)ktn * 2048;
        s16x8 kn0 = *(const s16x8*)&Ktn[0];
        s16x8 kn1 = *(const s16x8*)&Ktn[512];
        s16x8 kn2 = *(const s16x8*)&Ktn[1024];
        s16x8 kn3 = *(const s16x8*)&Ktn[1536];

        f32x16 sacc = (f32x16)0.f;
        sacc = __builtin_amdgcn_mfma_f32_32x32x16_bf16(kl0, qa0, sacc, 0, 0, 0);
        sacc = __builtin_amdgcn_mfma_f32_32x32x16_bf16(ka0, ql0, sacc, 0, 0, 0);
        sacc = __builtin_amdgcn_mfma_f32_32x32x16_bf16(ka0, qa0, sacc, 0, 0, 0);
        sacc = __builtin_amdgcn_mfma_f32_32x32x16_bf16(kl1, qa1, sacc, 0, 0, 0);
        sacc = __builtin_amdgcn_mfma_f32_32x32x16_bf16(ka1, ql1, sacc, 0, 0, 0);
        sacc = __builtin_amdgcn_mfma_f32_32x32x16_bf16(ka1, qa1, sacc, 0, 0, 0);

        float tmax = sacc[0];
#pragma unroll
        for (int r = 1; r < 16; ++r) tmax = fmaxf(tmax, sacc[r]);
        tmax = fmaxf(tmax, __shfl_xor(tmax, 32, 64));
        if (__any(tmax > m + 8.f)) {
            float mn = fmaxf(m, tmax);
            float sc = __expf(m - mn);
#pragma unroll
            for (int s = 0; s < 4; ++s) acc[s] = acc[s] * sc;
            lsum *= sc;
            m = mn;
        }
        unsigned P2[8];
        float tsum = 0.f;
#pragma unroll
        for (int j = 0; j < 8; ++j) {
            float pa = __expf(sacc[2 * j] - m);
            float pb = __expf(sacc[2 * j + 1] - m);
            tsum += pa + pb;
            P2[j] = cvt_pk_bf16(pa, pb);
        }
        lsum += tsum + __shfl_xor(tsum, 32, 64);
        unsigned X2[8];
#pragma unroll
        for (int j = 0; j < 8; ++j) X2[j] = (unsigned)__shfl_xor((int)P2[j], 32, 64);
        u32x4 b0u, b1u;
        if (hh == 0) {
            b0u[0] = P2[0]; b0u[1] = P2[1]; b0u[2] = X2[0]; b0u[3] = X2[1];
            b1u[0] = P2[4]; b1u[1] = P2[5]; b1u[2] = X2[4]; b1u[3] = X2[5];
        } else {
            b0u[0] = X2[2]; b0u[1] = X2[3]; b0u[2] = P2[2]; b0u[3] = P2[3];
            b1u[0] = X2[6]; b1u[1] = X2[7]; b1u[2] = P2[6]; b1u[3] = P2[7];
        }
        s16x8 pb0 = __builtin_bit_cast(s16x8, b0u);
        s16x8 pb1 = __builtin_bit_cast(s16x8, b1u);

#pragma unroll
        for (int sub = 0; sub < 4; ++sub) {
            acc[sub] = __builtin_amdgcn_mfma_f32_32x32x16_bf16(va[2 * sub],     pb0, acc[sub], 0, 0, 0);
            acc[sub] = __builtin_amdgcn_mfma_f32_32x32x16_bf16(va[2 * sub + 1], pb1, acc[sub], 0, 0, 0);
        }
        ka0 = kn0; ka1 = kn1; kl0 = kn2; kl1 = kn3;
    }

    float inv = 1.f / lsum;
    float* rwg = rw + ((size_t)bh * NTOT + q0) * FDIM;
#pragma unroll
    for (int c = 0; c < 4; ++c) {
        __syncthreads();
        if (w == c) {
#pragma unroll
            for (int sub = 0; sub < 4; ++sub) {
#pragma unroll
                for (int r = 0; r < 16; ++r) {
                    int fl = sub * 32 + (r & 3) + 8 * (r >> 2) + 4 * hh;
                    ebuf[l31 * 132 + fl] = acc[sub][r] * inv;
                }
            }
        }
        __syncthreads();
        int qr = t >> 3, cb = (t & 7) * 16;
#pragma unroll
        for (int j = 0; j < 4; ++j) {
            *(float4*)&rwg[(size_t)qr * FDIM + c * 128 + cb + j * 4] =
                *(const float4*)&ebuf[qr * 132 + cb + j * 4];
        }
    }
}

// ---------------------------------------------------------------------------
// K5: MFMA GEMM per window: out(64n x 256c) = rwL(64n x 64j) @ Wback(64j x 256c)
__global__ __launch_bounds__(256) void k5_back(
    const float* __restrict__ rw, const unsigned short* __restrict__ Wp,
    float* __restrict__ out) {
    __shared__ unsigned short SB[2 * 64 * 72];   // hi plane, lo plane (18.4 KB)
    unsigned short* BhL = SB;
    unsigned short* BlL = SB + 64 * 72;
    int blk = blockIdx.x;
    int b = blk / NTOT, N = blk % NTOT;
    int src = N / NSRC, nloc = N % NSRC;
    int wh = nloc / 28, ww = nloc % 28;
    int t = threadIdx.x;
    int w = t >> 6, lane = t & 63;
    int lm = lane & 15, lk = lane >> 4;
    int pbase = (b * 224 + wh * 8) * 224 + ww * 8;

#pragma unroll
    for (int i = 0; i < 4; ++i) {
        int flat4 = i * 256 + t;
        int h = flat4 >> 7;
        int f0 = (flat4 & 127) * 4;
        float4 v = *(const float4*)&rw[((size_t)(b * NHD + h) * NTOT + N) * FDIM + f0];
        int n = f0 >> 3;
        int ebase = f0 & 7;
        float vv[4] = {v.x, v.y, v.z, v.w};
#pragma unroll
        for (int u = 0; u < 4; ++u) {
            int j8 = ebase + u;
            unsigned short h16, l16;
            split_bf(vv[u], h16, l16);
            int col = ((j8 ^ (n & 7)) << 3) | h;
            BhL[n * 72 + col] = h16;
            BlL[n * 72 + col] = l16;
        }
    }
    __syncthreads();

    f32x4 acc[4][4];
#pragma unroll
    for (int mi = 0; mi < 4; ++mi)
#pragma unroll
        for (int nt = 0; nt < 4; ++nt) acc[mi][nt] = (f32x4)0.f;

    const unsigned short* Wpw = Wp + (size_t)(w * 4) * 2048 + lane * 8;
#pragma unroll
    for (int kc = 0; kc < 2; ++kc) {
        s16x8 Ah[4], Al[4], Bh4[4], Bl4[4];
#pragma unroll
        for (int mi = 0; mi < 4; ++mi) {
            int base = mi * 2048 + kc * 1024;
            Ah[mi] = *(const s16x8*)&Wpw[base];
            Al[mi] = *(const s16x8*)&Wpw[base + 512];
        }
#pragma unroll
        for (int nt = 0; nt < 4; ++nt) {
            int n = nt * 16 + lm;
            int addr = n * 72 + (((kc * 4 + lk) ^ (n & 7)) << 3);
            Bh4[nt] = *(const s16x8*)&BhL[addr];
            Bl4[nt] = *(const s16x8*)&BlL[addr];
        }
#pragma unroll
        for (int mi = 0; mi < 4; ++mi)
#pragma unroll
            for (int nt = 0; nt < 4; ++nt) {
                acc[mi][nt] = __builtin_amdgcn_mfma_f32_16x16x32_bf16(Ah[mi], Bl4[nt], acc[mi][nt], 0, 0, 0);
                acc[mi][nt] = __builtin_amdgcn_mfma_f32_16x16x32_bf16(Al[mi], Bh4[nt], acc[mi][nt], 0, 0, 0);
                acc[mi][nt] = __builtin_amdgcn_mfma_f32_16x16x32_bf16(Ah[mi], Bh4[nt], acc[mi][nt], 0, 0, 0);
            }
    }

    float* eb = (float*)SB;
    float* outp = out + (size_t)src * OUT_PER_SRC;
#pragma unroll
    for (int ch = 0; ch < 4; ++ch) {
        __syncthreads();
        if (w == ch) {
#pragma unroll
            for (int mi = 0; mi < 4; ++mi)
#pragma unroll
                for (int nt = 0; nt < 4; ++nt)
#pragma unroll
                    for (int r = 0; r < 4; ++r) {
                        int n = nt * 16 + lm;
                        int cl = mi * 16 + lk * 4 + r;
                        eb[n * 68 + cl] = acc[mi][nt][r];
                    }
        }
        __syncthreads();
#pragma unroll
        for (int i = 0; i < 4; ++i) {
            int fl4 = i * 256 + t;
            int n = fl4 >> 4, c4 = (fl4 & 15) * 4;
            int opix = pbase + (n >> 3) * 224 + (n & 7);
            *(float4*)&outp[(size_t)opix * DVC + ch * 64 + c4] =
                *(const float4*)&eb[n * 68 + c4];
        }
    }
}

// ---------------------------------------------------------------------------
extern "C" void kernel_launch(void* const* d_in, const int* in_sizes, int n_in,
                              void* d_out, int out_size, void* d_ws, size_t ws_size,
                              hipStream_t stream) {
    const float* v0   = (const float*)d_in[0];
    const float* c0   = (const float*)d_in[1];
    const float* v1   = (const float*)d_in[2];
    const float* c1   = (const float*)d_in[3];
    const float* Wqkv = (const float*)d_in[4];
    const float* bqkv = (const float*)d_in[5];
    const float* gv   = (const float*)d_in[6];
    const float* Wqkc = (const float*)d_in[7];
    const float* bqkc = (const float*)d_in[8];
    const float* gc   = (const float*)d_in[9];
    const float* Wv   = (const float*)d_in[10];
    const float* Wbk  = (const float*)d_in[11];

    float* ws = (float*)d_ws;
    float* rw   = ws;                        // 12,845,056 fl (aliases Vavg/Cavg)
    float* Vavg = ws;                        //    802,816 fl
    float* Cavg = ws + 802816;               //    200,704 fl
    unsigned short* Qp   = (unsigned short*)(ws + 12845056);  // 1,605,632 u16
    unsigned short* Kp   = (unsigned short*)(ws + 13647872);  // 1,605,632 u16
    unsigned short* Wvp  = (unsigned short*)(ws + 14450688);  //    32,768 u16
    unsigned short* Vvb  = (unsigned short*)(ws + 14467072);  // 12,845,056 u16
    unsigned short* Vp   = (unsigned short*)(ws + 20889600);  // 12,845,056 u16
    unsigned short* Wp   = (unsigned short*)(ws + 27312128);  //    65,536 u16
    // total ends at 27,344,896 fl = 109.4 MB

    float* outp = (float*)d_out;

    kz_zero   <<<1568, 256, 0, stream>>>(Qp);   // zeros Qp+Kp (contiguous)
    k0c_wvpack<<<256, 256, 0, stream>>>(Wv, Wvp);
    k0b_wback <<<256, 256, 0, stream>>>(Wbk, Wp);
    k3_vv     <<<2 * NTOT, 256, 0, stream>>>(v0, v1, Wvp, Vvb, Vavg);
    k1c_avg   <<<784, 256, 0, stream>>>(c0, c1, Cavg);
    k2_qk     <<<2 * NTOT, 256, 0, stream>>>(Vavg, Cavg, Wqkv, bqkv, gv, Wqkc, bqkc, gc, Qp, Kp);
    k3b_pack  <<<dim3(49, 16), 256, 0, stream>>>(Vvb, Vp);
    k4_attn   <<<784, 256, 0, stream>>>(Qp, Kp, Vp, rw);
    k5_back   <<<2 * NTOT, 256, 0, stream>>>(rw, Wp, outp);
}